// Round 1
// 732.419 us; speedup vs baseline: 1.3762x; 1.3762x over previous
//
#include <hip/hip_runtime.h>

#define NG 20000
#define ND 8000
#define NS 8000
#define EE 300000
#define DIM 256
#define SCALE_QK 0.17677669529663687f  // 1/sqrt(32)
#define LNEPS 1e-5f

typedef __attribute__((ext_vector_type(4))) float floatx4;
typedef __attribute__((ext_vector_type(8))) short shortx8;

__device__ __forceinline__ float bf2f(unsigned short u) {
    union { unsigned u; float f; } c; c.u = ((unsigned)u) << 16; return c.f;
}
__device__ __forceinline__ unsigned short f2bf(float f) {
    union { float f; unsigned u; } c; c.f = f;
    return (unsigned short)((c.u + 0x7fffu + ((c.u >> 16) & 1u)) >> 16);
}
__device__ __forceinline__ float gelu_exact(float v) {
    return 0.5f * v * (1.0f + erff(v * 0.70710678118654752f));
}

// ---------------------------------------------------------------------------
// MFMA GEMM: C[M,256] = A[M,256] @ W[256,256]^T + bias
// A bf16, W bf16 (pre-converted), bias fp32, C bf16.
// MODE 0: store bf16 C.  MODE 1: Bahdanau epilogue e[m] += sum_n v[n]*tanh(C+b)
// Tile 128m x 64n, BK=32, 256 threads (4 waves; wave -> 32 m-rows).
// ---------------------------------------------------------------------------
template <int MODE>
__global__ __launch_bounds__(256, 2) void gemm_nt(
    const unsigned short* __restrict__ A, const unsigned short* __restrict__ W,
    const float* __restrict__ bias, unsigned short* __restrict__ C,
    const float* __restrict__ vvec, float* __restrict__ evec, int M)
{
    __shared__ unsigned short As[128][40];  // 40 shorts = 80 B rows (16B-aligned)
    __shared__ unsigned short Bs[64][40];
    const int tid = threadIdx.x;
    const int lane = tid & 63, wv = tid >> 6;
    const int quad = lane >> 4, l16 = lane & 15;
    const int m0 = blockIdx.x * 128;
    const int n0 = blockIdx.y * 64;

    floatx4 acc[2][4];
#pragma unroll
    for (int i = 0; i < 2; ++i)
#pragma unroll
        for (int j = 0; j < 4; ++j) acc[i][j] = (floatx4){0.f, 0.f, 0.f, 0.f};

    const int sr = tid >> 2;         // 0..63
    const int sc = (tid & 3) * 8;    // 0,8,16,24

    for (int k0 = 0; k0 < 256; k0 += 32) {
        __syncthreads();
        // B tile: row = output col n0+sr (bf16 direct copy)
        *(int4*)(&Bs[sr][sc]) =
            *(const int4*)(W + (size_t)(n0 + sr) * 256 + k0 + sc);
#pragma unroll
        for (int rr = 0; rr < 2; ++rr) {  // A tile: 128 rows
            int row = sr + rr * 64;
            int gm = m0 + row;
            int4 av = make_int4(0, 0, 0, 0);
            if (gm < M)
                av = *(const int4*)(A + (size_t)gm * 256 + k0 + sc);
            *(int4*)(&As[row][sc]) = av;
        }
        __syncthreads();
        shortx8 af[2], bfr[4];
#pragma unroll
        for (int mf = 0; mf < 2; ++mf)
            af[mf] = *(const shortx8*)(&As[wv * 32 + mf * 16 + l16][quad * 8]);
#pragma unroll
        for (int nf = 0; nf < 4; ++nf)
            bfr[nf] = *(const shortx8*)(&Bs[nf * 16 + l16][quad * 8]);
#pragma unroll
        for (int mf = 0; mf < 2; ++mf)
#pragma unroll
            for (int nf = 0; nf < 4; ++nf)
                acc[mf][nf] = __builtin_amdgcn_mfma_f32_16x16x32_bf16(
                    af[mf], bfr[nf], acc[mf][nf], 0, 0, 0);
    }

    if (MODE == 0) {
#pragma unroll
        for (int mf = 0; mf < 2; ++mf)
#pragma unroll
            for (int r = 0; r < 4; ++r) {
                int m = m0 + wv * 32 + mf * 16 + quad * 4 + r;
                if (m < M) {
#pragma unroll
                    for (int nf = 0; nf < 4; ++nf) {
                        int n = n0 + nf * 16 + l16;
                        C[(size_t)m * 256 + n] = f2bf(acc[mf][nf][r] + bias[n]);
                    }
                }
            }
    } else {
        float p[2][4] = {};
#pragma unroll
        for (int mf = 0; mf < 2; ++mf)
#pragma unroll
            for (int nf = 0; nf < 4; ++nf) {
                int n = n0 + nf * 16 + l16;
                float vn = vvec[n];
                float bn = bias[n];
#pragma unroll
                for (int r = 0; r < 4; ++r)
                    p[mf][r] += vn * tanhf(acc[mf][nf][r] + bn);
            }
#pragma unroll
        for (int mf = 0; mf < 2; ++mf)
#pragma unroll
            for (int r = 0; r < 4; ++r) {
                float s = p[mf][r];
                s += __shfl_xor(s, 1); s += __shfl_xor(s, 2);
                s += __shfl_xor(s, 4); s += __shfl_xor(s, 8);
                if (l16 == 0) {
                    int m = m0 + wv * 32 + mf * 16 + quad * 4 + r;
                    if (m < M) atomicAdd(&evec[m], s);
                }
            }
    }
}

// ---------------------------------------------------------------------------
// bf16 pre-conversion
// ---------------------------------------------------------------------------
struct WSrc { const float* p[14]; };

__global__ void convert_w_kernel(WSrc s, unsigned short* __restrict__ out) {
    int idx = blockIdx.x * 256 + threadIdx.x;       // 14*16384 items
    int mat = idx >> 14;
    int e = (idx & 16383) << 2;
    float4 f = *(const float4*)(s.p[mat] + e);
    ushort4 t;
    t.x = f2bf(f.x); t.y = f2bf(f.y); t.z = f2bf(f.z); t.w = f2bf(f.w);
    *(ushort4*)(out + ((size_t)mat << 16) + e) = t;
}

__global__ void convert_f_kernel(const float* __restrict__ in,
                                 unsigned short* __restrict__ out, int n4) {
    int i = blockIdx.x * 256 + threadIdx.x;
    if (i < n4) {
        float4 f = *(const float4*)(in + (size_t)i * 4);
        ushort4 t;
        t.x = f2bf(f.x); t.y = f2bf(f.y); t.z = f2bf(f.z); t.w = f2bf(f.w);
        *(ushort4*)(out + (size_t)i * 4) = t;
    }
}

// ---------------------------------------------------------------------------
// Utility + CSR build
// ---------------------------------------------------------------------------
__global__ void zero_kernel(int* __restrict__ p, int n) {
    int i = blockIdx.x * blockDim.x + threadIdx.x;
    if (i < n) p[i] = 0;
}
__global__ void fillf_kernel(float* __restrict__ p, int n, float v) {
    int i = blockIdx.x * blockDim.x + threadIdx.x;
    if (i < n) p[i] = v;
}
__global__ void count_kernel(const int* __restrict__ dst, int* __restrict__ cnt, int n) {
    int i = blockIdx.x * blockDim.x + threadIdx.x;
    if (i < n) atomicAdd(&cnt[dst[i]], 1);
}
__global__ void scatter_kernel(const int* __restrict__ src, const int* __restrict__ dst,
                               const int* __restrict__ offs, int* __restrict__ cur,
                               int* __restrict__ srcs, int n) {
    int i = blockIdx.x * blockDim.x + threadIdx.x;
    if (i < n) {
        int d = dst[i];
        int pos = offs[d] + atomicAdd(&cur[d], 1);
        srcs[pos] = src[i];
    }
}
__device__ void block_exscan(const int* cnt, int* offs, int n) {
    __shared__ int wsum[4];
    int t = threadIdx.x, lane = t & 63, wv = t >> 6;
    int carry = 0;
    for (int base = 0; base < n; base += 256) {
        int i = base + t;
        int v = (i < n) ? cnt[i] : 0;
        int x = v;
#pragma unroll
        for (int o = 1; o < 64; o <<= 1) {
            int u = __shfl_up(x, o);
            if (lane >= o) x += u;
        }
        if (lane == 63) wsum[wv] = x;
        __syncthreads();
        int woff = 0;
        for (int w = 0; w < wv; ++w) woff += wsum[w];
        int total = wsum[0] + wsum[1] + wsum[2] + wsum[3];
        if (i < n) offs[i] = carry + woff + x - v;   // exclusive prefix
        carry += total;
        __syncthreads();
    }
}
__global__ void scan4_kernel(const int* c0, int* o0, int n0, const int* c1, int* o1, int n1,
                             const int* c2, int* o2, int n2, const int* c3, int* o3, int n3) {
    if (blockIdx.x == 0) block_exscan(c0, o0, n0);
    else if (blockIdx.x == 1) block_exscan(c1, o1, n1);
    else if (blockIdx.x == 2) block_exscan(c2, o2, n2);
    else block_exscan(c3, o3, n3);
}

// ---------------------------------------------------------------------------
// Fused CSR aggregation, wave-parallel version.
// Each WAVE covers the full 256-feature row (4 bf16 per lane, 8B loads);
// head h = dims 32h..32h+31 = lanes 8h..8h+7 -> 3-shfl dot reduce.
// The block's 4 waves split the edge list (stride 4); each wave processes
// edges in PAIRS (two independent load+dot chains per online update).
// Per-wave (m, l, acc[4]) partials merged via LDS at the end. Atomic-free.
// ---------------------------------------------------------------------------
__device__ __forceinline__ void wave_attn4(
    const unsigned short* __restrict__ Q, const unsigned short* __restrict__ K,
    const unsigned short* __restrict__ V, const int* __restrict__ offs,
    const int* __restrict__ cnt, const int* __restrict__ srcs,
    int d, int lane, int wv, float& mO, float& lO, float acc[4])
{
    const int lo = lane * 4;
    ushort4 qv = *(const ushort4*)(Q + (size_t)d * 256 + lo);
    const float q0 = bf2f(qv.x), q1 = bf2f(qv.y), q2 = bf2f(qv.z), q3 = bf2f(qv.w);
    const int beg = offs[d], num = cnt[d];
    float m = -INFINITY, l = 0.f;
    float a0 = 0.f, a1 = 0.f, a2 = 0.f, a3 = 0.f;
    int i = wv;
    for (; i + 4 < num; i += 8) {
        int s0 = srcs[beg + i], s1 = srcs[beg + i + 4];
        const size_t r0 = (size_t)s0 * 256 + lo, r1 = (size_t)s1 * 256 + lo;
        ushort4 k0 = *(const ushort4*)(K + r0);
        ushort4 k1 = *(const ushort4*)(K + r1);
        ushort4 v0 = *(const ushort4*)(V + r0);
        ushort4 v1 = *(const ushort4*)(V + r1);
        float p0 = q0 * bf2f(k0.x) + q1 * bf2f(k0.y) + q2 * bf2f(k0.z) + q3 * bf2f(k0.w);
        float p1 = q0 * bf2f(k1.x) + q1 * bf2f(k1.y) + q2 * bf2f(k1.z) + q3 * bf2f(k1.w);
        p0 += __shfl_xor(p0, 1); p1 += __shfl_xor(p1, 1);
        p0 += __shfl_xor(p0, 2); p1 += __shfl_xor(p1, 2);
        p0 += __shfl_xor(p0, 4); p1 += __shfl_xor(p1, 4);
        float sc0 = p0 * SCALE_QK, sc1 = p1 * SCALE_QK;
        float mn = fmaxf(m, fmaxf(sc0, sc1));
        float eo = __expf(m - mn);   // first iter: exp(-inf)=0
        float e0 = __expf(sc0 - mn), e1 = __expf(sc1 - mn);
        a0 = a0 * eo + e0 * bf2f(v0.x) + e1 * bf2f(v1.x);
        a1 = a1 * eo + e0 * bf2f(v0.y) + e1 * bf2f(v1.y);
        a2 = a2 * eo + e0 * bf2f(v0.z) + e1 * bf2f(v1.z);
        a3 = a3 * eo + e0 * bf2f(v0.w) + e1 * bf2f(v1.w);
        l = l * eo + e0 + e1;
        m = mn;
    }
    if (i < num) {
        int s0 = srcs[beg + i];
        const size_t r0 = (size_t)s0 * 256 + lo;
        ushort4 k0 = *(const ushort4*)(K + r0);
        ushort4 v0 = *(const ushort4*)(V + r0);
        float p0 = q0 * bf2f(k0.x) + q1 * bf2f(k0.y) + q2 * bf2f(k0.z) + q3 * bf2f(k0.w);
        p0 += __shfl_xor(p0, 1);
        p0 += __shfl_xor(p0, 2);
        p0 += __shfl_xor(p0, 4);
        float sc0 = p0 * SCALE_QK;
        float mn = fmaxf(m, sc0);
        float eo = __expf(m - mn);
        float e0 = __expf(sc0 - mn);
        a0 = a0 * eo + e0 * bf2f(v0.x);
        a1 = a1 * eo + e0 * bf2f(v0.y);
        a2 = a2 * eo + e0 * bf2f(v0.z);
        a3 = a3 * eo + e0 * bf2f(v0.w);
        l = l * eo + e0;
        m = mn;
    }
    mO = m; lO = l;
    acc[0] = a0; acc[1] = a1; acc[2] = a2; acc[3] = a3;
}

// Merge 4 per-wave partials; returns msg for feature t (thread t owns feat t).
__device__ __forceinline__ float merge4(
    float m, float l, const float acc[4], int tid,
    float* sA /*[4*256]*/, float* sM /*[32]*/, float* sL /*[32]*/)
{
    int lane = tid & 63, wv = tid >> 6;
    float* aw = sA + wv * 256 + lane * 4;
    aw[0] = acc[0]; aw[1] = acc[1]; aw[2] = acc[2]; aw[3] = acc[3];
    if ((lane & 7) == 0) { sM[wv * 8 + (lane >> 3)] = m; sL[wv * 8 + (lane >> 3)] = l; }
    __syncthreads();
    int h = tid >> 5;
    float m0 = sM[h], m1 = sM[8 + h], m2 = sM[16 + h], m3 = sM[24 + h];
    float ms = fmaxf(fmaxf(m0, m1), fmaxf(m2, m3));
    float A = 0.f, L = 0.f;
    if (ms > -INFINITY) {
        float w0 = __expf(m0 - ms), w1 = __expf(m1 - ms);
        float w2 = __expf(m2 - ms), w3 = __expf(m3 - ms);
        L = sL[h] * w0 + sL[8 + h] * w1 + sL[16 + h] * w2 + sL[24 + h] * w3;
        A = sA[tid] * w0 + sA[256 + tid] * w1 + sA[512 + tid] * w2 + sA[768 + tid] * w3;
    }
    return (L > 0.f) ? A / L : 0.f;
}

__device__ __forceinline__ void block_ln_store(
    float x, const float* __restrict__ g, const float* __restrict__ b,
    float* __restrict__ out, unsigned short* __restrict__ out_bf, int d, int t)
{
    __shared__ float rbuf[8];
    float s1 = x, s2 = x * x;
#pragma unroll
    for (int o = 1; o < 64; o <<= 1) { s1 += __shfl_xor(s1, o); s2 += __shfl_xor(s2, o); }
    int lane = t & 63, wv = t >> 6;
    if (lane == 0) { rbuf[wv] = s1; rbuf[4 + wv] = s2; }
    __syncthreads();
    float a0 = rbuf[0] + rbuf[1] + rbuf[2] + rbuf[3];
    float b0 = rbuf[4] + rbuf[5] + rbuf[6] + rbuf[7];
    float mu = a0 * (1.f / 256.f);
    float var = fmaxf(b0 * (1.f / 256.f) - mu * mu, 0.f);
    float y = (x - mu) * rsqrtf(var + LNEPS) * g[t] + b[t];
    out[(size_t)d * 256 + t] = y;
    if (out_bf) out_bf[(size_t)d * 256 + t] = f2bf(y);
}

__global__ __launch_bounds__(256) void agg_gm_kernel(
    const unsigned short* __restrict__ Q, const unsigned short* __restrict__ K,
    const unsigned short* __restrict__ V, const int* __restrict__ offs,
    const int* __restrict__ cnt, const int* __restrict__ srcs,
    unsigned short* __restrict__ gm)
{
    __shared__ float sA[4 * 256];
    __shared__ float sM[32], sL[32];
    int d = blockIdx.x, tid = threadIdx.x;
    float m, l, acc[4];
    wave_attn4(Q, K, V, offs, cnt, srcs, d, tid & 63, tid >> 6, m, l, acc);
    float msg = merge4(m, l, acc, tid, sA, sM, sL);
    gm[(size_t)d * 256 + tid] = f2bf(msg);
}

__global__ __launch_bounds__(256) void agg_ln_kernel(
    const unsigned short* __restrict__ Q, const unsigned short* __restrict__ K,
    const unsigned short* __restrict__ V, const int* __restrict__ offs,
    const int* __restrict__ cnt, const int* __restrict__ srcs,
    const float* __restrict__ feat, const float* __restrict__ g,
    const float* __restrict__ b, float* __restrict__ out)
{
    __shared__ float sA[4 * 256];
    __shared__ float sM[32], sL[32];
    int d = blockIdx.x, tid = threadIdx.x;
    float m, l, acc[4];
    wave_attn4(Q, K, V, offs, cnt, srcs, d, tid & 63, tid >> 6, m, l, acc);
    float msg = merge4(m, l, acc, tid, sA, sM, sL);
    float x = feat[(size_t)d * 256 + tid] + gelu_exact(msg);
    block_ln_store(x, g, b, out, nullptr, d, tid);
}

__global__ __launch_bounds__(256) void gene_fusion_kernel(
    const float* __restrict__ gene_feat, const unsigned short* __restrict__ gm_d,
    const unsigned short* __restrict__ gm_s, const float* __restrict__ e1,
    const float* __restrict__ e2, const int* __restrict__ cnt_d,
    const int* __restrict__ cnt_s, const float* __restrict__ g,
    const float* __restrict__ b, float* __restrict__ out,
    unsigned short* __restrict__ out_bf)
{
    int d = blockIdx.x, t = threadIdx.x;
    float g1 = bf2f(gm_d[(size_t)d * 256 + t]);
    float g2 = bf2f(gm_s[(size_t)d * 256 + t]);
    bool hd = cnt_d[d] > 0, hs = cnt_s[d] > 0;
    float msg;
    if (hd && hs) {
        float a = e1[d], bb = e2[d];
        float mm = fmaxf(a, bb);   // softmax([e1+bv,e2+bv]) == softmax([e1,e2])
        float wa = __expf(a - mm), wb = __expf(bb - mm);
        msg = (wa * g1 + wb * g2) / (wa + wb);
    } else if (hd) msg = g1;
    else if (hs) msg = g2;
    else msg = 0.f;
    float x = gene_feat[(size_t)d * 256 + t] + gelu_exact(msg);
    block_ln_store(x, g, b, out, out_bf, d, t);
}

// ---------------------------------------------------------------------------
extern "C" void kernel_launch(void* const* d_in, const int* in_sizes, int n_in,
                              void* d_out, int out_size, void* d_ws, size_t ws_size,
                              hipStream_t stream)
{
    float* out_f32 = (float*)d_out;

    const float* gene_feat    = (const float*)d_in[0];
    const float* drug_feat    = (const float*)d_in[1];
    const float* disease_feat = (const float*)d_in[2];
    const float* dg_Wq = (const float*)d_in[3];
    const float* dg_bq = (const float*)d_in[4];
    const float* dg_Wk = (const float*)d_in[5];
    const float* dg_bk = (const float*)d_in[6];
    const float* dg_Wv = (const float*)d_in[7];
    const float* dg_bv = (const float*)d_in[8];
    const float* disg_Wq = (const float*)d_in[9];
    const float* disg_bq = (const float*)d_in[10];
    const float* disg_Wk = (const float*)d_in[11];
    const float* disg_bk = (const float*)d_in[12];
    const float* disg_Wv = (const float*)d_in[13];
    const float* disg_bv = (const float*)d_in[14];
    const float* gd_Wq = (const float*)d_in[15];
    const float* gd_bq = (const float*)d_in[16];
    const float* gd_Wk = (const float*)d_in[17];
    const float* gd_bk = (const float*)d_in[18];
    const float* gd_Wv = (const float*)d_in[19];
    const float* gd_bv = (const float*)d_in[20];
    const float* gdis_Wq = (const float*)d_in[21];
    const float* gdis_bq = (const float*)d_in[22];
    const float* gdis_Wk = (const float*)d_in[23];
    const float* gdis_bk = (const float*)d_in[24];
    const float* gdis_Wv = (const float*)d_in[25];
    const float* gdis_bv = (const float*)d_in[26];
    const float* f_W1 = (const float*)d_in[27];
    const float* f_b1 = (const float*)d_in[28];
    const float* f_W2 = (const float*)d_in[29];
    const float* f_b2 = (const float*)d_in[30];
    const float* f_v  = (const float*)d_in[31];
    const float* ln1_g = (const float*)d_in[33];
    const float* ln1_b = (const float*)d_in[34];
    const float* ln2_g = (const float*)d_in[35];
    const float* ln2_b = (const float*)d_in[36];
    const int* dg_src   = (const int*)d_in[37];
    const int* dg_dst   = (const int*)d_in[38];
    const int* disg_src = (const int*)d_in[39];
    const int* disg_dst = (const int*)d_in[40];
    const int* gd_src   = (const int*)d_in[41];
    const int* gd_dst   = (const int*)d_in[42];
    const int* gdis_src = (const int*)d_in[43];
    const int* gdis_dst = (const int*)d_in[44];

    // ---- workspace (~77 MB) ----
    char* ws = (char*)d_ws;
    size_t off = 0;
    auto alloc = [&](size_t bytes) -> char* {
        char* p = ws + off;
        off += (bytes + 511) & ~(size_t)511;
        return p;
    };
    // zero region start
    int* cnt_dg   = (int*)alloc(NG * 4);
    int* cnt_disg = (int*)alloc(NG * 4);
    int* cnt_gd   = (int*)alloc(ND * 4);
    int* cnt_gdis = (int*)alloc(NS * 4);
    int* cur_dg   = (int*)alloc(NG * 4);
    int* cur_disg = (int*)alloc(NG * 4);
    int* cur_gd   = (int*)alloc(ND * 4);
    int* cur_gdis = (int*)alloc(NS * 4);
    float* e1 = (float*)alloc(NG * 4);
    float* e2 = (float*)alloc(NG * 4);
    size_t zero_len = off;   // bytes to zero each call
    int* offs_dg   = (int*)alloc(NG * 4);
    int* offs_disg = (int*)alloc(NG * 4);
    int* offs_gd   = (int*)alloc(ND * 4);
    int* offs_gdis = (int*)alloc(NS * 4);
    int* srcs_dg   = (int*)alloc((size_t)EE * 4);
    int* srcs_disg = (int*)alloc((size_t)EE * 4);
    int* srcs_gd   = (int*)alloc((size_t)EE * 4);
    int* srcs_gdis = (int*)alloc((size_t)EE * 4);
    unsigned short* Qb   = (unsigned short*)alloc((size_t)NG * 256 * 2);
    unsigned short* Kb   = (unsigned short*)alloc((size_t)NG * 256 * 2);
    unsigned short* Vb   = (unsigned short*)alloc((size_t)NG * 256 * 2);
    unsigned short* gm_d = (unsigned short*)alloc((size_t)NG * 256 * 2);
    unsigned short* gm_s = (unsigned short*)alloc((size_t)NG * 256 * 2);
    unsigned short* gene_bf = (unsigned short*)alloc((size_t)NG * 256 * 2);
    unsigned short* drug_bf = (unsigned short*)alloc((size_t)ND * 256 * 2);
    unsigned short* dis_bf  = (unsigned short*)alloc((size_t)NS * 256 * 2);
    unsigned short* Wbf     = (unsigned short*)alloc((size_t)14 * 65536 * 2);
    size_t need = off;

    // gm_d is dead after gene_fusion_kernel -> reuse as bf16 gene_out
    unsigned short* gene_out_bf = gm_d;

    float* out_drug = out_f32;                       // [8000, 256]
    float* out_dis  = out_drug + (size_t)ND * 256;   // [8000, 256]
    float* out_gene = out_dis + (size_t)NS * 256;    // [20000, 256]

    if (ws_size < need) {   // sentinel: 1000.0f
        fillf_kernel<<<(out_size + 255) / 256, 256, 0, stream>>>(out_f32, out_size, 1000.0f);
        return;
    }

    zero_kernel<<<((int)(zero_len / 4) + 255) / 256, 256, 0, stream>>>(
        (int*)d_ws, (int)(zero_len / 4));

    // ---- bf16 pre-conversion (weights + input features) ----
    {
        WSrc s;
        const float* wl[14] = {dg_Wq, dg_Wk, dg_Wv, disg_Wq, disg_Wk, disg_Wv,
                               gd_Wq, gd_Wk, gd_Wv, gdis_Wq, gdis_Wk, gdis_Wv,
                               f_W1, f_W2};
        for (int i = 0; i < 14; ++i) s.p[i] = wl[i];
        convert_w_kernel<<<(14 * 16384) / 256, 256, 0, stream>>>(s, Wbf);
    }
    convert_f_kernel<<<(NG * 64) / 256, 256, 0, stream>>>(gene_feat, gene_bf, NG * 64);
    convert_f_kernel<<<(ND * 64) / 256, 256, 0, stream>>>(drug_feat, drug_bf, ND * 64);
    convert_f_kernel<<<(NS * 64) / 256, 256, 0, stream>>>(disease_feat, dis_bf, NS * 64);

    // ---- CSR build for all 4 graphs ----
    const int EB = (EE + 255) / 256;
    count_kernel<<<EB, 256, 0, stream>>>(dg_dst, cnt_dg, EE);
    count_kernel<<<EB, 256, 0, stream>>>(disg_dst, cnt_disg, EE);
    count_kernel<<<EB, 256, 0, stream>>>(gd_dst, cnt_gd, EE);
    count_kernel<<<EB, 256, 0, stream>>>(gdis_dst, cnt_gdis, EE);
    scan4_kernel<<<4, 256, 0, stream>>>(cnt_dg, offs_dg, NG, cnt_disg, offs_disg, NG,
                                        cnt_gd, offs_gd, ND, cnt_gdis, offs_gdis, NS);
    scatter_kernel<<<EB, 256, 0, stream>>>(dg_src, dg_dst, offs_dg, cur_dg, srcs_dg, EE);
    scatter_kernel<<<EB, 256, 0, stream>>>(disg_src, disg_dst, offs_disg, cur_disg, srcs_disg, EE);
    scatter_kernel<<<EB, 256, 0, stream>>>(gd_src, gd_dst, offs_gd, cur_gd, srcs_gd, EE);
    scatter_kernel<<<EB, 256, 0, stream>>>(gdis_src, gdis_dst, offs_gdis, cur_gdis, srcs_gdis, EE);

    auto gemmB = [&](const unsigned short* A, int widx, const float* bias,
                     unsigned short* C, int M) {
        dim3 g((M + 127) / 128, 4);
        gemm_nt<0><<<g, 256, 0, stream>>>(A, Wbf + (size_t)widx * 65536, bias, C,
                                          nullptr, nullptr, M);
    };

    // ---- stage 1: drug->gene ----
    gemmB(gene_bf, 0, dg_bq, Qb, NG);
    gemmB(drug_bf, 1, dg_bk, Kb, ND);
    gemmB(drug_bf, 2, dg_bv, Vb, ND);
    agg_gm_kernel<<<NG, 256, 0, stream>>>(Qb, Kb, Vb, offs_dg, cnt_dg, srcs_dg, gm_d);

    // ---- stage 1: disease->gene ----
    gemmB(gene_bf, 3, disg_bq, Qb, NG);
    gemmB(dis_bf, 4, disg_bk, Kb, NS);
    gemmB(dis_bf, 5, disg_bv, Vb, NS);
    agg_gm_kernel<<<NG, 256, 0, stream>>>(Qb, Kb, Vb, offs_disg, cnt_disg, srcs_disg, gm_s);

    // ---- Bahdanau fusion + LN1 -> gene_out (fp32 + bf16 copy) ----
    {
        dim3 gb((NG + 127) / 128, 4);
        gemm_nt<1><<<gb, 256, 0, stream>>>(gm_d, Wbf + (size_t)12 * 65536, f_b1,
                                           nullptr, f_v, e1, NG);
        gemm_nt<1><<<gb, 256, 0, stream>>>(gm_s, Wbf + (size_t)13 * 65536, f_b2,
                                           nullptr, f_v, e2, NG);
    }
    gene_fusion_kernel<<<NG, 256, 0, stream>>>(gene_feat, gm_d, gm_s, e1, e2,
                                               cnt_dg, cnt_disg, ln1_g, ln1_b,
                                               out_gene, gene_out_bf);

    // ---- stage 2: gene->drug ----
    gemmB(drug_bf, 6, gd_bq, Qb, ND);
    gemmB(gene_out_bf, 7, gd_bk, Kb, NG);
    gemmB(gene_out_bf, 8, gd_bv, Vb, NG);
    agg_ln_kernel<<<ND, 256, 0, stream>>>(Qb, Kb, Vb, offs_gd, cnt_gd, srcs_gd,
                                          drug_feat, ln2_g, ln2_b, out_drug);

    // ---- stage 2: gene->disease ----
    gemmB(dis_bf, 9, gdis_bq, Qb, NS);
    gemmB(gene_out_bf, 10, gdis_bk, Kb, NG);
    gemmB(gene_out_bf, 11, gdis_bv, Vb, NG);
    agg_ln_kernel<<<NS, 256, 0, stream>>>(Qb, Kb, Vb, offs_gdis, cnt_gdis, srcs_gdis,
                                          disease_feat, ln2_g, ln2_b, out_dis);
}

// Round 2
// 631.530 us; speedup vs baseline: 1.5961x; 1.1598x over previous
//
#include <hip/hip_runtime.h>

#define NG 20000
#define ND 8000
#define NS 8000
#define EE 300000
#define DIM 256
#define SCALE_QK 0.17677669529663687f  // 1/sqrt(32)
#define LNEPS 1e-5f

typedef __attribute__((ext_vector_type(4))) float floatx4;
typedef __attribute__((ext_vector_type(8))) short shortx8;

__device__ __forceinline__ float bf2f(unsigned short u) {
    union { unsigned u; float f; } c; c.u = ((unsigned)u) << 16; return c.f;
}
__device__ __forceinline__ unsigned short f2bf(float f) {
    union { float f; unsigned u; } c; c.f = f;
    return (unsigned short)((c.u + 0x7fffu + ((c.u >> 16) & 1u)) >> 16);
}
__device__ __forceinline__ float gelu_exact(float v) {
    return 0.5f * v * (1.0f + erff(v * 0.70710678118654752f));
}

// ---------------------------------------------------------------------------
// MFMA GEMM: C[M, NCOLS] = A[M,256] @ W[NCOLS,256]^T + bias
// A bf16, W bf16 (pre-converted), bias fp32, C bf16 (row stride ldc).
// Columns n<256 use bias1[n]; n>=256 use bias2[n-256] (for fused K|V GEMM).
// MODE 0: store bf16 C.  MODE 1: Bahdanau epilogue e[m] += sum_n v[n]*tanh(C+b)
// Tile 128m x 64n, BK=32, 256 threads (4 waves; wave -> 32 m-rows).
// ---------------------------------------------------------------------------
template <int MODE>
__global__ __launch_bounds__(256, 2) void gemm_nt(
    const unsigned short* __restrict__ A, const unsigned short* __restrict__ W,
    const float* __restrict__ bias1, const float* __restrict__ bias2,
    unsigned short* __restrict__ C, int ldc,
    const float* __restrict__ vvec, float* __restrict__ evec, int M)
{
    __shared__ unsigned short As[128][40];  // 40 shorts = 80 B rows (16B-aligned)
    __shared__ unsigned short Bs[64][40];
    const int tid = threadIdx.x;
    const int lane = tid & 63, wv = tid >> 6;
    const int quad = lane >> 4, l16 = lane & 15;
    const int m0 = blockIdx.x * 128;
    const int n0 = blockIdx.y * 64;

    floatx4 acc[2][4];
#pragma unroll
    for (int i = 0; i < 2; ++i)
#pragma unroll
        for (int j = 0; j < 4; ++j) acc[i][j] = (floatx4){0.f, 0.f, 0.f, 0.f};

    const int sr = tid >> 2;         // 0..63
    const int sc = (tid & 3) * 8;    // 0,8,16,24

    for (int k0 = 0; k0 < 256; k0 += 32) {
        __syncthreads();
        // B tile: row = output col n0+sr (bf16 direct copy)
        *(int4*)(&Bs[sr][sc]) =
            *(const int4*)(W + (size_t)(n0 + sr) * 256 + k0 + sc);
#pragma unroll
        for (int rr = 0; rr < 2; ++rr) {  // A tile: 128 rows
            int row = sr + rr * 64;
            int gm = m0 + row;
            int4 av = make_int4(0, 0, 0, 0);
            if (gm < M)
                av = *(const int4*)(A + (size_t)gm * 256 + k0 + sc);
            *(int4*)(&As[row][sc]) = av;
        }
        __syncthreads();
        shortx8 af[2], bfr[4];
#pragma unroll
        for (int mf = 0; mf < 2; ++mf)
            af[mf] = *(const shortx8*)(&As[wv * 32 + mf * 16 + l16][quad * 8]);
#pragma unroll
        for (int nf = 0; nf < 4; ++nf)
            bfr[nf] = *(const shortx8*)(&Bs[nf * 16 + l16][quad * 8]);
#pragma unroll
        for (int mf = 0; mf < 2; ++mf)
#pragma unroll
            for (int nf = 0; nf < 4; ++nf)
                acc[mf][nf] = __builtin_amdgcn_mfma_f32_16x16x32_bf16(
                    af[mf], bfr[nf], acc[mf][nf], 0, 0, 0);
    }

    if (MODE == 0) {
#pragma unroll
        for (int mf = 0; mf < 2; ++mf)
#pragma unroll
            for (int r = 0; r < 4; ++r) {
                int m = m0 + wv * 32 + mf * 16 + quad * 4 + r;
                if (m < M) {
#pragma unroll
                    for (int nf = 0; nf < 4; ++nf) {
                        int n = n0 + nf * 16 + l16;
                        float bn = (n < 256) ? bias1[n] : bias2[n - 256];
                        C[(size_t)m * ldc + n] = f2bf(acc[mf][nf][r] + bn);
                    }
                }
            }
    } else {
        float p[2][4] = {};
#pragma unroll
        for (int mf = 0; mf < 2; ++mf)
#pragma unroll
            for (int nf = 0; nf < 4; ++nf) {
                int n = n0 + nf * 16 + l16;
                float vn = vvec[n];
                float bn = bias1[n];
#pragma unroll
                for (int r = 0; r < 4; ++r)
                    p[mf][r] += vn * tanhf(acc[mf][nf][r] + bn);
            }
#pragma unroll
        for (int mf = 0; mf < 2; ++mf)
#pragma unroll
            for (int r = 0; r < 4; ++r) {
                float s = p[mf][r];
                s += __shfl_xor(s, 1); s += __shfl_xor(s, 2);
                s += __shfl_xor(s, 4); s += __shfl_xor(s, 8);
                if (l16 == 0) {
                    int m = m0 + wv * 32 + mf * 16 + quad * 4 + r;
                    if (m < M) atomicAdd(&evec[m], s);
                }
            }
    }
}

// ---------------------------------------------------------------------------
// bf16 pre-conversion
// ---------------------------------------------------------------------------
struct WSrc { const float* p[14]; };

__global__ void convert_w_kernel(WSrc s, unsigned short* __restrict__ out) {
    int idx = blockIdx.x * 256 + threadIdx.x;       // 14*16384 items
    int mat = idx >> 14;
    int e = (idx & 16383) << 2;
    float4 f = *(const float4*)(s.p[mat] + e);
    ushort4 t;
    t.x = f2bf(f.x); t.y = f2bf(f.y); t.z = f2bf(f.z); t.w = f2bf(f.w);
    *(ushort4*)(out + ((size_t)mat << 16) + e) = t;
}

__global__ void convert_feat_kernel(
    const float* __restrict__ gf, const float* __restrict__ df,
    const float* __restrict__ sf, unsigned short* __restrict__ go,
    unsigned short* __restrict__ dougo, unsigned short* __restrict__ so)
{
    const int NG4 = NG * 64, ND4 = ND * 64, NS4 = NS * 64;
    int i = blockIdx.x * 256 + threadIdx.x;
    const float* in; unsigned short* out; int j;
    if (i < NG4) { in = gf; out = go; j = i; }
    else if (i < NG4 + ND4) { in = df; out = dougo; j = i - NG4; }
    else if (i < NG4 + ND4 + NS4) { in = sf; out = so; j = i - NG4 - ND4; }
    else return;
    float4 f = *(const float4*)(in + (size_t)j * 4);
    ushort4 t;
    t.x = f2bf(f.x); t.y = f2bf(f.y); t.z = f2bf(f.z); t.w = f2bf(f.w);
    *(ushort4*)(out + (size_t)j * 4) = t;
}

// ---------------------------------------------------------------------------
// Utility + CSR build
// ---------------------------------------------------------------------------
__global__ void zero_kernel(int* __restrict__ p, int n) {
    int i = blockIdx.x * blockDim.x + threadIdx.x;
    if (i < n) p[i] = 0;
}
__global__ void fillf_kernel(float* __restrict__ p, int n, float v) {
    int i = blockIdx.x * blockDim.x + threadIdx.x;
    if (i < n) p[i] = v;
}

struct Cnt4 {
    const int* dst[4];
    int* cnt[4];
};
__global__ void count4_kernel(Cnt4 a) {
    int i = blockIdx.x * 256 + threadIdx.x;
    if (i >= 4 * EE) return;
    int g = i / EE, e = i - g * EE;
    atomicAdd(&a.cnt[g][a.dst[g][e]], 1);
}

struct Sc4 {
    const int* src[4];
    const int* dst[4];
    const int* offs[4];
    int* cur[4];
    int* srcs[4];
};
__global__ void scatter4_kernel(Sc4 a) {
    int i = blockIdx.x * 256 + threadIdx.x;
    if (i >= 4 * EE) return;
    int g = i / EE, e = i - g * EE;
    int d = a.dst[g][e];
    int pos = a.offs[g][d] + atomicAdd(&a.cur[g][d], 1);
    a.srcs[g][pos] = a.src[g][e];
}

// Fast single-block exclusive scan: segment per thread, no per-chunk barriers.
__device__ void block_exscan(const int* __restrict__ cnt, int* __restrict__ offs, int n) {
    __shared__ int ws4[4];
    int t = threadIdx.x, lane = t & 63, wv = t >> 6;
    int seg = (n + 255) >> 8;
    int beg = t * seg;
    int end = beg + seg; if (end > n) end = n;
    int sum = 0;
#pragma unroll 4
    for (int i = beg; i < end; ++i) sum += cnt[i];
    int x = sum;
#pragma unroll
    for (int o = 1; o < 64; o <<= 1) {
        int u = __shfl_up(x, o);
        if (lane >= o) x += u;
    }
    if (lane == 63) ws4[wv] = x;
    __syncthreads();
    int woff = 0;
    for (int w = 0; w < wv; ++w) woff += ws4[w];
    int run = woff + x - sum;   // exclusive prefix of this thread's segment
#pragma unroll 4
    for (int i = beg; i < end; ++i) { offs[i] = run; run += cnt[i]; }
}
__global__ void scan4_kernel(const int* c0, int* o0, int n0, const int* c1, int* o1, int n1,
                             const int* c2, int* o2, int n2, const int* c3, int* o3, int n3) {
    if (blockIdx.x == 0) block_exscan(c0, o0, n0);
    else if (blockIdx.x == 1) block_exscan(c1, o1, n1);
    else if (blockIdx.x == 2) block_exscan(c2, o2, n2);
    else block_exscan(c3, o3, n3);
}

// ---------------------------------------------------------------------------
// Fused CSR aggregation — ONE WAVE PER NODE (4 nodes/block, no LDS/barriers).
// Wave covers the full 256-feature row (4 bf16/lane, 8B loads);
// head h = dims 32h..32h+31 = lanes 8h..8h+7 -> 3-shfl dot reduce.
// 4 independent online-softmax chains (edge i -> chain i&3), merged
// in-register at the end. K/V interleaved: KV[s][0:256]=K, KV[s][256:512]=V.
// ---------------------------------------------------------------------------
__device__ __forceinline__ void chain_update(
    float sc, const ushort4& vx, float& m, float& l,
    float& a0, float& a1, float& a2, float& a3)
{
    float mn = fmaxf(m, sc);
    float eo = __expf(m - mn);   // first edge: exp(-inf)=0
    float en = __expf(sc - mn);
    a0 = a0 * eo + en * bf2f(vx.x);
    a1 = a1 * eo + en * bf2f(vx.y);
    a2 = a2 * eo + en * bf2f(vx.z);
    a3 = a3 * eo + en * bf2f(vx.w);
    l = l * eo + en;
    m = mn;
}

__device__ __forceinline__ void wave_attn_node(
    const unsigned short* __restrict__ Q, const unsigned short* __restrict__ KV,
    const int* __restrict__ offs, const int* __restrict__ cnt,
    const int* __restrict__ srcs, int du, int lane,
    float& g0, float& g1, float& g2, float& g3)
{
    const int lo = lane * 4;
    ushort4 qv = *(const ushort4*)(Q + (size_t)du * 256 + lo);
    const float q0 = bf2f(qv.x), q1 = bf2f(qv.y), q2 = bf2f(qv.z), q3 = bf2f(qv.w);
    const int beg = offs[du], num = cnt[du];

    float m[4], l[4], a[4][4];
#pragma unroll
    for (int c = 0; c < 4; ++c) {
        m[c] = -INFINITY; l[c] = 0.f;
        a[c][0] = a[c][1] = a[c][2] = a[c][3] = 0.f;
    }

    int i = 0;
    for (; i + 3 < num; i += 4) {
        ushort4 kx[4], vx[4];
#pragma unroll
        for (int c = 0; c < 4; ++c) {
            int s = srcs[beg + i + c];
            const unsigned short* r = KV + (size_t)s * 512 + lo;
            kx[c] = *(const ushort4*)r;
            vx[c] = *(const ushort4*)(r + 256);
        }
        float p[4];
#pragma unroll
        for (int c = 0; c < 4; ++c)
            p[c] = q0 * bf2f(kx[c].x) + q1 * bf2f(kx[c].y) +
                   q2 * bf2f(kx[c].z) + q3 * bf2f(kx[c].w);
#pragma unroll
        for (int c = 0; c < 4; ++c) p[c] += __shfl_xor(p[c], 1);
#pragma unroll
        for (int c = 0; c < 4; ++c) p[c] += __shfl_xor(p[c], 2);
#pragma unroll
        for (int c = 0; c < 4; ++c) p[c] += __shfl_xor(p[c], 4);
#pragma unroll
        for (int c = 0; c < 4; ++c)
            chain_update(p[c] * SCALE_QK, vx[c], m[c], l[c],
                         a[c][0], a[c][1], a[c][2], a[c][3]);
    }
    for (; i < num; ++i) {
        int c = i & 3;
        int s = srcs[beg + i];
        const unsigned short* r = KV + (size_t)s * 512 + lo;
        ushort4 kx = *(const ushort4*)r;
        ushort4 vx = *(const ushort4*)(r + 256);
        float p = q0 * bf2f(kx.x) + q1 * bf2f(kx.y) + q2 * bf2f(kx.z) + q3 * bf2f(kx.w);
        p += __shfl_xor(p, 1); p += __shfl_xor(p, 2); p += __shfl_xor(p, 4);
        chain_update(p * SCALE_QK, vx, m[c], l[c], a[c][0], a[c][1], a[c][2], a[c][3]);
    }

    // merge 4 chains in-register
    float ms = fmaxf(fmaxf(m[0], m[1]), fmaxf(m[2], m[3]));
    float A0 = 0.f, A1 = 0.f, A2 = 0.f, A3 = 0.f, L = 0.f;
    if (ms > -INFINITY) {
#pragma unroll
        for (int c = 0; c < 4; ++c) {
            float w = __expf(m[c] - ms);
            A0 += a[c][0] * w; A1 += a[c][1] * w;
            A2 += a[c][2] * w; A3 += a[c][3] * w;
            L += l[c] * w;
        }
    }
    float inv = (L > 0.f) ? 1.f / L : 0.f;
    g0 = A0 * inv; g1 = A1 * inv; g2 = A2 * inv; g3 = A3 * inv;
}

// Wave-level LN (no LDS): x_j for 4 features/lane, full-wave reduce.
__device__ __forceinline__ void wave_ln_store(
    float x0, float x1, float x2, float x3,
    const float* __restrict__ g, const float* __restrict__ b,
    float* __restrict__ out, unsigned short* __restrict__ out_bf,
    int du, int lo)
{
    float s1 = x0 + x1 + x2 + x3;
    float s2 = x0 * x0 + x1 * x1 + x2 * x2 + x3 * x3;
#pragma unroll
    for (int o = 1; o < 64; o <<= 1) {
        s1 += __shfl_xor(s1, o);
        s2 += __shfl_xor(s2, o);
    }
    float mu = s1 * (1.f / 256.f);
    float var = fmaxf(s2 * (1.f / 256.f) - mu * mu, 0.f);
    float rs = rsqrtf(var + LNEPS);
    float4 gv = *(const float4*)(g + lo);
    float4 bv = *(const float4*)(b + lo);
    float y0 = (x0 - mu) * rs * gv.x + bv.x;
    float y1 = (x1 - mu) * rs * gv.y + bv.y;
    float y2 = (x2 - mu) * rs * gv.z + bv.z;
    float y3 = (x3 - mu) * rs * gv.w + bv.w;
    *(float4*)(out + (size_t)du * 256 + lo) = make_float4(y0, y1, y2, y3);
    if (out_bf) {
        ushort4 t; t.x = f2bf(y0); t.y = f2bf(y1); t.z = f2bf(y2); t.w = f2bf(y3);
        *(ushort4*)(out_bf + (size_t)du * 256 + lo) = t;
    }
}

__global__ __launch_bounds__(256) void agg_gm_kernel(
    const unsigned short* __restrict__ Q, const unsigned short* __restrict__ KV,
    const int* __restrict__ offs, const int* __restrict__ cnt,
    const int* __restrict__ srcs, unsigned short* __restrict__ gm, int N)
{
    int lane = threadIdx.x & 63, wv = threadIdx.x >> 6;
    int d = blockIdx.x * 4 + wv;
    if (d >= N) return;
    int du = __builtin_amdgcn_readfirstlane(d);
    float g0, g1, g2, g3;
    wave_attn_node(Q, KV, offs, cnt, srcs, du, lane, g0, g1, g2, g3);
    ushort4 t; t.x = f2bf(g0); t.y = f2bf(g1); t.z = f2bf(g2); t.w = f2bf(g3);
    *(ushort4*)(gm + (size_t)du * 256 + lane * 4) = t;
}

__global__ __launch_bounds__(256) void agg_ln_kernel(
    const unsigned short* __restrict__ Q, const unsigned short* __restrict__ KV,
    const int* __restrict__ offs, const int* __restrict__ cnt,
    const int* __restrict__ srcs, const float* __restrict__ feat,
    const float* __restrict__ g, const float* __restrict__ b,
    float* __restrict__ out, int N)
{
    int lane = threadIdx.x & 63, wv = threadIdx.x >> 6;
    int d = blockIdx.x * 4 + wv;
    if (d >= N) return;
    int du = __builtin_amdgcn_readfirstlane(d);
    int lo = lane * 4;
    float g0, g1, g2, g3;
    wave_attn_node(Q, KV, offs, cnt, srcs, du, lane, g0, g1, g2, g3);
    float4 fv = *(const float4*)(feat + (size_t)du * 256 + lo);
    float x0 = fv.x + gelu_exact(g0);
    float x1 = fv.y + gelu_exact(g1);
    float x2 = fv.z + gelu_exact(g2);
    float x3 = fv.w + gelu_exact(g3);
    wave_ln_store(x0, x1, x2, x3, g, b, out, nullptr, du, lo);
}

__global__ __launch_bounds__(256) void gene_fusion_kernel(
    const float* __restrict__ gene_feat, const unsigned short* __restrict__ gm_d,
    const unsigned short* __restrict__ gm_s, const float* __restrict__ e1,
    const float* __restrict__ e2, const int* __restrict__ cnt_d,
    const int* __restrict__ cnt_s, const float* __restrict__ g,
    const float* __restrict__ b, float* __restrict__ out,
    unsigned short* __restrict__ out_bf)
{
    int lane = threadIdx.x & 63, wv = threadIdx.x >> 6;
    int d = blockIdx.x * 4 + wv;
    if (d >= NG) return;
    int du = __builtin_amdgcn_readfirstlane(d);
    int lo = lane * 4;
    ushort4 v1 = *(const ushort4*)(gm_d + (size_t)du * 256 + lo);
    ushort4 v2 = *(const ushort4*)(gm_s + (size_t)du * 256 + lo);
    bool hd = cnt_d[du] > 0, hs = cnt_s[du] > 0;
    float wa, wb;
    if (hd && hs) {
        float aa = e1[du], bb = e2[du];
        float mm = fmaxf(aa, bb);   // softmax([e1+bv,e2+bv]) == softmax([e1,e2])
        float ea = __expf(aa - mm), eb = __expf(bb - mm);
        float inv = 1.f / (ea + eb);
        wa = ea * inv; wb = eb * inv;
    } else if (hd) { wa = 1.f; wb = 0.f; }
    else if (hs) { wa = 0.f; wb = 1.f; }
    else { wa = 0.f; wb = 0.f; }
    float m0 = wa * bf2f(v1.x) + wb * bf2f(v2.x);
    float m1 = wa * bf2f(v1.y) + wb * bf2f(v2.y);
    float m2 = wa * bf2f(v1.z) + wb * bf2f(v2.z);
    float m3 = wa * bf2f(v1.w) + wb * bf2f(v2.w);
    float4 fv = *(const float4*)(gene_feat + (size_t)du * 256 + lo);
    float x0 = fv.x + gelu_exact(m0);
    float x1 = fv.y + gelu_exact(m1);
    float x2 = fv.z + gelu_exact(m2);
    float x3 = fv.w + gelu_exact(m3);
    wave_ln_store(x0, x1, x2, x3, g, b, out, out_bf, du, lo);
}

// ---------------------------------------------------------------------------
extern "C" void kernel_launch(void* const* d_in, const int* in_sizes, int n_in,
                              void* d_out, int out_size, void* d_ws, size_t ws_size,
                              hipStream_t stream)
{
    float* out_f32 = (float*)d_out;

    const float* gene_feat    = (const float*)d_in[0];
    const float* drug_feat    = (const float*)d_in[1];
    const float* disease_feat = (const float*)d_in[2];
    const float* dg_Wq = (const float*)d_in[3];
    const float* dg_bq = (const float*)d_in[4];
    const float* dg_Wk = (const float*)d_in[5];
    const float* dg_bk = (const float*)d_in[6];
    const float* dg_Wv = (const float*)d_in[7];
    const float* dg_bv = (const float*)d_in[8];
    const float* disg_Wq = (const float*)d_in[9];
    const float* disg_bq = (const float*)d_in[10];
    const float* disg_Wk = (const float*)d_in[11];
    const float* disg_bk = (const float*)d_in[12];
    const float* disg_Wv = (const float*)d_in[13];
    const float* disg_bv = (const float*)d_in[14];
    const float* gd_Wq = (const float*)d_in[15];
    const float* gd_bq = (const float*)d_in[16];
    const float* gd_Wk = (const float*)d_in[17];
    const float* gd_bk = (const float*)d_in[18];
    const float* gd_Wv = (const float*)d_in[19];
    const float* gd_bv = (const float*)d_in[20];
    const float* gdis_Wq = (const float*)d_in[21];
    const float* gdis_bq = (const float*)d_in[22];
    const float* gdis_Wk = (const float*)d_in[23];
    const float* gdis_bk = (const float*)d_in[24];
    const float* gdis_Wv = (const float*)d_in[25];
    const float* gdis_bv = (const float*)d_in[26];
    const float* f_W1 = (const float*)d_in[27];
    const float* f_b1 = (const float*)d_in[28];
    const float* f_W2 = (const float*)d_in[29];
    const float* f_b2 = (const float*)d_in[30];
    const float* f_v  = (const float*)d_in[31];
    const float* ln1_g = (const float*)d_in[33];
    const float* ln1_b = (const float*)d_in[34];
    const float* ln2_g = (const float*)d_in[35];
    const float* ln2_b = (const float*)d_in[36];
    const int* dg_src   = (const int*)d_in[37];
    const int* dg_dst   = (const int*)d_in[38];
    const int* disg_src = (const int*)d_in[39];
    const int* disg_dst = (const int*)d_in[40];
    const int* gd_src   = (const int*)d_in[41];
    const int* gd_dst   = (const int*)d_in[42];
    const int* gdis_src = (const int*)d_in[43];
    const int* gdis_dst = (const int*)d_in[44];

    // ---- workspace ----
    char* ws = (char*)d_ws;
    size_t off = 0;
    auto alloc = [&](size_t bytes) -> char* {
        char* p = ws + off;
        off += (bytes + 511) & ~(size_t)511;
        return p;
    };
    // zero region start
    int* cnt_dg   = (int*)alloc(NG * 4);
    int* cnt_disg = (int*)alloc(NG * 4);
    int* cnt_gd   = (int*)alloc(ND * 4);
    int* cnt_gdis = (int*)alloc(NS * 4);
    int* cur_dg   = (int*)alloc(NG * 4);
    int* cur_disg = (int*)alloc(NG * 4);
    int* cur_gd   = (int*)alloc(ND * 4);
    int* cur_gdis = (int*)alloc(NS * 4);
    float* e1 = (float*)alloc(NG * 4);
    float* e2 = (float*)alloc(NG * 4);
    size_t zero_len = off;   // bytes to zero each call
    int* offs_dg   = (int*)alloc(NG * 4);
    int* offs_disg = (int*)alloc(NG * 4);
    int* offs_gd   = (int*)alloc(ND * 4);
    int* offs_gdis = (int*)alloc(NS * 4);
    int* srcs_dg   = (int*)alloc((size_t)EE * 4);
    int* srcs_disg = (int*)alloc((size_t)EE * 4);
    int* srcs_gd   = (int*)alloc((size_t)EE * 4);
    int* srcs_gdis = (int*)alloc((size_t)EE * 4);
    unsigned short* Qb   = (unsigned short*)alloc((size_t)NG * 256 * 2);
    unsigned short* KVb  = (unsigned short*)alloc((size_t)NG * 512 * 2);
    unsigned short* gm_d = (unsigned short*)alloc((size_t)NG * 256 * 2);
    unsigned short* gm_s = (unsigned short*)alloc((size_t)NG * 256 * 2);
    unsigned short* gene_bf = (unsigned short*)alloc((size_t)NG * 256 * 2);
    unsigned short* drug_bf = (unsigned short*)alloc((size_t)ND * 256 * 2);
    unsigned short* dis_bf  = (unsigned short*)alloc((size_t)NS * 256 * 2);
    unsigned short* Wbf     = (unsigned short*)alloc((size_t)14 * 65536 * 2);
    size_t need = off;

    // gm_d is dead after gene_fusion_kernel -> reuse as bf16 gene_out
    unsigned short* gene_out_bf = gm_d;

    float* out_drug = out_f32;                       // [8000, 256]
    float* out_dis  = out_drug + (size_t)ND * 256;   // [8000, 256]
    float* out_gene = out_dis + (size_t)NS * 256;    // [20000, 256]

    if (ws_size < need) {   // sentinel: 1000.0f
        fillf_kernel<<<(out_size + 255) / 256, 256, 0, stream>>>(out_f32, out_size, 1000.0f);
        return;
    }

    zero_kernel<<<((int)(zero_len / 4) + 255) / 256, 256, 0, stream>>>(
        (int*)d_ws, (int)(zero_len / 4));

    // ---- bf16 pre-conversion (weights + input features) ----
    {
        WSrc s;
        const float* wl[14] = {dg_Wq, dg_Wk, dg_Wv, disg_Wq, disg_Wk, disg_Wv,
                               gd_Wq, gd_Wk, gd_Wv, gdis_Wq, gdis_Wk, gdis_Wv,
                               f_W1, f_W2};
        for (int i = 0; i < 14; ++i) s.p[i] = wl[i];
        convert_w_kernel<<<(14 * 16384) / 256, 256, 0, stream>>>(s, Wbf);
    }
    convert_feat_kernel<<<((NG + ND + NS) * 64 + 255) / 256, 256, 0, stream>>>(
        gene_feat, drug_feat, disease_feat, gene_bf, drug_bf, dis_bf);

    // ---- CSR build for all 4 graphs (fused dispatches) ----
    {
        Cnt4 c;
        c.dst[0] = dg_dst; c.dst[1] = disg_dst; c.dst[2] = gd_dst; c.dst[3] = gdis_dst;
        c.cnt[0] = cnt_dg; c.cnt[1] = cnt_disg; c.cnt[2] = cnt_gd; c.cnt[3] = cnt_gdis;
        count4_kernel<<<(4 * EE + 255) / 256, 256, 0, stream>>>(c);
    }
    scan4_kernel<<<4, 256, 0, stream>>>(cnt_dg, offs_dg, NG, cnt_disg, offs_disg, NG,
                                        cnt_gd, offs_gd, ND, cnt_gdis, offs_gdis, NS);
    {
        Sc4 s;
        s.src[0] = dg_src; s.src[1] = disg_src; s.src[2] = gd_src; s.src[3] = gdis_src;
        s.dst[0] = dg_dst; s.dst[1] = disg_dst; s.dst[2] = gd_dst; s.dst[3] = gdis_dst;
        s.offs[0] = offs_dg; s.offs[1] = offs_disg; s.offs[2] = offs_gd; s.offs[3] = offs_gdis;
        s.cur[0] = cur_dg; s.cur[1] = cur_disg; s.cur[2] = cur_gd; s.cur[3] = cur_gdis;
        s.srcs[0] = srcs_dg; s.srcs[1] = srcs_disg; s.srcs[2] = srcs_gd; s.srcs[3] = srcs_gdis;
        scatter4_kernel<<<(4 * EE + 255) / 256, 256, 0, stream>>>(s);
    }

    // Q GEMM (N=256) and fused K|V GEMM (N=512, Wk & Wv contiguous in Wbf)
    auto gemmQ = [&](const unsigned short* A, int widx, const float* bias,
                     unsigned short* C, int M) {
        dim3 g((M + 127) / 128, 4);
        gemm_nt<0><<<g, 256, 0, stream>>>(A, Wbf + (size_t)widx * 65536,
                                          bias, bias, C, 256, nullptr, nullptr, M);
    };
    auto gemmKV = [&](const unsigned short* A, int widx, const float* bk,
                      const float* bv, int M) {
        dim3 g((M + 127) / 128, 8);
        gemm_nt<0><<<g, 256, 0, stream>>>(A, Wbf + (size_t)widx * 65536,
                                          bk, bv, KVb, 512, nullptr, nullptr, M);
    };

    // ---- stage 1: drug->gene ----
    gemmQ(gene_bf, 0, dg_bq, Qb, NG);
    gemmKV(drug_bf, 1, dg_bk, dg_bv, ND);
    agg_gm_kernel<<<(NG + 3) / 4, 256, 0, stream>>>(Qb, KVb, offs_dg, cnt_dg,
                                                    srcs_dg, gm_d, NG);

    // ---- stage 1: disease->gene ----
    gemmQ(gene_bf, 3, disg_bq, Qb, NG);
    gemmKV(dis_bf, 4, disg_bk, disg_bv, NS);
    agg_gm_kernel<<<(NG + 3) / 4, 256, 0, stream>>>(Qb, KVb, offs_disg, cnt_disg,
                                                    srcs_disg, gm_s, NG);

    // ---- Bahdanau fusion + LN1 -> gene_out (fp32 + bf16 copy) ----
    {
        dim3 gb((NG + 127) / 128, 4);
        gemm_nt<1><<<gb, 256, 0, stream>>>(gm_d, Wbf + (size_t)12 * 65536, f_b1, f_b1,
                                           nullptr, 256, f_v, e1, NG);
        gemm_nt<1><<<gb, 256, 0, stream>>>(gm_s, Wbf + (size_t)13 * 65536, f_b2, f_b2,
                                           nullptr, 256, f_v, e2, NG);
    }
    gene_fusion_kernel<<<(NG + 3) / 4, 256, 0, stream>>>(
        gene_feat, gm_d, gm_s, e1, e2, cnt_dg, cnt_disg, ln1_g, ln1_b,
        out_gene, gene_out_bf);

    // ---- stage 2: gene->drug ----
    gemmQ(drug_bf, 6, gd_bq, Qb, ND);
    gemmKV(gene_out_bf, 7, gd_bk, gd_bv, NG);
    agg_ln_kernel<<<(ND + 3) / 4, 256, 0, stream>>>(Qb, KVb, offs_gd, cnt_gd, srcs_gd,
                                                    drug_feat, ln2_g, ln2_b, out_drug, ND);

    // ---- stage 2: gene->disease ----
    gemmQ(dis_bf, 9, gdis_bq, Qb, NS);
    gemmKV(gene_out_bf, 10, gdis_bk, gdis_bv, NG);
    agg_ln_kernel<<<(NS + 3) / 4, 256, 0, stream>>>(Qb, KVb, offs_gdis, cnt_gdis, srcs_gdis,
                                                    disease_feat, ln2_g, ln2_b, out_dis, NS);
}

// Round 3
// 615.351 us; speedup vs baseline: 1.6380x; 1.0263x over previous
//
#include <hip/hip_runtime.h>

#define NG 20000
#define ND 8000
#define NS 8000
#define EE 300000
#define DIM 256
#define SCALE_QK 0.17677669529663687f  // 1/sqrt(32)
#define LNEPS 1e-5f

#define SCH 4096                       // edges per scatter chunk
#define NC ((EE + SCH - 1) / SCH)      // chunks per graph (74)

typedef __attribute__((ext_vector_type(4))) float floatx4;
typedef __attribute__((ext_vector_type(8))) short shortx8;
typedef __attribute__((ext_vector_type(8))) unsigned short ushortx8;

__device__ __forceinline__ float bf2f(unsigned short u) {
    union { unsigned u; float f; } c; c.u = ((unsigned)u) << 16; return c.f;
}
__device__ __forceinline__ unsigned short f2bf(float f) {
    union { float f; unsigned u; } c; c.f = f;
    return (unsigned short)((c.u + 0x7fffu + ((c.u >> 16) & 1u)) >> 16);
}
__device__ __forceinline__ float gelu_exact(float v) {
    return 0.5f * v * (1.0f + erff(v * 0.70710678118654752f));
}

// ---------------------------------------------------------------------------
// MFMA GEMM: C[M, NCOLS] = A[M,256] @ W[NCOLS,256]^T + bias
// A bf16, W bf16 (pre-converted), bias fp32, C bf16 (row stride ldc).
// Columns n<256 use bias1[n]; n>=256 use bias2[n-256] (for fused K|V GEMM).
// KVI=1: write KV-interleaved layout: dim d of K -> (d>>2)*8 + (d&3),
//        dim d of V -> (d>>2)*8 + 4 + (d&3)  (so one 16B load gets K+V chunk).
// MODE 0: store bf16 C.  MODE 1: Bahdanau epilogue e[m] += sum_n v[n]*tanh(C+b)
// Tile 128m x 64n, BK=32, 256 threads (4 waves; wave -> 32 m-rows).
// ---------------------------------------------------------------------------
template <int MODE, int KVI>
__global__ __launch_bounds__(256, 2) void gemm_nt(
    const unsigned short* __restrict__ A, const unsigned short* __restrict__ W,
    const float* __restrict__ bias1, const float* __restrict__ bias2,
    unsigned short* __restrict__ C, int ldc,
    const float* __restrict__ vvec, float* __restrict__ evec, int M)
{
    __shared__ unsigned short As[128][40];  // 40 shorts = 80 B rows (16B-aligned)
    __shared__ unsigned short Bs[64][40];
    const int tid = threadIdx.x;
    const int lane = tid & 63, wv = tid >> 6;
    const int quad = lane >> 4, l16 = lane & 15;
    const int m0 = blockIdx.x * 128;
    const int n0 = blockIdx.y * 64;

    floatx4 acc[2][4];
#pragma unroll
    for (int i = 0; i < 2; ++i)
#pragma unroll
        for (int j = 0; j < 4; ++j) acc[i][j] = (floatx4){0.f, 0.f, 0.f, 0.f};

    const int sr = tid >> 2;         // 0..63
    const int sc = (tid & 3) * 8;    // 0,8,16,24

    for (int k0 = 0; k0 < 256; k0 += 32) {
        __syncthreads();
        // B tile: row = output col n0+sr (bf16 direct copy)
        *(int4*)(&Bs[sr][sc]) =
            *(const int4*)(W + (size_t)(n0 + sr) * 256 + k0 + sc);
#pragma unroll
        for (int rr = 0; rr < 2; ++rr) {  // A tile: 128 rows
            int row = sr + rr * 64;
            int gm = m0 + row;
            int4 av = make_int4(0, 0, 0, 0);
            if (gm < M)
                av = *(const int4*)(A + (size_t)gm * 256 + k0 + sc);
            *(int4*)(&As[row][sc]) = av;
        }
        __syncthreads();
        shortx8 af[2], bfr[4];
#pragma unroll
        for (int mf = 0; mf < 2; ++mf)
            af[mf] = *(const shortx8*)(&As[wv * 32 + mf * 16 + l16][quad * 8]);
#pragma unroll
        for (int nf = 0; nf < 4; ++nf)
            bfr[nf] = *(const shortx8*)(&Bs[nf * 16 + l16][quad * 8]);
#pragma unroll
        for (int mf = 0; mf < 2; ++mf)
#pragma unroll
            for (int nf = 0; nf < 4; ++nf)
                acc[mf][nf] = __builtin_amdgcn_mfma_f32_16x16x32_bf16(
                    af[mf], bfr[nf], acc[mf][nf], 0, 0, 0);
    }

    if (MODE == 0) {
#pragma unroll
        for (int mf = 0; mf < 2; ++mf)
#pragma unroll
            for (int r = 0; r < 4; ++r) {
                int m = m0 + wv * 32 + mf * 16 + quad * 4 + r;
                if (m < M) {
#pragma unroll
                    for (int nf = 0; nf < 4; ++nf) {
                        int n = n0 + nf * 16 + l16;
                        float bn = (n < 256) ? bias1[n] : bias2[n - 256];
                        int pos;
                        if (KVI) {
                            int nn = n & 255;
                            pos = ((nn >> 2) << 3) + (n & 3) + ((n >> 8) << 2);
                        } else {
                            pos = n;
                        }
                        C[(size_t)m * ldc + pos] = f2bf(acc[mf][nf][r] + bn);
                    }
                }
            }
    } else {
        float p[2][4] = {};
#pragma unroll
        for (int mf = 0; mf < 2; ++mf)
#pragma unroll
            for (int nf = 0; nf < 4; ++nf) {
                int n = n0 + nf * 16 + l16;
                float vn = vvec[n];
                float bn = bias1[n];
#pragma unroll
                for (int r = 0; r < 4; ++r)
                    p[mf][r] += vn * tanhf(acc[mf][nf][r] + bn);
            }
#pragma unroll
        for (int mf = 0; mf < 2; ++mf)
#pragma unroll
            for (int r = 0; r < 4; ++r) {
                float s = p[mf][r];
                s += __shfl_xor(s, 1); s += __shfl_xor(s, 2);
                s += __shfl_xor(s, 4); s += __shfl_xor(s, 8);
                if (l16 == 0) {
                    int m = m0 + wv * 32 + mf * 16 + quad * 4 + r;
                    if (m < M) atomicAdd(&evec[m], s);
                }
            }
    }
}

// ---------------------------------------------------------------------------
// bf16 pre-conversion
// ---------------------------------------------------------------------------
struct WSrc { const float* p[14]; };

__global__ void convert_w_kernel(WSrc s, unsigned short* __restrict__ out) {
    int idx = blockIdx.x * 256 + threadIdx.x;       // 14*16384 items
    int mat = idx >> 14;
    int e = (idx & 16383) << 2;
    float4 f = *(const float4*)(s.p[mat] + e);
    ushort4 t;
    t.x = f2bf(f.x); t.y = f2bf(f.y); t.z = f2bf(f.z); t.w = f2bf(f.w);
    *(ushort4*)(out + ((size_t)mat << 16) + e) = t;
}

__global__ void convert_feat_kernel(
    const float* __restrict__ gf, const float* __restrict__ df,
    const float* __restrict__ sf, unsigned short* __restrict__ go,
    unsigned short* __restrict__ dougo, unsigned short* __restrict__ so)
{
    const int NG4 = NG * 64, ND4 = ND * 64, NS4 = NS * 64;
    int i = blockIdx.x * 256 + threadIdx.x;
    const float* in; unsigned short* out; int j;
    if (i < NG4) { in = gf; out = go; j = i; }
    else if (i < NG4 + ND4) { in = df; out = dougo; j = i - NG4; }
    else if (i < NG4 + ND4 + NS4) { in = sf; out = so; j = i - NG4 - ND4; }
    else return;
    float4 f = *(const float4*)(in + (size_t)j * 4);
    ushort4 t;
    t.x = f2bf(f.x); t.y = f2bf(f.y); t.z = f2bf(f.z); t.w = f2bf(f.w);
    *(ushort4*)(out + (size_t)j * 4) = t;
}

// ---------------------------------------------------------------------------
// Utility + CSR build
// ---------------------------------------------------------------------------
__global__ void zero_kernel(int* __restrict__ p, int n) {
    int i = blockIdx.x * blockDim.x + threadIdx.x;
    if (i < n) p[i] = 0;
}
__global__ void fillf_kernel(float* __restrict__ p, int n, float v) {
    int i = blockIdx.x * blockDim.x + threadIdx.x;
    if (i < n) p[i] = v;
}

// count + rank capture: rank[e] = old counter value (edge's slot within dst)
struct Cnt4 {
    const int* dst[4];
    int* cnt[4];
    int* rank[4];
};
__global__ void count4_kernel(Cnt4 a) {
    int i = blockIdx.x * 256 + threadIdx.x;
    if (i >= 4 * EE) return;
    int g = i / EE, e = i - g * EE;
    int old = atomicAdd(&a.cnt[g][a.dst[g][e]], 1);
    a.rank[g][e] = old;
}

// Partitioned, atomic-free scatter. partition = blockIdx.x & 7 (XCD-affine
// under round-robin dispatch): all writes of a partition go to a contiguous
// ~EE/8 slice of srcs -> L2-resident, full-line writebacks.
struct Sc4 {
    const int* src[4];
    const int* dst[4];
    const int* rank[4];
    const int* offs[4];
    int* srcs[4];
    int nrange[4];      // ceil(N/8) per graph
};
__global__ void scatter4_kernel(Sc4 a) {
    int p = blockIdx.x & 7;
    int blk = blockIdx.x >> 3;          // 0 .. 4*NC-1
    int g = blk / NC, c = blk - g * NC;
    int base = c * SCH;
    int end = base + SCH; if (end > EE) end = EE;
    const int* __restrict__ dstp = a.dst[g];
    const int* __restrict__ srcp = a.src[g];
    const int* __restrict__ rnk  = a.rank[g];
    const int* __restrict__ ofs  = a.offs[g];
    int* __restrict__ out = a.srcs[g];
    int lo = p * a.nrange[g], hi = lo + a.nrange[g];
    for (int e = base + (int)threadIdx.x; e < end; e += 256) {
        int d = dstp[e];
        if (d >= lo && d < hi)
            out[ofs[d] + rnk[e]] = srcp[e];
    }
}

// Fast single-block exclusive scan: segment per thread, no per-chunk barriers.
__device__ void block_exscan(const int* __restrict__ cnt, int* __restrict__ offs, int n) {
    __shared__ int ws4[4];
    int t = threadIdx.x, lane = t & 63, wv = t >> 6;
    int seg = (n + 255) >> 8;
    int beg = t * seg;
    int end = beg + seg; if (end > n) end = n;
    int sum = 0;
#pragma unroll 4
    for (int i = beg; i < end; ++i) sum += cnt[i];
    int x = sum;
#pragma unroll
    for (int o = 1; o < 64; o <<= 1) {
        int u = __shfl_up(x, o);
        if (lane >= o) x += u;
    }
    if (lane == 63) ws4[wv] = x;
    __syncthreads();
    int woff = 0;
    for (int w = 0; w < wv; ++w) woff += ws4[w];
    int run = woff + x - sum;   // exclusive prefix of this thread's segment
#pragma unroll 4
    for (int i = beg; i < end; ++i) { offs[i] = run; run += cnt[i]; }
}
__global__ void scan4_kernel(const int* c0, int* o0, int n0, const int* c1, int* o1, int n1,
                             const int* c2, int* o2, int n2, const int* c3, int* o3, int n3) {
    if (blockIdx.x == 0) block_exscan(c0, o0, n0);
    else if (blockIdx.x == 1) block_exscan(c1, o1, n1);
    else if (blockIdx.x == 2) block_exscan(c2, o2, n2);
    else block_exscan(c3, o3, n3);
}

// ---------------------------------------------------------------------------
// Fused CSR aggregation — ONE WAVE PER NODE (4 nodes/block, no LDS/barriers).
// KV interleaved per 4 dims: one 16B load/lane yields both K-chunk (dims
// lane*4..+3 at [0:4]) and V-chunk (same dims at [4:8]).
// 8 independent online-softmax chains (edge i -> chain i&7) with masked tail,
// merged in-register at the end. Head h = lanes 8h..8h+7 -> 3-shfl dot reduce.
// ---------------------------------------------------------------------------
__device__ __forceinline__ void wave_attn_node(
    const unsigned short* __restrict__ Q, const unsigned short* __restrict__ KV,
    const int* __restrict__ offs, const int* __restrict__ cnt,
    const int* __restrict__ srcs, int du, int lane,
    float& g0, float& g1, float& g2, float& g3)
{
    const int lo = lane * 4;
    const int lofs = lane * 8;
    ushort4 qv = *(const ushort4*)(Q + (size_t)du * 256 + lo);
    const float q0 = bf2f(qv.x), q1 = bf2f(qv.y), q2 = bf2f(qv.z), q3 = bf2f(qv.w);
    const int beg = offs[du], num = cnt[du];

    float m[8], l[8], a[8][4];
#pragma unroll
    for (int c = 0; c < 8; ++c) {
        m[c] = -INFINITY; l[c] = 0.f;
        a[c][0] = a[c][1] = a[c][2] = a[c][3] = 0.f;
    }

    for (int i = 0; i < num; i += 8) {
        ushortx8 kv[8];
#pragma unroll
        for (int c = 0; c < 8; ++c) {
            int idx = i + c;
            int cidx = (idx < num) ? idx : (num - 1);   // clamped (masked later)
            int s = srcs[beg + cidx];
            kv[c] = *(const ushortx8*)(KV + (size_t)s * 512 + lofs);
        }
        float p[8];
#pragma unroll
        for (int c = 0; c < 8; ++c)
            p[c] = q0 * bf2f(kv[c][0]) + q1 * bf2f(kv[c][1]) +
                   q2 * bf2f(kv[c][2]) + q3 * bf2f(kv[c][3]);
#pragma unroll
        for (int c = 0; c < 8; ++c) p[c] += __shfl_xor(p[c], 1);
#pragma unroll
        for (int c = 0; c < 8; ++c) p[c] += __shfl_xor(p[c], 2);
#pragma unroll
        for (int c = 0; c < 8; ++c) p[c] += __shfl_xor(p[c], 4);
#pragma unroll
        for (int c = 0; c < 8; ++c) {
            if (i + c < num) {   // wave-uniform branch
                float sc = p[c] * SCALE_QK;
                float mn = fmaxf(m[c], sc);
                float eo = __expf(m[c] - mn);   // first edge: exp(-inf)=0
                float en = __expf(sc - mn);
                a[c][0] = a[c][0] * eo + en * bf2f(kv[c][4]);
                a[c][1] = a[c][1] * eo + en * bf2f(kv[c][5]);
                a[c][2] = a[c][2] * eo + en * bf2f(kv[c][6]);
                a[c][3] = a[c][3] * eo + en * bf2f(kv[c][7]);
                l[c] = l[c] * eo + en;
                m[c] = mn;
            }
        }
    }

    // merge 8 chains in-register
    float ms = fmaxf(fmaxf(fmaxf(m[0], m[1]), fmaxf(m[2], m[3])),
                     fmaxf(fmaxf(m[4], m[5]), fmaxf(m[6], m[7])));
    float A0 = 0.f, A1 = 0.f, A2 = 0.f, A3 = 0.f, L = 0.f;
    if (ms > -INFINITY) {
#pragma unroll
        for (int c = 0; c < 8; ++c) {
            float w = __expf(m[c] - ms);
            A0 += a[c][0] * w; A1 += a[c][1] * w;
            A2 += a[c][2] * w; A3 += a[c][3] * w;
            L += l[c] * w;
        }
    }
    float inv = (L > 0.f) ? 1.f / L : 0.f;
    g0 = A0 * inv; g1 = A1 * inv; g2 = A2 * inv; g3 = A3 * inv;
}

// Wave-level LN (no LDS): x_j for 4 features/lane, full-wave reduce.
__device__ __forceinline__ void wave_ln_store(
    float x0, float x1, float x2, float x3,
    const float* __restrict__ g, const float* __restrict__ b,
    float* __restrict__ out, unsigned short* __restrict__ out_bf,
    int du, int lo)
{
    float s1 = x0 + x1 + x2 + x3;
    float s2 = x0 * x0 + x1 * x1 + x2 * x2 + x3 * x3;
#pragma unroll
    for (int o = 1; o < 64; o <<= 1) {
        s1 += __shfl_xor(s1, o);
        s2 += __shfl_xor(s2, o);
    }
    float mu = s1 * (1.f / 256.f);
    float var = fmaxf(s2 * (1.f / 256.f) - mu * mu, 0.f);
    float rs = rsqrtf(var + LNEPS);
    float4 gv = *(const float4*)(g + lo);
    float4 bv = *(const float4*)(b + lo);
    float y0 = (x0 - mu) * rs * gv.x + bv.x;
    float y1 = (x1 - mu) * rs * gv.y + bv.y;
    float y2 = (x2 - mu) * rs * gv.z + bv.z;
    float y3 = (x3 - mu) * rs * gv.w + bv.w;
    *(float4*)(out + (size_t)du * 256 + lo) = make_float4(y0, y1, y2, y3);
    if (out_bf) {
        ushort4 t; t.x = f2bf(y0); t.y = f2bf(y1); t.z = f2bf(y2); t.w = f2bf(y3);
        *(ushort4*)(out_bf + (size_t)du * 256 + lo) = t;
    }
}

__global__ __launch_bounds__(256) void agg_gm_kernel(
    const unsigned short* __restrict__ Q, const unsigned short* __restrict__ KV,
    const int* __restrict__ offs, const int* __restrict__ cnt,
    const int* __restrict__ srcs, unsigned short* __restrict__ gm, int N)
{
    int lane = threadIdx.x & 63, wv = threadIdx.x >> 6;
    int d = blockIdx.x * 4 + wv;
    if (d >= N) return;
    int du = __builtin_amdgcn_readfirstlane(d);
    float g0, g1, g2, g3;
    wave_attn_node(Q, KV, offs, cnt, srcs, du, lane, g0, g1, g2, g3);
    ushort4 t; t.x = f2bf(g0); t.y = f2bf(g1); t.z = f2bf(g2); t.w = f2bf(g3);
    *(ushort4*)(gm + (size_t)du * 256 + lane * 4) = t;
}

__global__ __launch_bounds__(256) void agg_ln_kernel(
    const unsigned short* __restrict__ Q, const unsigned short* __restrict__ KV,
    const int* __restrict__ offs, const int* __restrict__ cnt,
    const int* __restrict__ srcs, const float* __restrict__ feat,
    const float* __restrict__ g, const float* __restrict__ b,
    float* __restrict__ out, int N)
{
    int lane = threadIdx.x & 63, wv = threadIdx.x >> 6;
    int d = blockIdx.x * 4 + wv;
    if (d >= N) return;
    int du = __builtin_amdgcn_readfirstlane(d);
    int lo = lane * 4;
    float g0, g1, g2, g3;
    wave_attn_node(Q, KV, offs, cnt, srcs, du, lane, g0, g1, g2, g3);
    float4 fv = *(const float4*)(feat + (size_t)du * 256 + lo);
    float x0 = fv.x + gelu_exact(g0);
    float x1 = fv.y + gelu_exact(g1);
    float x2 = fv.z + gelu_exact(g2);
    float x3 = fv.w + gelu_exact(g3);
    wave_ln_store(x0, x1, x2, x3, g, b, out, nullptr, du, lo);
}

__global__ __launch_bounds__(256) void gene_fusion_kernel(
    const float* __restrict__ gene_feat, const unsigned short* __restrict__ gm_d,
    const unsigned short* __restrict__ gm_s, const float* __restrict__ e1,
    const float* __restrict__ e2, const int* __restrict__ cnt_d,
    const int* __restrict__ cnt_s, const float* __restrict__ g,
    const float* __restrict__ b, float* __restrict__ out,
    unsigned short* __restrict__ out_bf)
{
    int lane = threadIdx.x & 63, wv = threadIdx.x >> 6;
    int d = blockIdx.x * 4 + wv;
    if (d >= NG) return;
    int du = __builtin_amdgcn_readfirstlane(d);
    int lo = lane * 4;
    ushort4 v1 = *(const ushort4*)(gm_d + (size_t)du * 256 + lo);
    ushort4 v2 = *(const ushort4*)(gm_s + (size_t)du * 256 + lo);
    bool hd = cnt_d[du] > 0, hs = cnt_s[du] > 0;
    float wa, wb;
    if (hd && hs) {
        float aa = e1[du], bb = e2[du];
        float mm = fmaxf(aa, bb);   // softmax([e1+bv,e2+bv]) == softmax([e1,e2])
        float ea = __expf(aa - mm), eb = __expf(bb - mm);
        float inv = 1.f / (ea + eb);
        wa = ea * inv; wb = eb * inv;
    } else if (hd) { wa = 1.f; wb = 0.f; }
    else if (hs) { wa = 0.f; wb = 1.f; }
    else { wa = 0.f; wb = 0.f; }
    float m0 = wa * bf2f(v1.x) + wb * bf2f(v2.x);
    float m1 = wa * bf2f(v1.y) + wb * bf2f(v2.y);
    float m2 = wa * bf2f(v1.z) + wb * bf2f(v2.z);
    float m3 = wa * bf2f(v1.w) + wb * bf2f(v2.w);
    float4 fv = *(const float4*)(gene_feat + (size_t)du * 256 + lo);
    float x0 = fv.x + gelu_exact(m0);
    float x1 = fv.y + gelu_exact(m1);
    float x2 = fv.z + gelu_exact(m2);
    float x3 = fv.w + gelu_exact(m3);
    wave_ln_store(x0, x1, x2, x3, g, b, out, out_bf, du, lo);
}

// ---------------------------------------------------------------------------
extern "C" void kernel_launch(void* const* d_in, const int* in_sizes, int n_in,
                              void* d_out, int out_size, void* d_ws, size_t ws_size,
                              hipStream_t stream)
{
    float* out_f32 = (float*)d_out;

    const float* gene_feat    = (const float*)d_in[0];
    const float* drug_feat    = (const float*)d_in[1];
    const float* disease_feat = (const float*)d_in[2];
    const float* dg_Wq = (const float*)d_in[3];
    const float* dg_bq = (const float*)d_in[4];
    const float* dg_Wk = (const float*)d_in[5];
    const float* dg_bk = (const float*)d_in[6];
    const float* dg_Wv = (const float*)d_in[7];
    const float* dg_bv = (const float*)d_in[8];
    const float* disg_Wq = (const float*)d_in[9];
    const float* disg_bq = (const float*)d_in[10];
    const float* disg_Wk = (const float*)d_in[11];
    const float* disg_bk = (const float*)d_in[12];
    const float* disg_Wv = (const float*)d_in[13];
    const float* disg_bv = (const float*)d_in[14];
    const float* gd_Wq = (const float*)d_in[15];
    const float* gd_bq = (const float*)d_in[16];
    const float* gd_Wk = (const float*)d_in[17];
    const float* gd_bk = (const float*)d_in[18];
    const float* gd_Wv = (const float*)d_in[19];
    const float* gd_bv = (const float*)d_in[20];
    const float* gdis_Wq = (const float*)d_in[21];
    const float* gdis_bq = (const float*)d_in[22];
    const float* gdis_Wk = (const float*)d_in[23];
    const float* gdis_bk = (const float*)d_in[24];
    const float* gdis_Wv = (const float*)d_in[25];
    const float* gdis_bv = (const float*)d_in[26];
    const float* f_W1 = (const float*)d_in[27];
    const float* f_b1 = (const float*)d_in[28];
    const float* f_W2 = (const float*)d_in[29];
    const float* f_b2 = (const float*)d_in[30];
    const float* f_v  = (const float*)d_in[31];
    const float* ln1_g = (const float*)d_in[33];
    const float* ln1_b = (const float*)d_in[34];
    const float* ln2_g = (const float*)d_in[35];
    const float* ln2_b = (const float*)d_in[36];
    const int* dg_src   = (const int*)d_in[37];
    const int* dg_dst   = (const int*)d_in[38];
    const int* disg_src = (const int*)d_in[39];
    const int* disg_dst = (const int*)d_in[40];
    const int* gd_src   = (const int*)d_in[41];
    const int* gd_dst   = (const int*)d_in[42];
    const int* gdis_src = (const int*)d_in[43];
    const int* gdis_dst = (const int*)d_in[44];

    // ---- workspace ----
    char* ws = (char*)d_ws;
    size_t off = 0;
    auto alloc = [&](size_t bytes) -> char* {
        char* p = ws + off;
        off += (bytes + 511) & ~(size_t)511;
        return p;
    };
    // zero region start
    int* cnt_dg   = (int*)alloc(NG * 4);
    int* cnt_disg = (int*)alloc(NG * 4);
    int* cnt_gd   = (int*)alloc(ND * 4);
    int* cnt_gdis = (int*)alloc(NS * 4);
    float* e1 = (float*)alloc(NG * 4);
    float* e2 = (float*)alloc(NG * 4);
    size_t zero_len = off;   // bytes to zero each call
    int* offs_dg   = (int*)alloc(NG * 4);
    int* offs_disg = (int*)alloc(NG * 4);
    int* offs_gd   = (int*)alloc(ND * 4);
    int* offs_gdis = (int*)alloc(NS * 4);
    int* srcs_dg   = (int*)alloc((size_t)EE * 4);
    int* srcs_disg = (int*)alloc((size_t)EE * 4);
    int* srcs_gd   = (int*)alloc((size_t)EE * 4);
    int* srcs_gdis = (int*)alloc((size_t)EE * 4);
    int* rank_dg   = (int*)alloc((size_t)EE * 4);
    int* rank_disg = (int*)alloc((size_t)EE * 4);
    int* rank_gd   = (int*)alloc((size_t)EE * 4);
    int* rank_gdis = (int*)alloc((size_t)EE * 4);
    unsigned short* Qb   = (unsigned short*)alloc((size_t)NG * 256 * 2);
    unsigned short* KVb  = (unsigned short*)alloc((size_t)NG * 512 * 2);
    unsigned short* gm_d = (unsigned short*)alloc((size_t)NG * 256 * 2);
    unsigned short* gm_s = (unsigned short*)alloc((size_t)NG * 256 * 2);
    unsigned short* gene_bf = (unsigned short*)alloc((size_t)NG * 256 * 2);
    unsigned short* drug_bf = (unsigned short*)alloc((size_t)ND * 256 * 2);
    unsigned short* dis_bf  = (unsigned short*)alloc((size_t)NS * 256 * 2);
    unsigned short* Wbf     = (unsigned short*)alloc((size_t)14 * 65536 * 2);
    size_t need = off;

    // gm_d is dead after gene_fusion_kernel -> reuse as bf16 gene_out
    unsigned short* gene_out_bf = gm_d;

    float* out_drug = out_f32;                       // [8000, 256]
    float* out_dis  = out_drug + (size_t)ND * 256;   // [8000, 256]
    float* out_gene = out_dis + (size_t)NS * 256;    // [20000, 256]

    if (ws_size < need) {   // sentinel: 1000.0f
        fillf_kernel<<<(out_size + 255) / 256, 256, 0, stream>>>(out_f32, out_size, 1000.0f);
        return;
    }

    zero_kernel<<<((int)(zero_len / 4) + 255) / 256, 256, 0, stream>>>(
        (int*)d_ws, (int)(zero_len / 4));

    // ---- bf16 pre-conversion (weights + input features) ----
    {
        WSrc s;
        const float* wl[14] = {dg_Wq, dg_Wk, dg_Wv, disg_Wq, disg_Wk, disg_Wv,
                               gd_Wq, gd_Wk, gd_Wv, gdis_Wq, gdis_Wk, gdis_Wv,
                               f_W1, f_W2};
        for (int i = 0; i < 14; ++i) s.p[i] = wl[i];
        convert_w_kernel<<<(14 * 16384) / 256, 256, 0, stream>>>(s, Wbf);
    }
    convert_feat_kernel<<<((NG + ND + NS) * 64 + 255) / 256, 256, 0, stream>>>(
        gene_feat, drug_feat, disease_feat, gene_bf, drug_bf, dis_bf);

    // ---- CSR build for all 4 graphs ----
    {
        Cnt4 c;
        c.dst[0] = dg_dst; c.dst[1] = disg_dst; c.dst[2] = gd_dst; c.dst[3] = gdis_dst;
        c.cnt[0] = cnt_dg; c.cnt[1] = cnt_disg; c.cnt[2] = cnt_gd; c.cnt[3] = cnt_gdis;
        c.rank[0] = rank_dg; c.rank[1] = rank_disg; c.rank[2] = rank_gd; c.rank[3] = rank_gdis;
        count4_kernel<<<(4 * EE + 255) / 256, 256, 0, stream>>>(c);
    }
    scan4_kernel<<<4, 256, 0, stream>>>(cnt_dg, offs_dg, NG, cnt_disg, offs_disg, NG,
                                        cnt_gd, offs_gd, ND, cnt_gdis, offs_gdis, NS);
    {
        Sc4 s;
        s.src[0] = dg_src; s.src[1] = disg_src; s.src[2] = gd_src; s.src[3] = gdis_src;
        s.dst[0] = dg_dst; s.dst[1] = disg_dst; s.dst[2] = gd_dst; s.dst[3] = gdis_dst;
        s.rank[0] = rank_dg; s.rank[1] = rank_disg; s.rank[2] = rank_gd; s.rank[3] = rank_gdis;
        s.offs[0] = offs_dg; s.offs[1] = offs_disg; s.offs[2] = offs_gd; s.offs[3] = offs_gdis;
        s.srcs[0] = srcs_dg; s.srcs[1] = srcs_disg; s.srcs[2] = srcs_gd; s.srcs[3] = srcs_gdis;
        s.nrange[0] = (NG + 7) / 8; s.nrange[1] = (NG + 7) / 8;
        s.nrange[2] = (ND + 7) / 8; s.nrange[3] = (NS + 7) / 8;
        scatter4_kernel<<<8 * 4 * NC, 256, 0, stream>>>(s);
    }

    // Q GEMM (N=256) and fused K|V GEMM (N=512, Wk & Wv contiguous in Wbf)
    auto gemmQ = [&](const unsigned short* A, int widx, const float* bias,
                     unsigned short* C, int M) {
        dim3 g((M + 127) / 128, 4);
        gemm_nt<0, 0><<<g, 256, 0, stream>>>(A, Wbf + (size_t)widx * 65536,
                                             bias, bias, C, 256, nullptr, nullptr, M);
    };
    auto gemmKV = [&](const unsigned short* A, int widx, const float* bk,
                      const float* bv, int M) {
        dim3 g((M + 127) / 128, 8);
        gemm_nt<0, 1><<<g, 256, 0, stream>>>(A, Wbf + (size_t)widx * 65536,
                                             bk, bv, KVb, 512, nullptr, nullptr, M);
    };

    // ---- stage 1: drug->gene ----
    gemmQ(gene_bf, 0, dg_bq, Qb, NG);
    gemmKV(drug_bf, 1, dg_bk, dg_bv, ND);
    agg_gm_kernel<<<(NG + 3) / 4, 256, 0, stream>>>(Qb, KVb, offs_dg, cnt_dg,
                                                    srcs_dg, gm_d, NG);

    // ---- stage 1: disease->gene ----
    gemmQ(gene_bf, 3, disg_bq, Qb, NG);
    gemmKV(dis_bf, 4, disg_bk, disg_bv, NS);
    agg_gm_kernel<<<(NG + 3) / 4, 256, 0, stream>>>(Qb, KVb, offs_disg, cnt_disg,
                                                    srcs_disg, gm_s, NG);

    // ---- Bahdanau fusion + LN1 -> gene_out (fp32 + bf16 copy) ----
    {
        dim3 gb((NG + 127) / 128, 4);
        gemm_nt<1, 0><<<gb, 256, 0, stream>>>(gm_d, Wbf + (size_t)12 * 65536, f_b1, f_b1,
                                              nullptr, 256, f_v, e1, NG);
        gemm_nt<1, 0><<<gb, 256, 0, stream>>>(gm_s, Wbf + (size_t)13 * 65536, f_b2, f_b2,
                                              nullptr, 256, f_v, e2, NG);
    }
    gene_fusion_kernel<<<(NG + 3) / 4, 256, 0, stream>>>(
        gene_feat, gm_d, gm_s, e1, e2, cnt_dg, cnt_disg, ln1_g, ln1_b,
        out_gene, gene_out_bf);

    // ---- stage 2: gene->drug ----
    gemmQ(drug_bf, 6, gd_bq, Qb, ND);
    gemmKV(gene_out_bf, 7, gd_bk, gd_bv, NG);
    agg_ln_kernel<<<(ND + 3) / 4, 256, 0, stream>>>(Qb, KVb, offs_gd, cnt_gd, srcs_gd,
                                                    drug_feat, ln2_g, ln2_b, out_drug, ND);

    // ---- stage 2: gene->disease ----
    gemmQ(dis_bf, 9, gdis_bq, Qb, NS);
    gemmKV(gene_out_bf, 10, gdis_bk, gdis_bv, NG);
    agg_ln_kernel<<<(NS + 3) / 4, 256, 0, stream>>>(Qb, KVb, offs_gdis, cnt_gdis, srcs_gdis,
                                                    disease_feat, ln2_g, ln2_b, out_dis, NS);
}

// Round 4
// 535.457 us; speedup vs baseline: 1.8824x; 1.1492x over previous
//
#include <hip/hip_runtime.h>

#define NG 20000
#define ND 8000
#define NS 8000
#define EE 300000
#define DIM 256
#define SCALE_QK 0.17677669529663687f  // 1/sqrt(32)
#define LNEPS 1e-5f

#define MAXB 40                        // max buckets per graph
#define L1CH 2048                      // edges per level-1 block
#define NCH1 ((EE + L1CH - 1) / L1CH)  // 147 blocks per graph
// bucket geometry: graphs 0,1 (dst<NG): shift 9 -> 40 buckets, cap 8704
//                  graphs 2,3 (dst<ND/NS): shift 8 -> 32 buckets, cap 10496
#define CB_G 8704
#define CB_S 10496
#define RB_G (40 * CB_G)               // 348160 records
#define RB_S (32 * CB_S)               // 335872 records

typedef __attribute__((ext_vector_type(4))) float floatx4;
typedef __attribute__((ext_vector_type(8))) short shortx8;
typedef __attribute__((ext_vector_type(8))) unsigned short ushortx8;

__device__ __forceinline__ float bf2f(unsigned short u) {
    union { unsigned u; float f; } c; c.u = ((unsigned)u) << 16; return c.f;
}
__device__ __forceinline__ unsigned short f2bf(float f) {
    union { float f; unsigned u; } c; c.f = f;
    return (unsigned short)((c.u + 0x7fffu + ((c.u >> 16) & 1u)) >> 16);
}
__device__ __forceinline__ float gelu_exact(float v) {
    return 0.5f * v * (1.0f + erff(v * 0.70710678118654752f));
}

// ---------------------------------------------------------------------------
// MFMA GEMM: C[M, NCOL] = A[M,256] @ W[NCOL,256]^T + bias
// A bf16, W bf16 (pre-converted), bias fp32 (b1..b4 per 256-col range),
// C bf16 (row stride ldc).
// KVI=1: within each 512-col half, write KV-interleaved: dim d of K ->
//   (d>>2)*8+(d&3), dim d of V -> (d>>2)*8+4+(d&3) (16B load = K+V chunk).
// MODE 0: store bf16 C.  MODE 1: Bahdanau epilogue e[m] += sum_n v[n]*tanh(C+b)
// Tile 128m x 64n, BK=32, 256 threads (4 waves; wave -> 32 m-rows).
// ---------------------------------------------------------------------------
template <int MODE, int KVI>
__global__ __launch_bounds__(256, 2) void gemm_nt(
    const unsigned short* __restrict__ A, const unsigned short* __restrict__ W,
    const float* __restrict__ bias1, const float* __restrict__ bias2,
    const float* __restrict__ bias3, const float* __restrict__ bias4,
    unsigned short* __restrict__ C, int ldc,
    const float* __restrict__ vvec, float* __restrict__ evec, int M)
{
    __shared__ unsigned short As[128][40];  // 40 shorts = 80 B rows (16B-aligned)
    __shared__ unsigned short Bs[64][40];
    const int tid = threadIdx.x;
    const int lane = tid & 63, wv = tid >> 6;
    const int quad = lane >> 4, l16 = lane & 15;
    const int m0 = blockIdx.x * 128;
    const int n0 = blockIdx.y * 64;

    floatx4 acc[2][4];
#pragma unroll
    for (int i = 0; i < 2; ++i)
#pragma unroll
        for (int j = 0; j < 4; ++j) acc[i][j] = (floatx4){0.f, 0.f, 0.f, 0.f};

    const int sr = tid >> 2;         // 0..63
    const int sc = (tid & 3) * 8;    // 0,8,16,24

    for (int k0 = 0; k0 < 256; k0 += 32) {
        __syncthreads();
        // B tile: row = output col n0+sr (bf16 direct copy)
        *(int4*)(&Bs[sr][sc]) =
            *(const int4*)(W + (size_t)(n0 + sr) * 256 + k0 + sc);
#pragma unroll
        for (int rr = 0; rr < 2; ++rr) {  // A tile: 128 rows
            int row = sr + rr * 64;
            int gm = m0 + row;
            int4 av = make_int4(0, 0, 0, 0);
            if (gm < M)
                av = *(const int4*)(A + (size_t)gm * 256 + k0 + sc);
            *(int4*)(&As[row][sc]) = av;
        }
        __syncthreads();
        shortx8 af[2], bfr[4];
#pragma unroll
        for (int mf = 0; mf < 2; ++mf)
            af[mf] = *(const shortx8*)(&As[wv * 32 + mf * 16 + l16][quad * 8]);
#pragma unroll
        for (int nf = 0; nf < 4; ++nf)
            bfr[nf] = *(const shortx8*)(&Bs[nf * 16 + l16][quad * 8]);
#pragma unroll
        for (int mf = 0; mf < 2; ++mf)
#pragma unroll
            for (int nf = 0; nf < 4; ++nf)
                acc[mf][nf] = __builtin_amdgcn_mfma_f32_16x16x32_bf16(
                    af[mf], bfr[nf], acc[mf][nf], 0, 0, 0);
    }

    if (MODE == 0) {
#pragma unroll
        for (int mf = 0; mf < 2; ++mf)
#pragma unroll
            for (int r = 0; r < 4; ++r) {
                int m = m0 + wv * 32 + mf * 16 + quad * 4 + r;
                if (m < M) {
#pragma unroll
                    for (int nf = 0; nf < 4; ++nf) {
                        int n = n0 + nf * 16 + l16;
                        int h = n >> 8;
                        const float* bp = (h == 0) ? bias1 : (h == 1) ? bias2
                                        : (h == 2) ? bias3 : bias4;
                        float bn = bp[n & 255];
                        int pos;
                        if (KVI) {
                            int nn = n & 511;
                            pos = (n & ~511) + ((nn & 255) >> 2) * 8 + (nn & 3) +
                                  ((nn >> 8) << 2);
                        } else {
                            pos = n;
                        }
                        C[(size_t)m * ldc + pos] = f2bf(acc[mf][nf][r] + bn);
                    }
                }
            }
    } else {
        float p[2][4] = {};
#pragma unroll
        for (int mf = 0; mf < 2; ++mf)
#pragma unroll
            for (int nf = 0; nf < 4; ++nf) {
                int n = n0 + nf * 16 + l16;
                float vn = vvec[n];
                float bn = bias1[n];
#pragma unroll
                for (int r = 0; r < 4; ++r)
                    p[mf][r] += vn * tanhf(acc[mf][nf][r] + bn);
            }
#pragma unroll
        for (int mf = 0; mf < 2; ++mf)
#pragma unroll
            for (int r = 0; r < 4; ++r) {
                float s = p[mf][r];
                s += __shfl_xor(s, 1); s += __shfl_xor(s, 2);
                s += __shfl_xor(s, 4); s += __shfl_xor(s, 8);
                if (l16 == 0) {
                    int m = m0 + wv * 32 + mf * 16 + quad * 4 + r;
                    if (m < M) atomicAdd(&evec[m], s);
                }
            }
    }
}

// ---------------------------------------------------------------------------
// bf16 pre-conversion
// ---------------------------------------------------------------------------
struct WSrc { const float* p[14]; };

__global__ void convert_w_kernel(WSrc s, unsigned short* __restrict__ out) {
    int idx = blockIdx.x * 256 + threadIdx.x;       // 14*16384 items
    int mat = idx >> 14;
    int e = (idx & 16383) << 2;
    float4 f = *(const float4*)(s.p[mat] + e);
    ushort4 t;
    t.x = f2bf(f.x); t.y = f2bf(f.y); t.z = f2bf(f.z); t.w = f2bf(f.w);
    *(ushort4*)(out + ((size_t)mat << 16) + e) = t;
}

__global__ void convert_feat_kernel(
    const float* __restrict__ gf, const float* __restrict__ df,
    const float* __restrict__ sf, unsigned short* __restrict__ go,
    unsigned short* __restrict__ dougo, unsigned short* __restrict__ so)
{
    const int NG4 = NG * 64, ND4 = ND * 64, NS4 = NS * 64;
    int i = blockIdx.x * 256 + threadIdx.x;
    const float* in; unsigned short* out; int j;
    if (i < NG4) { in = gf; out = go; j = i; }
    else if (i < NG4 + ND4) { in = df; out = dougo; j = i - NG4; }
    else if (i < NG4 + ND4 + NS4) { in = sf; out = so; j = i - NG4 - ND4; }
    else return;
    float4 f = *(const float4*)(in + (size_t)j * 4);
    ushort4 t;
    t.x = f2bf(f.x); t.y = f2bf(f.y); t.z = f2bf(f.z); t.w = f2bf(f.w);
    *(ushort4*)(out + (size_t)j * 4) = t;
}

// ---------------------------------------------------------------------------
// Utility
// ---------------------------------------------------------------------------
__global__ void zero_kernel(int* __restrict__ p, int n) {
    int i = blockIdx.x * blockDim.x + threadIdx.x;
    if (i < n) p[i] = 0;
}
__global__ void fillf_kernel(float* __restrict__ p, int n, float v) {
    int i = blockIdx.x * blockDim.x + threadIdx.x;
    if (i < n) p[i] = v;
}

// ---------------------------------------------------------------------------
// 2-level CSR build. Level 1: coarse-bucket records with per-block LDS
// histogram; ONE global atomic per (block, nonzero bucket) (~120K total vs
// 1.2M per-edge). Level 2: one block per bucket; LDS fine histogram + scan
// produce cnt/offs densely, then dense scatter into the bucket's CSR slice.
// Record: (dstLocal<<15) | src  (dstLocal<512, src<32768).
// ---------------------------------------------------------------------------
struct L1P {
    const int* src[4];
    const int* dst[4];
    int* brec[4];
    int* bcur;          // [4*MAXB], zeroed before launch
};
__global__ __launch_bounds__(256) void l1_bucket_kernel(L1P a) {
    __shared__ int hist[MAXB];
    int g = blockIdx.x / NCH1, c = blockIdx.x - g * NCH1;
    int base = c * L1CH;
    int tid = threadIdx.x;
    const int shift = (g < 2) ? 9 : 8;
    const int CB = (g < 2) ? CB_G : CB_S;
    const int NB = (g < 2) ? 40 : 32;
    if (tid < NB) hist[tid] = 0;
    __syncthreads();
    const int* __restrict__ dstp = a.dst[g];
    const int* __restrict__ srcp = a.src[g];
    int bk[8], rec[8], lr[8];
#pragma unroll
    for (int j = 0; j < 8; ++j) {
        int e = base + j * 256 + tid;
        bool ok = e < EE;
        int dd = ok ? dstp[e] : 0;
        int ss = ok ? srcp[e] : 0;
        bk[j] = dd >> shift;
        rec[j] = ((dd & ((1 << shift) - 1)) << 15) | ss;
        lr[j] = ok ? atomicAdd(&hist[bk[j]], 1) : -1;
    }
    __syncthreads();
    if (tid < NB) {
        int h = hist[tid];
        if (h > 0) hist[tid] = atomicAdd(&a.bcur[g * MAXB + tid], h);
    }
    __syncthreads();
    int* __restrict__ recp = a.brec[g];
#pragma unroll
    for (int j = 0; j < 8; ++j) {
        if (lr[j] >= 0) {
            int pos = hist[bk[j]] + lr[j];
            if (pos < CB) recp[bk[j] * CB + pos] = rec[j];
        }
    }
}

struct L2P {
    const int* brec[4];
    const int* bcur;
    int* cnt[4];
    int* offs[4];
    int* srcs[4];
};
__global__ __launch_bounds__(256) void l2_csr_kernel(L2P a) {
    __shared__ int hist[512];
    __shared__ int loffs[512];
    __shared__ int cur[512];
    __shared__ int ws2[4];
    __shared__ int bb;
    int bid = blockIdx.x, tid = threadIdx.x;
    int g, b;
    if (bid < 40) { g = 0; b = bid; }
    else if (bid < 80) { g = 1; b = bid - 40; }
    else if (bid < 112) { g = 2; b = bid - 80; }
    else { g = 3; b = bid - 112; }
    const int shift = (g < 2) ? 9 : 8;
    const int BSZ = 1 << shift;
    const int CB = (g < 2) ? CB_G : CB_S;
    const int N = (g < 2) ? NG : ((g == 2) ? ND : NS);
    hist[tid] = 0; hist[256 + tid] = 0;
    if (tid == 0) {
        int s = 0;
        const int* bc = a.bcur + g * MAXB;
        for (int i = 0; i < b; ++i) s += bc[i];
        bb = s;
    }
    __syncthreads();
    int total = a.bcur[g * MAXB + b];
    if (total > CB) total = CB;
    const int* __restrict__ recp = a.brec[g] + b * CB;
    for (int i = tid; i < total; i += 256)
        atomicAdd(&hist[recp[i] >> 15], 1);
    __syncthreads();
    // exclusive scan over 512 bins (upper half zero when BSZ=256)
    int v0 = hist[2 * tid], v1 = hist[2 * tid + 1];
    int s = v0 + v1, x = s;
    int lane = tid & 63, wv = tid >> 6;
#pragma unroll
    for (int o = 1; o < 64; o <<= 1) {
        int u = __shfl_up(x, o);
        if (lane >= o) x += u;
    }
    if (lane == 63) ws2[wv] = x;
    __syncthreads();
    int woff = 0;
    for (int w = 0; w < wv; ++w) woff += ws2[w];
    int excl = woff + x - s;
    loffs[2 * tid] = excl; loffs[2 * tid + 1] = excl + v0;
    cur[2 * tid] = excl;  cur[2 * tid + 1] = excl + v0;
    int base = bb;
    int lo = b << shift;
    for (int i = tid; i < BSZ; i += 256) {
        int d = lo + i;
        if (d < N) {
            a.cnt[g][d] = hist[i];
            a.offs[g][d] = base + loffs[i];
        }
    }
    __syncthreads();
    int* __restrict__ sp = a.srcs[g];
    for (int i = tid; i < total; i += 256) {
        int rec = recp[i];
        int pos = atomicAdd(&cur[rec >> 15], 1);
        sp[base + pos] = rec & 0x7fff;
    }
}

// ---------------------------------------------------------------------------
// Fused CSR aggregation — ONE WAVE PER NODE (4 nodes/block, no LDS/barriers).
// KV interleaved per 4 dims: one 16B load/lane yields both K-chunk and
// V-chunk. 8 independent online-softmax chains, merged in-register.
// Head h = lanes 8h..8h+7 -> 3-shfl dot reduce. Q row stride qs (fused Q).
// ---------------------------------------------------------------------------
__device__ __forceinline__ void wave_attn_node(
    const unsigned short* __restrict__ Q, int qs,
    const unsigned short* __restrict__ KV,
    const int* __restrict__ offs, const int* __restrict__ cnt,
    const int* __restrict__ srcs, int du, int lane,
    float& g0, float& g1, float& g2, float& g3)
{
    const int lo = lane * 4;
    const int lofs = lane * 8;
    ushort4 qv = *(const ushort4*)(Q + (size_t)du * qs + lo);
    const float q0 = bf2f(qv.x), q1 = bf2f(qv.y), q2 = bf2f(qv.z), q3 = bf2f(qv.w);
    const int beg = offs[du], num = cnt[du];

    float m[8], l[8], a[8][4];
#pragma unroll
    for (int c = 0; c < 8; ++c) {
        m[c] = -INFINITY; l[c] = 0.f;
        a[c][0] = a[c][1] = a[c][2] = a[c][3] = 0.f;
    }

    for (int i = 0; i < num; i += 8) {
        ushortx8 kv[8];
#pragma unroll
        for (int c = 0; c < 8; ++c) {
            int idx = i + c;
            int cidx = (idx < num) ? idx : (num - 1);   // clamped (masked later)
            int s = srcs[beg + cidx];
            kv[c] = *(const ushortx8*)(KV + (size_t)s * 512 + lofs);
        }
        float p[8];
#pragma unroll
        for (int c = 0; c < 8; ++c)
            p[c] = q0 * bf2f(kv[c][0]) + q1 * bf2f(kv[c][1]) +
                   q2 * bf2f(kv[c][2]) + q3 * bf2f(kv[c][3]);
#pragma unroll
        for (int c = 0; c < 8; ++c) p[c] += __shfl_xor(p[c], 1);
#pragma unroll
        for (int c = 0; c < 8; ++c) p[c] += __shfl_xor(p[c], 2);
#pragma unroll
        for (int c = 0; c < 8; ++c) p[c] += __shfl_xor(p[c], 4);
#pragma unroll
        for (int c = 0; c < 8; ++c) {
            if (i + c < num) {   // wave-uniform branch
                float sc = p[c] * SCALE_QK;
                float mn = fmaxf(m[c], sc);
                float eo = __expf(m[c] - mn);   // first edge: exp(-inf)=0
                float en = __expf(sc - mn);
                a[c][0] = a[c][0] * eo + en * bf2f(kv[c][4]);
                a[c][1] = a[c][1] * eo + en * bf2f(kv[c][5]);
                a[c][2] = a[c][2] * eo + en * bf2f(kv[c][6]);
                a[c][3] = a[c][3] * eo + en * bf2f(kv[c][7]);
                l[c] = l[c] * eo + en;
                m[c] = mn;
            }
        }
    }

    // merge 8 chains in-register
    float ms = fmaxf(fmaxf(fmaxf(m[0], m[1]), fmaxf(m[2], m[3])),
                     fmaxf(fmaxf(m[4], m[5]), fmaxf(m[6], m[7])));
    float A0 = 0.f, A1 = 0.f, A2 = 0.f, A3 = 0.f, L = 0.f;
    if (ms > -INFINITY) {
#pragma unroll
        for (int c = 0; c < 8; ++c) {
            float w = __expf(m[c] - ms);
            A0 += a[c][0] * w; A1 += a[c][1] * w;
            A2 += a[c][2] * w; A3 += a[c][3] * w;
            L += l[c] * w;
        }
    }
    float inv = (L > 0.f) ? 1.f / L : 0.f;
    g0 = A0 * inv; g1 = A1 * inv; g2 = A2 * inv; g3 = A3 * inv;
}

// Wave-level LN (no LDS): x_j for 4 features/lane, full-wave reduce.
__device__ __forceinline__ void wave_ln_store(
    float x0, float x1, float x2, float x3,
    const float* __restrict__ g, const float* __restrict__ b,
    float* __restrict__ out, unsigned short* __restrict__ out_bf,
    int du, int lo)
{
    float s1 = x0 + x1 + x2 + x3;
    float s2 = x0 * x0 + x1 * x1 + x2 * x2 + x3 * x3;
#pragma unroll
    for (int o = 1; o < 64; o <<= 1) {
        s1 += __shfl_xor(s1, o);
        s2 += __shfl_xor(s2, o);
    }
    float mu = s1 * (1.f / 256.f);
    float var = fmaxf(s2 * (1.f / 256.f) - mu * mu, 0.f);
    float rs = rsqrtf(var + LNEPS);
    float4 gv = *(const float4*)(g + lo);
    float4 bv = *(const float4*)(b + lo);
    float y0 = (x0 - mu) * rs * gv.x + bv.x;
    float y1 = (x1 - mu) * rs * gv.y + bv.y;
    float y2 = (x2 - mu) * rs * gv.z + bv.z;
    float y3 = (x3 - mu) * rs * gv.w + bv.w;
    *(float4*)(out + (size_t)du * 256 + lo) = make_float4(y0, y1, y2, y3);
    if (out_bf) {
        ushort4 t; t.x = f2bf(y0); t.y = f2bf(y1); t.z = f2bf(y2); t.w = f2bf(y3);
        *(ushort4*)(out_bf + (size_t)du * 256 + lo) = t;
    }
}

__global__ __launch_bounds__(256) void agg_gm_kernel(
    const unsigned short* __restrict__ Q, int qs,
    const unsigned short* __restrict__ KV,
    const int* __restrict__ offs, const int* __restrict__ cnt,
    const int* __restrict__ srcs, unsigned short* __restrict__ gm, int N)
{
    int lane = threadIdx.x & 63, wv = threadIdx.x >> 6;
    int d = blockIdx.x * 4 + wv;
    if (d >= N) return;
    int du = __builtin_amdgcn_readfirstlane(d);
    float g0, g1, g2, g3;
    wave_attn_node(Q, qs, KV, offs, cnt, srcs, du, lane, g0, g1, g2, g3);
    ushort4 t; t.x = f2bf(g0); t.y = f2bf(g1); t.z = f2bf(g2); t.w = f2bf(g3);
    *(ushort4*)(gm + (size_t)du * 256 + lane * 4) = t;
}

__global__ __launch_bounds__(256) void agg_ln_kernel(
    const unsigned short* __restrict__ Q, int qs,
    const unsigned short* __restrict__ KV,
    const int* __restrict__ offs, const int* __restrict__ cnt,
    const int* __restrict__ srcs, const float* __restrict__ feat,
    const float* __restrict__ g, const float* __restrict__ b,
    float* __restrict__ out, int N)
{
    int lane = threadIdx.x & 63, wv = threadIdx.x >> 6;
    int d = blockIdx.x * 4 + wv;
    if (d >= N) return;
    int du = __builtin_amdgcn_readfirstlane(d);
    int lo = lane * 4;
    float g0, g1, g2, g3;
    wave_attn_node(Q, qs, KV, offs, cnt, srcs, du, lane, g0, g1, g2, g3);
    float4 fv = *(const float4*)(feat + (size_t)du * 256 + lo);
    float x0 = fv.x + gelu_exact(g0);
    float x1 = fv.y + gelu_exact(g1);
    float x2 = fv.z + gelu_exact(g2);
    float x3 = fv.w + gelu_exact(g3);
    wave_ln_store(x0, x1, x2, x3, g, b, out, nullptr, du, lo);
}

__global__ __launch_bounds__(256) void gene_fusion_kernel(
    const float* __restrict__ gene_feat, const unsigned short* __restrict__ gm_d,
    const unsigned short* __restrict__ gm_s, const float* __restrict__ e1,
    const float* __restrict__ e2, const int* __restrict__ cnt_d,
    const int* __restrict__ cnt_s, const float* __restrict__ g,
    const float* __restrict__ b, float* __restrict__ out,
    unsigned short* __restrict__ out_bf)
{
    int lane = threadIdx.x & 63, wv = threadIdx.x >> 6;
    int d = blockIdx.x * 4 + wv;
    if (d >= NG) return;
    int du = __builtin_amdgcn_readfirstlane(d);
    int lo = lane * 4;
    ushort4 v1 = *(const ushort4*)(gm_d + (size_t)du * 256 + lo);
    ushort4 v2 = *(const ushort4*)(gm_s + (size_t)du * 256 + lo);
    bool hd = cnt_d[du] > 0, hs = cnt_s[du] > 0;
    float wa, wb;
    if (hd && hs) {
        float aa = e1[du], bb = e2[du];
        float mm = fmaxf(aa, bb);   // softmax([e1+bv,e2+bv]) == softmax([e1,e2])
        float ea = __expf(aa - mm), eb = __expf(bb - mm);
        float inv = 1.f / (ea + eb);
        wa = ea * inv; wb = eb * inv;
    } else if (hd) { wa = 1.f; wb = 0.f; }
    else if (hs) { wa = 0.f; wb = 1.f; }
    else { wa = 0.f; wb = 0.f; }
    float m0 = wa * bf2f(v1.x) + wb * bf2f(v2.x);
    float m1 = wa * bf2f(v1.y) + wb * bf2f(v2.y);
    float m2 = wa * bf2f(v1.z) + wb * bf2f(v2.z);
    float m3 = wa * bf2f(v1.w) + wb * bf2f(v2.w);
    float4 fv = *(const float4*)(gene_feat + (size_t)du * 256 + lo);
    float x0 = fv.x + gelu_exact(m0);
    float x1 = fv.y + gelu_exact(m1);
    float x2 = fv.z + gelu_exact(m2);
    float x3 = fv.w + gelu_exact(m3);
    wave_ln_store(x0, x1, x2, x3, g, b, out, out_bf, du, lo);
}

// ---------------------------------------------------------------------------
extern "C" void kernel_launch(void* const* d_in, const int* in_sizes, int n_in,
                              void* d_out, int out_size, void* d_ws, size_t ws_size,
                              hipStream_t stream)
{
    float* out_f32 = (float*)d_out;

    const float* gene_feat    = (const float*)d_in[0];
    const float* drug_feat    = (const float*)d_in[1];
    const float* disease_feat = (const float*)d_in[2];
    const float* dg_Wq = (const float*)d_in[3];
    const float* dg_bq = (const float*)d_in[4];
    const float* dg_Wk = (const float*)d_in[5];
    const float* dg_bk = (const float*)d_in[6];
    const float* dg_Wv = (const float*)d_in[7];
    const float* dg_bv = (const float*)d_in[8];
    const float* disg_Wq = (const float*)d_in[9];
    const float* disg_bq = (const float*)d_in[10];
    const float* disg_Wk = (const float*)d_in[11];
    const float* disg_bk = (const float*)d_in[12];
    const float* disg_Wv = (const float*)d_in[13];
    const float* disg_bv = (const float*)d_in[14];
    const float* gd_Wq = (const float*)d_in[15];
    const float* gd_bq = (const float*)d_in[16];
    const float* gd_Wk = (const float*)d_in[17];
    const float* gd_bk = (const float*)d_in[18];
    const float* gd_Wv = (const float*)d_in[19];
    const float* gd_bv = (const float*)d_in[20];
    const float* gdis_Wq = (const float*)d_in[21];
    const float* gdis_bq = (const float*)d_in[22];
    const float* gdis_Wk = (const float*)d_in[23];
    const float* gdis_bk = (const float*)d_in[24];
    const float* gdis_Wv = (const float*)d_in[25];
    const float* gdis_bv = (const float*)d_in[26];
    const float* f_W1 = (const float*)d_in[27];
    const float* f_b1 = (const float*)d_in[28];
    const float* f_W2 = (const float*)d_in[29];
    const float* f_b2 = (const float*)d_in[30];
    const float* f_v  = (const float*)d_in[31];
    const float* ln1_g = (const float*)d_in[33];
    const float* ln1_b = (const float*)d_in[34];
    const float* ln2_g = (const float*)d_in[35];
    const float* ln2_b = (const float*)d_in[36];
    const int* dg_src   = (const int*)d_in[37];
    const int* dg_dst   = (const int*)d_in[38];
    const int* disg_src = (const int*)d_in[39];
    const int* disg_dst = (const int*)d_in[40];
    const int* gd_src   = (const int*)d_in[41];
    const int* gd_dst   = (const int*)d_in[42];
    const int* gdis_src = (const int*)d_in[43];
    const int* gdis_dst = (const int*)d_in[44];

    // ---- workspace ----
    char* ws = (char*)d_ws;
    size_t off = 0;
    auto alloc = [&](size_t bytes) -> char* {
        char* p = ws + off;
        off += (bytes + 511) & ~(size_t)511;
        return p;
    };
    // zero region start
    int* bcur = (int*)alloc(4 * MAXB * 4);
    float* e1 = (float*)alloc(NG * 4);
    float* e2 = (float*)alloc(NG * 4);
    size_t zero_len = off;   // bytes to zero each call
    int* offs_dg   = (int*)alloc(NG * 4);
    int* offs_disg = (int*)alloc(NG * 4);
    int* offs_gd   = (int*)alloc(ND * 4);
    int* offs_gdis = (int*)alloc(NS * 4);
    int* cnt_dg    = (int*)alloc(NG * 4);
    int* cnt_disg  = (int*)alloc(NG * 4);
    int* cnt_gd    = (int*)alloc(ND * 4);
    int* cnt_gdis  = (int*)alloc(NS * 4);
    int* srcs_dg   = (int*)alloc((size_t)EE * 4);
    int* srcs_disg = (int*)alloc((size_t)EE * 4);
    int* srcs_gd   = (int*)alloc((size_t)EE * 4);
    int* srcs_gdis = (int*)alloc((size_t)EE * 4);
    unsigned short* Q12  = (unsigned short*)alloc((size_t)NG * 512 * 2);  // 20.5MB
    unsigned short* KVb  = (unsigned short*)alloc((size_t)NG * 512 * 2);
    unsigned short* gm_d = (unsigned short*)alloc((size_t)NG * 256 * 2);
    unsigned short* gm_s = (unsigned short*)alloc((size_t)NG * 256 * 2);
    unsigned short* gene_bf = (unsigned short*)alloc((size_t)NG * 256 * 2);
    unsigned short* drug_bf = (unsigned short*)alloc((size_t)ND * 256 * 2);
    unsigned short* dis_bf  = (unsigned short*)alloc((size_t)NS * 256 * 2);
    unsigned short* Wbf     = (unsigned short*)alloc((size_t)14 * 65536 * 2);
    size_t need = off;

    // level-1 record buffers overlay Q12 (dead until after l2_csr_kernel)
    int* brec0 = (int*)Q12;
    int* brec1 = brec0 + RB_G;
    int* brec2 = brec1 + RB_G;
    int* brec3 = brec2 + RB_S;     // total 5.47MB <= 20.5MB

    // gm_d is dead after gene_fusion_kernel -> reuse as bf16 gene_out
    unsigned short* gene_out_bf = gm_d;

    float* out_drug = out_f32;                       // [8000, 256]
    float* out_dis  = out_drug + (size_t)ND * 256;   // [8000, 256]
    float* out_gene = out_dis + (size_t)NS * 256;    // [20000, 256]

    if (ws_size < need) {   // sentinel: 1000.0f
        fillf_kernel<<<(out_size + 255) / 256, 256, 0, stream>>>(out_f32, out_size, 1000.0f);
        return;
    }

    zero_kernel<<<((int)(zero_len / 4) + 255) / 256, 256, 0, stream>>>(
        (int*)d_ws, (int)(zero_len / 4));

    // ---- bf16 pre-conversion (weights + input features) ----
    // W layout: 0 dg_Wq | 1 disg_Wq  (fused stage-1 Q, N=512)
    //           2 dg_Wk | 3 dg_Wv    (KV dg)      4 disg_Wk | 5 disg_Wv (KV disg)
    //           6 gd_Wk | 7 gd_Wv    (KV gd)      8 gdis_Wk | 9 gdis_Wv (KV gdis)
    //           10 gd_Wq  11 gdis_Wq  12 f_W1  13 f_W2
    {
        WSrc s;
        const float* wl[14] = {dg_Wq, disg_Wq, dg_Wk, dg_Wv, disg_Wk, disg_Wv,
                               gd_Wk, gd_Wv, gdis_Wk, gdis_Wv, gd_Wq, gdis_Wq,
                               f_W1, f_W2};
        for (int i = 0; i < 14; ++i) s.p[i] = wl[i];
        convert_w_kernel<<<(14 * 16384) / 256, 256, 0, stream>>>(s, Wbf);
    }
    convert_feat_kernel<<<((NG + ND + NS) * 64 + 255) / 256, 256, 0, stream>>>(
        gene_feat, drug_feat, disease_feat, gene_bf, drug_bf, dis_bf);

    // ---- 2-level CSR build for all 4 graphs ----
    {
        L1P p;
        p.src[0] = dg_src; p.src[1] = disg_src; p.src[2] = gd_src; p.src[3] = gdis_src;
        p.dst[0] = dg_dst; p.dst[1] = disg_dst; p.dst[2] = gd_dst; p.dst[3] = gdis_dst;
        p.brec[0] = brec0; p.brec[1] = brec1; p.brec[2] = brec2; p.brec[3] = brec3;
        p.bcur = bcur;
        l1_bucket_kernel<<<4 * NCH1, 256, 0, stream>>>(p);
    }
    {
        L2P p;
        p.brec[0] = brec0; p.brec[1] = brec1; p.brec[2] = brec2; p.brec[3] = brec3;
        p.bcur = bcur;
        p.cnt[0] = cnt_dg; p.cnt[1] = cnt_disg; p.cnt[2] = cnt_gd; p.cnt[3] = cnt_gdis;
        p.offs[0] = offs_dg; p.offs[1] = offs_disg; p.offs[2] = offs_gd; p.offs[3] = offs_gdis;
        p.srcs[0] = srcs_dg; p.srcs[1] = srcs_disg; p.srcs[2] = srcs_gd; p.srcs[3] = srcs_gdis;
        l2_csr_kernel<<<144, 256, 0, stream>>>(p);
    }

    // ---- stage 1: fused Q GEMM (dg|disg, N=512), then per-graph KV + agg ----
    {
        dim3 gq((NG + 127) / 128, 8);
        gemm_nt<0, 0><<<gq, 256, 0, stream>>>(gene_bf, Wbf, dg_bq, disg_bq,
                                              dg_bq, dg_bq, Q12, 512,
                                              nullptr, nullptr, NG);
    }
    {
        dim3 gkv((ND + 127) / 128, 8);
        gemm_nt<0, 1><<<gkv, 256, 0, stream>>>(drug_bf, Wbf + (size_t)2 * 65536,
                                               dg_bk, dg_bv, dg_bk, dg_bk,
                                               KVb, 512, nullptr, nullptr, ND);
    }
    agg_gm_kernel<<<(NG + 3) / 4, 256, 0, stream>>>(Q12, 512, KVb, offs_dg, cnt_dg,
                                                    srcs_dg, gm_d, NG);
    {
        dim3 gkv((NS + 127) / 128, 8);
        gemm_nt<0, 1><<<gkv, 256, 0, stream>>>(dis_bf, Wbf + (size_t)4 * 65536,
                                               disg_bk, disg_bv, disg_bk, disg_bk,
                                               KVb, 512, nullptr, nullptr, NS);
    }
    agg_gm_kernel<<<(NG + 3) / 4, 256, 0, stream>>>(Q12 + 256, 512, KVb, offs_disg,
                                                    cnt_disg, srcs_disg, gm_s, NG);

    // ---- Bahdanau fusion + LN1 -> gene_out (fp32 + bf16 copy) ----
    {
        dim3 gb((NG + 127) / 128, 4);
        gemm_nt<1, 0><<<gb, 256, 0, stream>>>(gm_d, Wbf + (size_t)12 * 65536,
                                              f_b1, f_b1, f_b1, f_b1,
                                              nullptr, 256, f_v, e1, NG);
        gemm_nt<1, 0><<<gb, 256, 0, stream>>>(gm_s, Wbf + (size_t)13 * 65536,
                                              f_b2, f_b2, f_b2, f_b2,
                                              nullptr, 256, f_v, e2, NG);
    }
    gene_fusion_kernel<<<(NG + 3) / 4, 256, 0, stream>>>(
        gene_feat, gm_d, gm_s, e1, e2, cnt_dg, cnt_disg, ln1_g, ln1_b,
        out_gene, gene_out_bf);

    // ---- stage 2: gene->drug ----
    {
        dim3 gq((ND + 127) / 128, 4);
        gemm_nt<0, 0><<<gq, 256, 0, stream>>>(drug_bf, Wbf + (size_t)10 * 65536,
                                              gd_bq, gd_bq, gd_bq, gd_bq,
                                              Q12, 256, nullptr, nullptr, ND);
    }
    {
        dim3 gkv((NG + 127) / 128, 8);
        gemm_nt<0, 1><<<gkv, 256, 0, stream>>>(gene_out_bf, Wbf + (size_t)6 * 65536,
                                               gd_bk, gd_bv, gd_bk, gd_bk,
                                               KVb, 512, nullptr, nullptr, NG);
    }
    agg_ln_kernel<<<(ND + 3) / 4, 256, 0, stream>>>(Q12, 256, KVb, offs_gd, cnt_gd,
                                                    srcs_gd, drug_feat, ln2_g, ln2_b,
                                                    out_drug, ND);

    // ---- stage 2: gene->disease ----
    {
        dim3 gq((NS + 127) / 128, 4);
        gemm_nt<0, 0><<<gq, 256, 0, stream>>>(dis_bf, Wbf + (size_t)11 * 65536,
                                              gdis_bq, gdis_bq, gdis_bq, gdis_bq,
                                              Q12, 256, nullptr, nullptr, NS);
    }
    {
        dim3 gkv((NG + 127) / 128, 8);
        gemm_nt<0, 1><<<gkv, 256, 0, stream>>>(gene_out_bf, Wbf + (size_t)8 * 65536,
                                               gdis_bk, gdis_bv, gdis_bk, gdis_bk,
                                               KVb, 512, nullptr, nullptr, NG);
    }
    agg_ln_kernel<<<(NS + 3) / 4, 256, 0, stream>>>(Q12, 256, KVb, offs_gdis, cnt_gdis,
                                                    srcs_gdis, disease_feat, ln2_g, ln2_b,
                                                    out_dis, NS);
}

// Round 5
// 515.856 us; speedup vs baseline: 1.9540x; 1.0380x over previous
//
#include <hip/hip_runtime.h>

#define NG 20000
#define ND 8000
#define NS 8000
#define EE 300000
#define DIM 256
#define SCALE_QK 0.17677669529663687f  // 1/sqrt(32)
#define LNEPS 1e-5f

#define MAXB 40                        // max buckets per graph
#define L1CH 2048                      // edges per level-1 block
#define NCH1 ((EE + L1CH - 1) / L1CH)  // 147 blocks per graph
// bucket geometry: graphs 0,1 (dst<NG): shift 9 -> 40 buckets, cap 8704
//                  graphs 2,3 (dst<ND/NS): shift 8 -> 32 buckets, cap 10496
#define CB_G 8704
#define CB_S 10496
#define RB_G (40 * CB_G)               // 348160 records
#define RB_S (32 * CB_S)               // 335872 records

typedef __attribute__((ext_vector_type(4))) float floatx4;
typedef __attribute__((ext_vector_type(8))) short shortx8;
typedef __attribute__((ext_vector_type(8))) unsigned short ushortx8;
typedef unsigned int u32;

__device__ __forceinline__ float bf2f(unsigned short u) {
    union { unsigned u; float f; } c; c.u = ((unsigned)u) << 16; return c.f;
}
__device__ __forceinline__ unsigned short f2bf(float f) {
    union { float f; unsigned u; } c; c.f = f;
    return (unsigned short)((c.u + 0x7fffu + ((c.u >> 16) & 1u)) >> 16);
}
__device__ __forceinline__ float gelu_exact(float v) {
    return 0.5f * v * (1.0f + erff(v * 0.70710678118654752f));
}

// async global->LDS, 16B per lane; LDS dest = wave-uniform base + lane*16
__device__ __forceinline__ void async_load16(const unsigned short* g,
                                             unsigned short* lds) {
    __builtin_amdgcn_global_load_lds(
        (const __attribute__((address_space(1))) u32*)(const void*)g,
        (__attribute__((address_space(3))) u32*)(void*)lds, 16, 0, 0);
}

// short-offset of the 16B chunk (row, q) in a swizzled [rows][32-short] tile.
// Swizzle: within each 16-row group, chunk (pair p, b=row&1, quad q) lives at
// slot8 = (4b+q)^p of pair-line p. Staging writes linearly (lane l -> slot l);
// the per-lane GLOBAL source is pre-permuted to match (rule: both sides).
__device__ __forceinline__ int swzoff(int row, int q) {
    int p = (row >> 1) & 7, b = row & 1;
    return ((row >> 4) * 64 + p * 8 + (((b << 2) + q) ^ p)) * 8;
}

// ---------------------------------------------------------------------------
// MFMA GEMM: C[M, NCOL] = A[M,256] @ W[NCOL,256]^T + bias
// A bf16, W bf16 (pre-converted), bias fp32 (b1..b4 per 256-col range),
// C bf16 (row stride ldc).
// global_load_lds staging (16B/lane) into double-buffered swizzled LDS,
// ONE barrier per K-step; tile k+1 prefetch issued before compute on tile k.
// NOTE: M-tail rows (m>=M) load garbage from adjacent workspace buffers —
// safe: all C/e writes are m<M guarded, MFMA garbage stays within its row.
// KVI=1: within each 512-col half, write KV-interleaved: dim d of K ->
//   (d>>2)*8+(d&3), dim d of V -> (d>>2)*8+4+(d&3) (16B load = K+V chunk).
// MODE 0: store bf16 C.  MODE 1: Bahdanau epilogue e[m] += sum_n v[n]*tanh(C+b)
// Tile 128m x 64n, BK=32, 256 threads (4 waves; wave -> 32 m-rows).
// ---------------------------------------------------------------------------
template <int MODE, int KVI>
__global__ __launch_bounds__(256, 4) void gemm_nt(
    const unsigned short* __restrict__ A, const unsigned short* __restrict__ W,
    const float* __restrict__ bias1, const float* __restrict__ bias2,
    const float* __restrict__ bias3, const float* __restrict__ bias4,
    unsigned short* __restrict__ C, int ldc,
    const float* __restrict__ vvec, float* __restrict__ evec, int M)
{
    __shared__ unsigned short As[2][128 * 32];
    __shared__ unsigned short Bs[2][64 * 32];
    const int tid = threadIdx.x;
    const int lane = tid & 63, wv = tid >> 6;
    const int quad = lane >> 4, l16 = lane & 15;
    const int m0 = blockIdx.x * 128;
    const int n0 = blockIdx.y * 64;

    // staging lane mapping: lane l writes LDS slot l of its 16-row group;
    // source chunk = logical (row = 2p + ((s^p)>>2), q = (s^p)&3)
    const int sp = lane >> 3, ss = lane & 7;
    const int srow = 2 * sp + ((ss ^ sp) >> 2);
    const int sq = (ss ^ sp) & 3;
    const unsigned short* gA0 = A + (size_t)(m0 + wv * 16 + srow) * 256 + sq * 8;
    const unsigned short* gA1 = A + (size_t)(m0 + 64 + wv * 16 + srow) * 256 + sq * 8;
    const unsigned short* gB  = W + (size_t)(n0 + wv * 16 + srow) * 256 + sq * 8;

    floatx4 acc[2][4];
#pragma unroll
    for (int i = 0; i < 2; ++i)
#pragma unroll
        for (int j = 0; j < 4; ++j) acc[i][j] = (floatx4){0.f, 0.f, 0.f, 0.f};

    // prologue: stage k0 = 0 into buf 0
    async_load16(gA0, &As[0][(wv * 16) * 32]);
    async_load16(gA1, &As[0][(64 + wv * 16) * 32]);
    async_load16(gB,  &Bs[0][(wv * 16) * 32]);
    __syncthreads();

    for (int k0 = 0; k0 < 256; k0 += 32) {
        const int buf = (k0 >> 5) & 1;
        if (k0 < 224) {   // prefetch next K-tile into other buffer
            const int nb = buf ^ 1;
            async_load16(gA0 + k0 + 32, &As[nb][(wv * 16) * 32]);
            async_load16(gA1 + k0 + 32, &As[nb][(64 + wv * 16) * 32]);
            async_load16(gB + k0 + 32,  &Bs[nb][(wv * 16) * 32]);
        }
        shortx8 af[2], bfr[4];
#pragma unroll
        for (int mf = 0; mf < 2; ++mf)
            af[mf] = *(const shortx8*)(&As[buf][swzoff(wv * 32 + mf * 16 + l16, quad)]);
#pragma unroll
        for (int nf = 0; nf < 4; ++nf)
            bfr[nf] = *(const shortx8*)(&Bs[buf][swzoff(nf * 16 + l16, quad)]);
#pragma unroll
        for (int mf = 0; mf < 2; ++mf)
#pragma unroll
            for (int nf = 0; nf < 4; ++nf)
                acc[mf][nf] = __builtin_amdgcn_mfma_f32_16x16x32_bf16(
                    af[mf], bfr[nf], acc[mf][nf], 0, 0, 0);
        __syncthreads();   // drains prefetch (vmcnt) + protects buf reuse
    }

    if (MODE == 0) {
#pragma unroll
        for (int mf = 0; mf < 2; ++mf)
#pragma unroll
            for (int r = 0; r < 4; ++r) {
                int m = m0 + wv * 32 + mf * 16 + quad * 4 + r;
                if (m < M) {
#pragma unroll
                    for (int nf = 0; nf < 4; ++nf) {
                        int n = n0 + nf * 16 + l16;
                        int h = n >> 8;
                        const float* bp = (h == 0) ? bias1 : (h == 1) ? bias2
                                        : (h == 2) ? bias3 : bias4;
                        float bn = bp[n & 255];
                        int pos;
                        if (KVI) {
                            int nn = n & 511;
                            pos = (n & ~511) + ((nn & 255) >> 2) * 8 + (nn & 3) +
                                  ((nn >> 8) << 2);
                        } else {
                            pos = n;
                        }
                        C[(size_t)m * ldc + pos] = f2bf(acc[mf][nf][r] + bn);
                    }
                }
            }
    } else {
        float p[2][4] = {};
#pragma unroll
        for (int mf = 0; mf < 2; ++mf)
#pragma unroll
            for (int nf = 0; nf < 4; ++nf) {
                int n = n0 + nf * 16 + l16;
                float vn = vvec[n];
                float bn = bias1[n];
#pragma unroll
                for (int r = 0; r < 4; ++r)
                    p[mf][r] += vn * tanhf(acc[mf][nf][r] + bn);
            }
#pragma unroll
        for (int mf = 0; mf < 2; ++mf)
#pragma unroll
            for (int r = 0; r < 4; ++r) {
                float s = p[mf][r];
                s += __shfl_xor(s, 1); s += __shfl_xor(s, 2);
                s += __shfl_xor(s, 4); s += __shfl_xor(s, 8);
                if (l16 == 0) {
                    int m = m0 + wv * 32 + mf * 16 + quad * 4 + r;
                    if (m < M) atomicAdd(&evec[m], s);
                }
            }
    }
}

// ---------------------------------------------------------------------------
// Fused prep: workspace zeroing + weight bf16 convert + feature bf16 convert
// (one dispatch instead of three).
// ---------------------------------------------------------------------------
struct PrepP {
    int* zb; int zn; int nzb;
    const float* wsrc[14];
    unsigned short* wout;
    const float* gf; const float* df; const float* sf;
    unsigned short* go; unsigned short* dfo; unsigned short* so;
};
__global__ void prep_kernel(PrepP p) {
    int bid = blockIdx.x, tid = threadIdx.x;
    if (bid < p.nzb) {
        int i = bid * 256 + tid;
        if (i < p.zn) p.zb[i] = 0;
        return;
    }
    bid -= p.nzb;
    if (bid < 896) {   // weights: 14 x 65536, 4 floats/thread
        int idx = bid * 256 + tid;
        int mat = idx >> 14;
        int e = (idx & 16383) << 2;
        float4 f = *(const float4*)(p.wsrc[mat] + e);
        ushort4 t;
        t.x = f2bf(f.x); t.y = f2bf(f.y); t.z = f2bf(f.z); t.w = f2bf(f.w);
        *(ushort4*)(p.wout + ((size_t)mat << 16) + e) = t;
        return;
    }
    bid -= 896;
    const int NG4 = NG * 64, ND4 = ND * 64, NS4 = NS * 64;
    int i = bid * 256 + tid;
    const float* in; unsigned short* out; int j;
    if (i < NG4) { in = p.gf; out = p.go; j = i; }
    else if (i < NG4 + ND4) { in = p.df; out = p.dfo; j = i - NG4; }
    else if (i < NG4 + ND4 + NS4) { in = p.sf; out = p.so; j = i - NG4 - ND4; }
    else return;
    float4 f = *(const float4*)(in + (size_t)j * 4);
    ushort4 t;
    t.x = f2bf(f.x); t.y = f2bf(f.y); t.z = f2bf(f.z); t.w = f2bf(f.w);
    *(ushort4*)(out + (size_t)j * 4) = t;
}

__global__ void fillf_kernel(float* __restrict__ p, int n, float v) {
    int i = blockIdx.x * blockDim.x + threadIdx.x;
    if (i < n) p[i] = v;
}

// ---------------------------------------------------------------------------
// 2-level CSR build. Level 1: coarse-bucket records with per-block LDS
// histogram; ONE global atomic per (block, nonzero bucket). Level 2: one
// block per bucket; LDS fine histogram + scan produce cnt/offs densely,
// then dense scatter into the bucket's CSR slice.
// Record: (dstLocal<<15) | src  (dstLocal<512, src<32768).
// ---------------------------------------------------------------------------
struct L1P {
    const int* src[4];
    const int* dst[4];
    int* brec[4];
    int* bcur;          // [4*MAXB], zeroed before launch
};
__global__ __launch_bounds__(256) void l1_bucket_kernel(L1P a) {
    __shared__ int hist[MAXB];
    int g = blockIdx.x / NCH1, c = blockIdx.x - g * NCH1;
    int base = c * L1CH;
    int tid = threadIdx.x;
    const int shift = (g < 2) ? 9 : 8;
    const int CB = (g < 2) ? CB_G : CB_S;
    const int NB = (g < 2) ? 40 : 32;
    if (tid < NB) hist[tid] = 0;
    __syncthreads();
    const int* __restrict__ dstp = a.dst[g];
    const int* __restrict__ srcp = a.src[g];
    int bk[8], rec[8], lr[8];
#pragma unroll
    for (int j = 0; j < 8; ++j) {
        int e = base + j * 256 + tid;
        bool ok = e < EE;
        int dd = ok ? dstp[e] : 0;
        int ss = ok ? srcp[e] : 0;
        bk[j] = dd >> shift;
        rec[j] = ((dd & ((1 << shift) - 1)) << 15) | ss;
        lr[j] = ok ? atomicAdd(&hist[bk[j]], 1) : -1;
    }
    __syncthreads();
    if (tid < NB) {
        int h = hist[tid];
        if (h > 0) hist[tid] = atomicAdd(&a.bcur[g * MAXB + tid], h);
    }
    __syncthreads();
    int* __restrict__ recp = a.brec[g];
#pragma unroll
    for (int j = 0; j < 8; ++j) {
        if (lr[j] >= 0) {
            int pos = hist[bk[j]] + lr[j];
            if (pos < CB) recp[bk[j] * CB + pos] = rec[j];
        }
    }
}

struct L2P {
    const int* brec[4];
    const int* bcur;
    int* cnt[4];
    int* offs[4];
    int* srcs[4];
};
__global__ __launch_bounds__(256) void l2_csr_kernel(L2P a) {
    __shared__ int hist[512];
    __shared__ int loffs[512];
    __shared__ int cur[512];
    __shared__ int ws2[4];
    __shared__ int bb;
    int bid = blockIdx.x, tid = threadIdx.x;
    int g, b;
    if (bid < 40) { g = 0; b = bid; }
    else if (bid < 80) { g = 1; b = bid - 40; }
    else if (bid < 112) { g = 2; b = bid - 80; }
    else { g = 3; b = bid - 112; }
    const int shift = (g < 2) ? 9 : 8;
    const int BSZ = 1 << shift;
    const int CB = (g < 2) ? CB_G : CB_S;
    const int N = (g < 2) ? NG : ((g == 2) ? ND : NS);
    hist[tid] = 0; hist[256 + tid] = 0;
    if (tid == 0) {
        int s = 0;
        const int* bc = a.bcur + g * MAXB;
        for (int i = 0; i < b; ++i) s += bc[i];
        bb = s;
    }
    __syncthreads();
    int total = a.bcur[g * MAXB + b];
    if (total > CB) total = CB;
    const int* __restrict__ recp = a.brec[g] + b * CB;
    for (int i = tid; i < total; i += 256)
        atomicAdd(&hist[recp[i] >> 15], 1);
    __syncthreads();
    // exclusive scan over 512 bins (upper half zero when BSZ=256)
    int v0 = hist[2 * tid], v1 = hist[2 * tid + 1];
    int s = v0 + v1, x = s;
    int lane = tid & 63, wv = tid >> 6;
#pragma unroll
    for (int o = 1; o < 64; o <<= 1) {
        int u = __shfl_up(x, o);
        if (lane >= o) x += u;
    }
    if (lane == 63) ws2[wv] = x;
    __syncthreads();
    int woff = 0;
    for (int w = 0; w < wv; ++w) woff += ws2[w];
    int excl = woff + x - s;
    loffs[2 * tid] = excl; loffs[2 * tid + 1] = excl + v0;
    cur[2 * tid] = excl;  cur[2 * tid + 1] = excl + v0;
    int base = bb;
    int lo = b << shift;
    for (int i = tid; i < BSZ; i += 256) {
        int d = lo + i;
        if (d < N) {
            a.cnt[g][d] = hist[i];
            a.offs[g][d] = base + loffs[i];
        }
    }
    __syncthreads();
    int* __restrict__ sp = a.srcs[g];
    for (int i = tid; i < total; i += 256) {
        int rec = recp[i];
        int pos = atomicAdd(&cur[rec >> 15], 1);
        sp[base + pos] = rec & 0x7fff;
    }
}

// ---------------------------------------------------------------------------
// Fused CSR aggregation — ONE WAVE PER NODE (4 nodes/block, no LDS/barriers).
// KV interleaved per 4 dims: one 16B load/lane yields both K-chunk and
// V-chunk. 8 independent online-softmax chains, merged in-register.
// Head h = lanes 8h..8h+7 -> 3-shfl dot reduce. Q row stride qs (fused Q).
// ---------------------------------------------------------------------------
__device__ __forceinline__ void wave_attn_node(
    const unsigned short* __restrict__ Q, int qs,
    const unsigned short* __restrict__ KV,
    const int* __restrict__ offs, const int* __restrict__ cnt,
    const int* __restrict__ srcs, int du, int lane,
    float& g0, float& g1, float& g2, float& g3)
{
    const int lo = lane * 4;
    const int lofs = lane * 8;
    ushort4 qv = *(const ushort4*)(Q + (size_t)du * qs + lo);
    const float q0 = bf2f(qv.x), q1 = bf2f(qv.y), q2 = bf2f(qv.z), q3 = bf2f(qv.w);
    const int beg = offs[du], num = cnt[du];

    float m[8], l[8], a[8][4];
#pragma unroll
    for (int c = 0; c < 8; ++c) {
        m[c] = -INFINITY; l[c] = 0.f;
        a[c][0] = a[c][1] = a[c][2] = a[c][3] = 0.f;
    }

    for (int i = 0; i < num; i += 8) {
        ushortx8 kv[8];
#pragma unroll
        for (int c = 0; c < 8; ++c) {
            int idx = i + c;
            int cidx = (idx < num) ? idx : (num - 1);   // clamped (masked later)
            int s = srcs[beg + cidx];
            kv[c] = *(const ushortx8*)(KV + (size_t)s * 512 + lofs);
        }
        float p[8];
#pragma unroll
        for (int c = 0; c < 8; ++c)
            p[c] = q0 * bf2f(kv[c][0]) + q1 * bf2f(kv[c][1]) +
                   q2 * bf2f(kv[c][2]) + q3 * bf2f(kv[c][3]);
#pragma unroll
        for (int c = 0; c < 8; ++c) p[c] += __shfl_xor(p[c], 1);
#pragma unroll
        for (int c = 0; c < 8; ++c) p[c] += __shfl_xor(p[c], 2);
#pragma unroll
        for (int c = 0; c < 8; ++c) p[c] += __shfl_xor(p[c], 4);
#pragma unroll
        for (int c = 0; c < 8; ++c) {
            if (i + c < num) {   // wave-uniform branch
                float sc = p[c] * SCALE_QK;
                float mn = fmaxf(m[c], sc);
                float eo = __expf(m[c] - mn);   // first edge: exp(-inf)=0
                float en = __expf(sc - mn);
                a[c][0] = a[c][0] * eo + en * bf2f(kv[c][4]);
                a[c][1] = a[c][1] * eo + en * bf2f(kv[c][5]);
                a[c][2] = a[c][2] * eo + en * bf2f(kv[c][6]);
                a[c][3] = a[c][3] * eo + en * bf2f(kv[c][7]);
                l[c] = l[c] * eo + en;
                m[c] = mn;
            }
        }
    }

    // merge 8 chains in-register
    float ms = fmaxf(fmaxf(fmaxf(m[0], m[1]), fmaxf(m[2], m[3])),
                     fmaxf(fmaxf(m[4], m[5]), fmaxf(m[6], m[7])));
    float A0 = 0.f, A1 = 0.f, A2 = 0.f, A3 = 0.f, L = 0.f;
    if (ms > -INFINITY) {
#pragma unroll
        for (int c = 0; c < 8; ++c) {
            float w = __expf(m[c] - ms);
            A0 += a[c][0] * w; A1 += a[c][1] * w;
            A2 += a[c][2] * w; A3 += a[c][3] * w;
            L += l[c] * w;
        }
    }
    float inv = (L > 0.f) ? 1.f / L : 0.f;
    g0 = A0 * inv; g1 = A1 * inv; g2 = A2 * inv; g3 = A3 * inv;
}

// Wave-level LN (no LDS): x_j for 4 features/lane, full-wave reduce.
__device__ __forceinline__ void wave_ln_store(
    float x0, float x1, float x2, float x3,
    const float* __restrict__ g, const float* __restrict__ b,
    float* __restrict__ out, unsigned short* __restrict__ out_bf,
    int du, int lo)
{
    float s1 = x0 + x1 + x2 + x3;
    float s2 = x0 * x0 + x1 * x1 + x2 * x2 + x3 * x3;
#pragma unroll
    for (int o = 1; o < 64; o <<= 1) {
        s1 += __shfl_xor(s1, o);
        s2 += __shfl_xor(s2, o);
    }
    float mu = s1 * (1.f / 256.f);
    float var = fmaxf(s2 * (1.f / 256.f) - mu * mu, 0.f);
    float rs = rsqrtf(var + LNEPS);
    float4 gv = *(const float4*)(g + lo);
    float4 bv = *(const float4*)(b + lo);
    float y0 = (x0 - mu) * rs * gv.x + bv.x;
    float y1 = (x1 - mu) * rs * gv.y + bv.y;
    float y2 = (x2 - mu) * rs * gv.z + bv.z;
    float y3 = (x3 - mu) * rs * gv.w + bv.w;
    *(float4*)(out + (size_t)du * 256 + lo) = make_float4(y0, y1, y2, y3);
    if (out_bf) {
        ushort4 t; t.x = f2bf(y0); t.y = f2bf(y1); t.z = f2bf(y2); t.w = f2bf(y3);
        *(ushort4*)(out_bf + (size_t)du * 256 + lo) = t;
    }
}

__global__ __launch_bounds__(256) void agg_gm_kernel(
    const unsigned short* __restrict__ Q, int qs,
    const unsigned short* __restrict__ KV,
    const int* __restrict__ offs, const int* __restrict__ cnt,
    const int* __restrict__ srcs, unsigned short* __restrict__ gm, int N)
{
    int lane = threadIdx.x & 63, wv = threadIdx.x >> 6;
    int d = blockIdx.x * 4 + wv;
    if (d >= N) return;
    int du = __builtin_amdgcn_readfirstlane(d);
    float g0, g1, g2, g3;
    wave_attn_node(Q, qs, KV, offs, cnt, srcs, du, lane, g0, g1, g2, g3);
    ushort4 t; t.x = f2bf(g0); t.y = f2bf(g1); t.z = f2bf(g2); t.w = f2bf(g3);
    *(ushort4*)(gm + (size_t)du * 256 + lane * 4) = t;
}

__global__ __launch_bounds__(256) void agg_ln_kernel(
    const unsigned short* __restrict__ Q, int qs,
    const unsigned short* __restrict__ KV,
    const int* __restrict__ offs, const int* __restrict__ cnt,
    const int* __restrict__ srcs, const float* __restrict__ feat,
    const float* __restrict__ g, const float* __restrict__ b,
    float* __restrict__ out, int N)
{
    int lane = threadIdx.x & 63, wv = threadIdx.x >> 6;
    int d = blockIdx.x * 4 + wv;
    if (d >= N) return;
    int du = __builtin_amdgcn_readfirstlane(d);
    int lo = lane * 4;
    float g0, g1, g2, g3;
    wave_attn_node(Q, qs, KV, offs, cnt, srcs, du, lane, g0, g1, g2, g3);
    float4 fv = *(const float4*)(feat + (size_t)du * 256 + lo);
    float x0 = fv.x + gelu_exact(g0);
    float x1 = fv.y + gelu_exact(g1);
    float x2 = fv.z + gelu_exact(g2);
    float x3 = fv.w + gelu_exact(g3);
    wave_ln_store(x0, x1, x2, x3, g, b, out, nullptr, du, lo);
}

__global__ __launch_bounds__(256) void gene_fusion_kernel(
    const float* __restrict__ gene_feat, const unsigned short* __restrict__ gm_d,
    const unsigned short* __restrict__ gm_s, const float* __restrict__ e1,
    const float* __restrict__ e2, const int* __restrict__ cnt_d,
    const int* __restrict__ cnt_s, const float* __restrict__ g,
    const float* __restrict__ b, float* __restrict__ out,
    unsigned short* __restrict__ out_bf)
{
    int lane = threadIdx.x & 63, wv = threadIdx.x >> 6;
    int d = blockIdx.x * 4 + wv;
    if (d >= NG) return;
    int du = __builtin_amdgcn_readfirstlane(d);
    int lo = lane * 4;
    ushort4 v1 = *(const ushort4*)(gm_d + (size_t)du * 256 + lo);
    ushort4 v2 = *(const ushort4*)(gm_s + (size_t)du * 256 + lo);
    bool hd = cnt_d[du] > 0, hs = cnt_s[du] > 0;
    float wa, wb;
    if (hd && hs) {
        float aa = e1[du], bb = e2[du];
        float mm = fmaxf(aa, bb);   // softmax([e1+bv,e2+bv]) == softmax([e1,e2])
        float ea = __expf(aa - mm), eb = __expf(bb - mm);
        float inv = 1.f / (ea + eb);
        wa = ea * inv; wb = eb * inv;
    } else if (hd) { wa = 1.f; wb = 0.f; }
    else if (hs) { wa = 0.f; wb = 1.f; }
    else { wa = 0.f; wb = 0.f; }
    float m0 = wa * bf2f(v1.x) + wb * bf2f(v2.x);
    float m1 = wa * bf2f(v1.y) + wb * bf2f(v2.y);
    float m2 = wa * bf2f(v1.z) + wb * bf2f(v2.z);
    float m3 = wa * bf2f(v1.w) + wb * bf2f(v2.w);
    float4 fv = *(const float4*)(gene_feat + (size_t)du * 256 + lo);
    float x0 = fv.x + gelu_exact(m0);
    float x1 = fv.y + gelu_exact(m1);
    float x2 = fv.z + gelu_exact(m2);
    float x3 = fv.w + gelu_exact(m3);
    wave_ln_store(x0, x1, x2, x3, g, b, out, out_bf, du, lo);
}

// ---------------------------------------------------------------------------
extern "C" void kernel_launch(void* const* d_in, const int* in_sizes, int n_in,
                              void* d_out, int out_size, void* d_ws, size_t ws_size,
                              hipStream_t stream)
{
    float* out_f32 = (float*)d_out;

    const float* gene_feat    = (const float*)d_in[0];
    const float* drug_feat    = (const float*)d_in[1];
    const float* disease_feat = (const float*)d_in[2];
    const float* dg_Wq = (const float*)d_in[3];
    const float* dg_bq = (const float*)d_in[4];
    const float* dg_Wk = (const float*)d_in[5];
    const float* dg_bk = (const float*)d_in[6];
    const float* dg_Wv = (const float*)d_in[7];
    const float* dg_bv = (const float*)d_in[8];
    const float* disg_Wq = (const float*)d_in[9];
    const float* disg_bq = (const float*)d_in[10];
    const float* disg_Wk = (const float*)d_in[11];
    const float* disg_bk = (const float*)d_in[12];
    const float* disg_Wv = (const float*)d_in[13];
    const float* disg_bv = (const float*)d_in[14];
    const float* gd_Wq = (const float*)d_in[15];
    const float* gd_bq = (const float*)d_in[16];
    const float* gd_Wk = (const float*)d_in[17];
    const float* gd_bk = (const float*)d_in[18];
    const float* gd_Wv = (const float*)d_in[19];
    const float* gd_bv = (const float*)d_in[20];
    const float* gdis_Wq = (const float*)d_in[21];
    const float* gdis_bq = (const float*)d_in[22];
    const float* gdis_Wk = (const float*)d_in[23];
    const float* gdis_bk = (const float*)d_in[24];
    const float* gdis_Wv = (const float*)d_in[25];
    const float* gdis_bv = (const float*)d_in[26];
    const float* f_W1 = (const float*)d_in[27];
    const float* f_b1 = (const float*)d_in[28];
    const float* f_W2 = (const float*)d_in[29];
    const float* f_b2 = (const float*)d_in[30];
    const float* f_v  = (const float*)d_in[31];
    const float* ln1_g = (const float*)d_in[33];
    const float* ln1_b = (const float*)d_in[34];
    const float* ln2_g = (const float*)d_in[35];
    const float* ln2_b = (const float*)d_in[36];
    const int* dg_src   = (const int*)d_in[37];
    const int* dg_dst   = (const int*)d_in[38];
    const int* disg_src = (const int*)d_in[39];
    const int* disg_dst = (const int*)d_in[40];
    const int* gd_src   = (const int*)d_in[41];
    const int* gd_dst   = (const int*)d_in[42];
    const int* gdis_src = (const int*)d_in[43];
    const int* gdis_dst = (const int*)d_in[44];

    // ---- workspace ----
    char* ws = (char*)d_ws;
    size_t off = 0;
    auto alloc = [&](size_t bytes) -> char* {
        char* p = ws + off;
        off += (bytes + 511) & ~(size_t)511;
        return p;
    };
    // zero region start
    int* bcur = (int*)alloc(4 * MAXB * 4);
    float* e1 = (float*)alloc(NG * 4);
    float* e2 = (float*)alloc(NG * 4);
    size_t zero_len = off;   // bytes to zero each call
    int* offs_dg   = (int*)alloc(NG * 4);
    int* offs_disg = (int*)alloc(NG * 4);
    int* offs_gd   = (int*)alloc(ND * 4);
    int* offs_gdis = (int*)alloc(NS * 4);
    int* cnt_dg    = (int*)alloc(NG * 4);
    int* cnt_disg  = (int*)alloc(NG * 4);
    int* cnt_gd    = (int*)alloc(ND * 4);
    int* cnt_gdis  = (int*)alloc(NS * 4);
    int* srcs_dg   = (int*)alloc((size_t)EE * 4);
    int* srcs_disg = (int*)alloc((size_t)EE * 4);
    int* srcs_gd   = (int*)alloc((size_t)EE * 4);
    int* srcs_gdis = (int*)alloc((size_t)EE * 4);
    unsigned short* Q12  = (unsigned short*)alloc((size_t)NG * 512 * 2);  // 20.5MB
    unsigned short* KVb  = (unsigned short*)alloc((size_t)NG * 512 * 2);
    unsigned short* gm_d = (unsigned short*)alloc((size_t)NG * 256 * 2);
    unsigned short* gm_s = (unsigned short*)alloc((size_t)NG * 256 * 2);
    unsigned short* gene_bf = (unsigned short*)alloc((size_t)NG * 256 * 2);
    unsigned short* drug_bf = (unsigned short*)alloc((size_t)ND * 256 * 2);
    unsigned short* dis_bf  = (unsigned short*)alloc((size_t)NS * 256 * 2);
    unsigned short* Wbf     = (unsigned short*)alloc((size_t)14 * 65536 * 2);
    char* guard = alloc(64 * 1024);   // M-tail garbage-read guard after Wbf
    (void)guard;
    size_t need = off;

    // level-1 record buffers overlay Q12 (dead until after l2_csr_kernel)
    int* brec0 = (int*)Q12;
    int* brec1 = brec0 + RB_G;
    int* brec2 = brec1 + RB_G;
    int* brec3 = brec2 + RB_S;     // total 5.47MB <= 20.5MB

    // gm_d is dead after gene_fusion_kernel -> reuse as bf16 gene_out
    unsigned short* gene_out_bf = gm_d;

    float* out_drug = out_f32;                       // [8000, 256]
    float* out_dis  = out_drug + (size_t)ND * 256;   // [8000, 256]
    float* out_gene = out_dis + (size_t)NS * 256;    // [20000, 256]

    if (ws_size < need) {   // sentinel: 1000.0f
        fillf_kernel<<<(out_size + 255) / 256, 256, 0, stream>>>(out_f32, out_size, 1000.0f);
        return;
    }

    // ---- fused prep: zero + weight convert + feature convert ----
    // W layout: 0 dg_Wq | 1 disg_Wq  (fused stage-1 Q, N=512)
    //           2 dg_Wk | 3 dg_Wv    (KV dg)      4 disg_Wk | 5 disg_Wv (KV disg)
    //           6 gd_Wk | 7 gd_Wv    (KV gd)      8 gdis_Wk | 9 gdis_Wv (KV gdis)
    //           10 gd_Wq  11 gdis_Wq  12 f_W1  13 f_W2
    {
        PrepP p;
        p.zb = (int*)d_ws;
        p.zn = (int)(zero_len / 4);
        p.nzb = (p.zn + 255) / 256;
        const float* wl[14] = {dg_Wq, disg_Wq, dg_Wk, dg_Wv, disg_Wk, disg_Wv,
                               gd_Wk, gd_Wv, gdis_Wk, gdis_Wv, gd_Wq, gdis_Wq,
                               f_W1, f_W2};
        for (int i = 0; i < 14; ++i) p.wsrc[i] = wl[i];
        p.wout = Wbf;
        p.gf = gene_feat; p.df = drug_feat; p.sf = disease_feat;
        p.go = gene_bf; p.dfo = drug_bf; p.so = dis_bf;
        int nfeat = ((NG + ND + NS) * 64 + 255) / 256;
        prep_kernel<<<p.nzb + 896 + nfeat, 256, 0, stream>>>(p);
    }

    // ---- 2-level CSR build for all 4 graphs ----
    {
        L1P p;
        p.src[0] = dg_src; p.src[1] = disg_src; p.src[2] = gd_src; p.src[3] = gdis_src;
        p.dst[0] = dg_dst; p.dst[1] = disg_dst; p.dst[2] = gd_dst; p.dst[3] = gdis_dst;
        p.brec[0] = brec0; p.brec[1] = brec1; p.brec[2] = brec2; p.brec[3] = brec3;
        p.bcur = bcur;
        l1_bucket_kernel<<<4 * NCH1, 256, 0, stream>>>(p);
    }
    {
        L2P p;
        p.brec[0] = brec0; p.brec[1] = brec1; p.brec[2] = brec2; p.brec[3] = brec3;
        p.bcur = bcur;
        p.cnt[0] = cnt_dg; p.cnt[1] = cnt_disg; p.cnt[2] = cnt_gd; p.cnt[3] = cnt_gdis;
        p.offs[0] = offs_dg; p.offs[1] = offs_disg; p.offs[2] = offs_gd; p.offs[3] = offs_gdis;
        p.srcs[0] = srcs_dg; p.srcs[1] = srcs_disg; p.srcs[2] = srcs_gd; p.srcs[3] = srcs_gdis;
        l2_csr_kernel<<<144, 256, 0, stream>>>(p);
    }

    // ---- stage 1: fused Q GEMM (dg|disg, N=512), then per-graph KV + agg ----
    {
        dim3 gq((NG + 127) / 128, 8);
        gemm_nt<0, 0><<<gq, 256, 0, stream>>>(gene_bf, Wbf, dg_bq, disg_bq,
                                              dg_bq, dg_bq, Q12, 512,
                                              nullptr, nullptr, NG);
    }
    {
        dim3 gkv((ND + 127) / 128, 8);
        gemm_nt<0, 1><<<gkv, 256, 0, stream>>>(drug_bf, Wbf + (size_t)2 * 65536,
                                               dg_bk, dg_bv, dg_bk, dg_bk,
                                               KVb, 512, nullptr, nullptr, ND);
    }
    agg_gm_kernel<<<(NG + 3) / 4, 256, 0, stream>>>(Q12, 512, KVb, offs_dg, cnt_dg,
                                                    srcs_dg, gm_d, NG);
    {
        dim3 gkv((NS + 127) / 128, 8);
        gemm_nt<0, 1><<<gkv, 256, 0, stream>>>(dis_bf, Wbf + (size_t)4 * 65536,
                                               disg_bk, disg_bv, disg_bk, disg_bk,
                                               KVb, 512, nullptr, nullptr, NS);
    }
    agg_gm_kernel<<<(NG + 3) / 4, 256, 0, stream>>>(Q12 + 256, 512, KVb, offs_disg,
                                                    cnt_disg, srcs_disg, gm_s, NG);

    // ---- Bahdanau fusion + LN1 -> gene_out (fp32 + bf16 copy) ----
    {
        dim3 gb((NG + 127) / 128, 4);
        gemm_nt<1, 0><<<gb, 256, 0, stream>>>(gm_d, Wbf + (size_t)12 * 65536,
                                              f_b1, f_b1, f_b1, f_b1,
                                              nullptr, 256, f_v, e1, NG);
        gemm_nt<1, 0><<<gb, 256, 0, stream>>>(gm_s, Wbf + (size_t)13 * 65536,
                                              f_b2, f_b2, f_b2, f_b2,
                                              nullptr, 256, f_v, e2, NG);
    }
    gene_fusion_kernel<<<(NG + 3) / 4, 256, 0, stream>>>(
        gene_feat, gm_d, gm_s, e1, e2, cnt_dg, cnt_disg, ln1_g, ln1_b,
        out_gene, gene_out_bf);

    // ---- stage 2: gene->drug ----
    {
        dim3 gq((ND + 127) / 128, 4);
        gemm_nt<0, 0><<<gq, 256, 0, stream>>>(drug_bf, Wbf + (size_t)10 * 65536,
                                              gd_bq, gd_bq, gd_bq, gd_bq,
                                              Q12, 256, nullptr, nullptr, ND);
    }
    {
        dim3 gkv((NG + 127) / 128, 8);
        gemm_nt<0, 1><<<gkv, 256, 0, stream>>>(gene_out_bf, Wbf + (size_t)6 * 65536,
                                               gd_bk, gd_bv, gd_bk, gd_bk,
                                               KVb, 512, nullptr, nullptr, NG);
    }
    agg_ln_kernel<<<(ND + 3) / 4, 256, 0, stream>>>(Q12, 256, KVb, offs_gd, cnt_gd,
                                                    srcs_gd, drug_feat, ln2_g, ln2_b,
                                                    out_drug, ND);

    // ---- stage 2: gene->disease ----
    {
        dim3 gq((NS + 127) / 128, 4);
        gemm_nt<0, 0><<<gq, 256, 0, stream>>>(dis_bf, Wbf + (size_t)11 * 65536,
                                              gdis_bq, gdis_bq, gdis_bq, gdis_bq,
                                              Q12, 256, nullptr, nullptr, NS);
    }
    {
        dim3 gkv((NG + 127) / 128, 8);
        gemm_nt<0, 1><<<gkv, 256, 0, stream>>>(gene_out_bf, Wbf + (size_t)8 * 65536,
                                               gdis_bk, gdis_bv, gdis_bk, gdis_bk,
                                               KVb, 512, nullptr, nullptr, NG);
    }
    agg_ln_kernel<<<(NS + 3) / 4, 256, 0, stream>>>(Q12, 256, KVb, offs_gdis, cnt_gdis,
                                                    srcs_gdis, disease_feat, ln2_g, ln2_b,
                                                    out_dis, NS);
}

// Round 6
// 484.952 us; speedup vs baseline: 2.0785x; 1.0637x over previous
//
#include <hip/hip_runtime.h>

#define NG 20000
#define ND 8000
#define NS 8000
#define EE 300000
#define DIM 256
#define SCALE_QK 0.17677669529663687f  // 1/sqrt(32)
#define LNEPS 1e-5f

#define MAXB 40                        // max buckets per graph
#define L1CH 2048                      // edges per level-1 block
#define NCH1 ((EE + L1CH - 1) / L1CH)  // 147 blocks per graph
// bucket geometry: graphs 0,1 (dst<NG): shift 9 -> 40 buckets, cap 8704
//                  graphs 2,3 (dst<ND/NS): shift 8 -> 32 buckets, cap 10496
#define CB_G 8704
#define CB_S 10496
#define RB_G (40 * CB_G)               // 348160 records
#define RB_S (32 * CB_S)               // 335872 records

typedef __attribute__((ext_vector_type(4))) float floatx4;
typedef __attribute__((ext_vector_type(8))) short shortx8;
typedef __attribute__((ext_vector_type(8))) unsigned short ushortx8;
typedef unsigned int u32;

__device__ __forceinline__ float bf2f(unsigned short u) {
    union { unsigned u; float f; } c; c.u = ((unsigned)u) << 16; return c.f;
}
__device__ __forceinline__ unsigned short f2bf(float f) {
    union { float f; unsigned u; } c; c.f = f;
    return (unsigned short)((c.u + 0x7fffu + ((c.u >> 16) & 1u)) >> 16);
}
__device__ __forceinline__ float gelu_exact(float v) {
    return 0.5f * v * (1.0f + erff(v * 0.70710678118654752f));
}

// async global->LDS, 16B per lane; LDS dest = wave-uniform base + lane*16
__device__ __forceinline__ void async_load16(const unsigned short* g,
                                             unsigned short* lds) {
    __builtin_amdgcn_global_load_lds(
        (const __attribute__((address_space(1))) u32*)(const void*)g,
        (__attribute__((address_space(3))) u32*)(void*)lds, 16, 0, 0);
}

// short-offset of the 16B chunk (row, q) in a swizzled [rows][32-short] tile.
// Within each 16-row group, chunk (pair p, b=row&1, quad q) lives at
// slot8 = (4b+q)^p of pair-line p. Staging writes linearly (lane l -> slot l);
// the per-lane GLOBAL source is pre-permuted to match (both-sides rule).
__device__ __forceinline__ int swzoff(int row, int q) {
    int p = (row >> 1) & 7, b = row & 1;
    return ((row >> 4) * 64 + p * 8 + (((b << 2) + q) ^ p)) * 8;
}

// ---------------------------------------------------------------------------
// Batched MFMA GEMM: up to 4 independent problems in ONE dispatch
// (blockIdx.z selects the descriptor; surplus blocks exit immediately).
// C[M, ncol] = A[M,256] @ W[ncol,256]^T + bias.  A/W bf16, C bf16.
// global_load_lds staging (16B/lane) into double-buffered swizzled LDS,
// one barrier per K-step, next-tile prefetch before compute.
// M-tail rows read garbage from adjacent workspace — safe (all writes m<M).
// kvi=1: within each 512-col half, KV-interleave: K dim d -> (d>>2)*8+(d&3),
//   V dim d -> (d>>2)*8+4+(d&3).
// mode 0: store bf16 C.  mode 1: Bahdanau e[m] += sum_n v[n]*tanh(C+b).
// Tile 128m x 64n, BK=32, 256 threads.
// ---------------------------------------------------------------------------
struct GemmDesc {
    const unsigned short* A; const unsigned short* W;
    const float* b1; const float* b2; const float* b3; const float* b4;
    unsigned short* C; int ldc;
    const float* vvec; float* evec;
    int M; int gx; int ncol; int mode; int kvi;
};
struct GemmBatch { GemmDesc d[4]; };

__global__ __launch_bounds__(256, 4) void gemm_batch_kernel(GemmBatch gb)
{
    __shared__ unsigned short As[2][128 * 32];
    __shared__ unsigned short Bs[2][64 * 32];
    const GemmDesc d = gb.d[blockIdx.z];
    if ((int)blockIdx.x >= d.gx) return;
    const int n0 = blockIdx.y * 64;
    if (n0 >= d.ncol) return;

    const int tid = threadIdx.x;
    const int lane = tid & 63, wv = tid >> 6;
    const int quad = lane >> 4, l16 = lane & 15;
    const int m0 = blockIdx.x * 128;

    // staging lane mapping: lane l writes LDS slot l of its 16-row group;
    // source chunk = logical (row = 2p + ((s^p)>>2), q = (s^p)&3)
    const int sp = lane >> 3, ss = lane & 7;
    const int srow = 2 * sp + ((ss ^ sp) >> 2);
    const int sq = (ss ^ sp) & 3;
    const unsigned short* gA0 = d.A + (size_t)(m0 + wv * 16 + srow) * 256 + sq * 8;
    const unsigned short* gA1 = d.A + (size_t)(m0 + 64 + wv * 16 + srow) * 256 + sq * 8;
    const unsigned short* gB  = d.W + (size_t)(n0 + wv * 16 + srow) * 256 + sq * 8;

    floatx4 acc[2][4];
#pragma unroll
    for (int i = 0; i < 2; ++i)
#pragma unroll
        for (int j = 0; j < 4; ++j) acc[i][j] = (floatx4){0.f, 0.f, 0.f, 0.f};

    // prologue: stage k0 = 0 into buf 0
    async_load16(gA0, &As[0][(wv * 16) * 32]);
    async_load16(gA1, &As[0][(64 + wv * 16) * 32]);
    async_load16(gB,  &Bs[0][(wv * 16) * 32]);
    __syncthreads();

    for (int k0 = 0; k0 < 256; k0 += 32) {
        const int buf = (k0 >> 5) & 1;
        if (k0 < 224) {   // prefetch next K-tile into other buffer
            const int nb = buf ^ 1;
            async_load16(gA0 + k0 + 32, &As[nb][(wv * 16) * 32]);
            async_load16(gA1 + k0 + 32, &As[nb][(64 + wv * 16) * 32]);
            async_load16(gB + k0 + 32,  &Bs[nb][(wv * 16) * 32]);
        }
        shortx8 af[2], bfr[4];
#pragma unroll
        for (int mf = 0; mf < 2; ++mf)
            af[mf] = *(const shortx8*)(&As[buf][swzoff(wv * 32 + mf * 16 + l16, quad)]);
#pragma unroll
        for (int nf = 0; nf < 4; ++nf)
            bfr[nf] = *(const shortx8*)(&Bs[buf][swzoff(nf * 16 + l16, quad)]);
#pragma unroll
        for (int mf = 0; mf < 2; ++mf)
#pragma unroll
            for (int nf = 0; nf < 4; ++nf)
                acc[mf][nf] = __builtin_amdgcn_mfma_f32_16x16x32_bf16(
                    af[mf], bfr[nf], acc[mf][nf], 0, 0, 0);
        __syncthreads();   // drains prefetch (vmcnt) + protects buf reuse
    }

    if (d.mode == 0) {
#pragma unroll
        for (int mf = 0; mf < 2; ++mf)
#pragma unroll
            for (int r = 0; r < 4; ++r) {
                int m = m0 + wv * 32 + mf * 16 + quad * 4 + r;
                if (m < d.M) {
#pragma unroll
                    for (int nf = 0; nf < 4; ++nf) {
                        int n = n0 + nf * 16 + l16;
                        int h = n >> 8;
                        const float* bp = (h == 0) ? d.b1 : (h == 1) ? d.b2
                                        : (h == 2) ? d.b3 : d.b4;
                        float bn = bp[n & 255];
                        int pos;
                        if (d.kvi) {
                            int nn = n & 511;
                            pos = (n & ~511) + ((nn & 255) >> 2) * 8 + (nn & 3) +
                                  ((nn >> 8) << 2);
                        } else {
                            pos = n;
                        }
                        d.C[(size_t)m * d.ldc + pos] = f2bf(acc[mf][nf][r] + bn);
                    }
                }
            }
    } else {
        float p[2][4] = {};
#pragma unroll
        for (int mf = 0; mf < 2; ++mf)
#pragma unroll
            for (int nf = 0; nf < 4; ++nf) {
                int n = n0 + nf * 16 + l16;
                float vn = d.vvec[n];
                float bn = d.b1[n];
#pragma unroll
                for (int r = 0; r < 4; ++r)
                    p[mf][r] += vn * tanhf(acc[mf][nf][r] + bn);
            }
#pragma unroll
        for (int mf = 0; mf < 2; ++mf)
#pragma unroll
            for (int r = 0; r < 4; ++r) {
                float s = p[mf][r];
                s += __shfl_xor(s, 1); s += __shfl_xor(s, 2);
                s += __shfl_xor(s, 4); s += __shfl_xor(s, 8);
                if (l16 == 0) {
                    int m = m0 + wv * 32 + mf * 16 + quad * 4 + r;
                    if (m < d.M) atomicAdd(&d.evec[m], s);
                }
            }
    }
}

// ---------------------------------------------------------------------------
// Fused prep: workspace zeroing + weight bf16 convert + feature bf16 convert
// ---------------------------------------------------------------------------
struct PrepP {
    int* zb; int zn; int nzb;
    const float* wsrc[14];
    unsigned short* wout;
    const float* gf; const float* df; const float* sf;
    unsigned short* go; unsigned short* dfo; unsigned short* so;
};
__global__ void prep_kernel(PrepP p) {
    int bid = blockIdx.x, tid = threadIdx.x;
    if (bid < p.nzb) {
        int i = bid * 256 + tid;
        if (i < p.zn) p.zb[i] = 0;
        return;
    }
    bid -= p.nzb;
    if (bid < 896) {   // weights: 14 x 65536, 4 floats/thread
        int idx = bid * 256 + tid;
        int mat = idx >> 14;
        int e = (idx & 16383) << 2;
        float4 f = *(const float4*)(p.wsrc[mat] + e);
        ushort4 t;
        t.x = f2bf(f.x); t.y = f2bf(f.y); t.z = f2bf(f.z); t.w = f2bf(f.w);
        *(ushort4*)(p.wout + ((size_t)mat << 16) + e) = t;
        return;
    }
    bid -= 896;
    const int NG4 = NG * 64, ND4 = ND * 64, NS4 = NS * 64;
    int i = bid * 256 + tid;
    const float* in; unsigned short* out; int j;
    if (i < NG4) { in = p.gf; out = p.go; j = i; }
    else if (i < NG4 + ND4) { in = p.df; out = p.dfo; j = i - NG4; }
    else if (i < NG4 + ND4 + NS4) { in = p.sf; out = p.so; j = i - NG4 - ND4; }
    else return;
    float4 f = *(const float4*)(in + (size_t)j * 4);
    ushort4 t;
    t.x = f2bf(f.x); t.y = f2bf(f.y); t.z = f2bf(f.z); t.w = f2bf(f.w);
    *(ushort4*)(out + (size_t)j * 4) = t;
}

__global__ void fillf_kernel(float* __restrict__ p, int n, float v) {
    int i = blockIdx.x * blockDim.x + threadIdx.x;
    if (i < n) p[i] = v;
}

// ---------------------------------------------------------------------------
// 2-level CSR build (unchanged from round 4/5).
// ---------------------------------------------------------------------------
struct L1P {
    const int* src[4];
    const int* dst[4];
    int* brec[4];
    int* bcur;          // [4*MAXB], zeroed before launch
};
__global__ __launch_bounds__(256) void l1_bucket_kernel(L1P a) {
    __shared__ int hist[MAXB];
    int g = blockIdx.x / NCH1, c = blockIdx.x - g * NCH1;
    int base = c * L1CH;
    int tid = threadIdx.x;
    const int shift = (g < 2) ? 9 : 8;
    const int CB = (g < 2) ? CB_G : CB_S;
    const int NB = (g < 2) ? 40 : 32;
    if (tid < NB) hist[tid] = 0;
    __syncthreads();
    const int* __restrict__ dstp = a.dst[g];
    const int* __restrict__ srcp = a.src[g];
    int bk[8], rec[8], lr[8];
#pragma unroll
    for (int j = 0; j < 8; ++j) {
        int e = base + j * 256 + tid;
        bool ok = e < EE;
        int dd = ok ? dstp[e] : 0;
        int ss = ok ? srcp[e] : 0;
        bk[j] = dd >> shift;
        rec[j] = ((dd & ((1 << shift) - 1)) << 15) | ss;
        lr[j] = ok ? atomicAdd(&hist[bk[j]], 1) : -1;
    }
    __syncthreads();
    if (tid < NB) {
        int h = hist[tid];
        if (h > 0) hist[tid] = atomicAdd(&a.bcur[g * MAXB + tid], h);
    }
    __syncthreads();
    int* __restrict__ recp = a.brec[g];
#pragma unroll
    for (int j = 0; j < 8; ++j) {
        if (lr[j] >= 0) {
            int pos = hist[bk[j]] + lr[j];
            if (pos < CB) recp[bk[j] * CB + pos] = rec[j];
        }
    }
}

struct L2P {
    const int* brec[4];
    const int* bcur;
    int* cnt[4];
    int* offs[4];
    int* srcs[4];
};
__global__ __launch_bounds__(256) void l2_csr_kernel(L2P a) {
    __shared__ int hist[512];
    __shared__ int loffs[512];
    __shared__ int cur[512];
    __shared__ int ws2[4];
    __shared__ int bb;
    int bid = blockIdx.x, tid = threadIdx.x;
    int g, b;
    if (bid < 40) { g = 0; b = bid; }
    else if (bid < 80) { g = 1; b = bid - 40; }
    else if (bid < 112) { g = 2; b = bid - 80; }
    else { g = 3; b = bid - 112; }
    const int shift = (g < 2) ? 9 : 8;
    const int BSZ = 1 << shift;
    const int CB = (g < 2) ? CB_G : CB_S;
    const int N = (g < 2) ? NG : ((g == 2) ? ND : NS);
    hist[tid] = 0; hist[256 + tid] = 0;
    if (tid == 0) {
        int s = 0;
        const int* bc = a.bcur + g * MAXB;
        for (int i = 0; i < b; ++i) s += bc[i];
        bb = s;
    }
    __syncthreads();
    int total = a.bcur[g * MAXB + b];
    if (total > CB) total = CB;
    const int* __restrict__ recp = a.brec[g] + b * CB;
    for (int i = tid; i < total; i += 256)
        atomicAdd(&hist[recp[i] >> 15], 1);
    __syncthreads();
    int v0 = hist[2 * tid], v1 = hist[2 * tid + 1];
    int s = v0 + v1, x = s;
    int lane = tid & 63, wv = tid >> 6;
#pragma unroll
    for (int o = 1; o < 64; o <<= 1) {
        int u = __shfl_up(x, o);
        if (lane >= o) x += u;
    }
    if (lane == 63) ws2[wv] = x;
    __syncthreads();
    int woff = 0;
    for (int w = 0; w < wv; ++w) woff += ws2[w];
    int excl = woff + x - s;
    loffs[2 * tid] = excl; loffs[2 * tid + 1] = excl + v0;
    cur[2 * tid] = excl;  cur[2 * tid + 1] = excl + v0;
    int base = bb;
    int lo = b << shift;
    for (int i = tid; i < BSZ; i += 256) {
        int dd = lo + i;
        if (dd < N) {
            a.cnt[g][dd] = hist[i];
            a.offs[g][dd] = base + loffs[i];
        }
    }
    __syncthreads();
    int* __restrict__ sp = a.srcs[g];
    for (int i = tid; i < total; i += 256) {
        int rec = recp[i];
        int pos = atomicAdd(&cur[rec >> 15], 1);
        sp[base + pos] = rec & 0x7fff;
    }
}

// ---------------------------------------------------------------------------
// Fused CSR aggregation — ONE WAVE PER NODE. KV interleaved per 4 dims; 8
// independent online-softmax chains; srcs for the NEXT batch are prefetched
// before issuing current KV loads (pipelines the srcs->KV latency chain).
// ---------------------------------------------------------------------------
__device__ __forceinline__ void wave_attn_node(
    const unsigned short* __restrict__ Q, int qs,
    const unsigned short* __restrict__ KV,
    const int* __restrict__ offs, const int* __restrict__ cnt,
    const int* __restrict__ srcs, int du, int lane,
    float& g0, float& g1, float& g2, float& g3)
{
    const int lo = lane * 4;
    const int lofs = lane * 8;
    ushort4 qv = *(const ushort4*)(Q + (size_t)du * qs + lo);
    const float q0 = bf2f(qv.x), q1 = bf2f(qv.y), q2 = bf2f(qv.z), q3 = bf2f(qv.w);
    const int beg = offs[du], num = cnt[du];

    float m[8], l[8], a[8][4];
#pragma unroll
    for (int c = 0; c < 8; ++c) {
        m[c] = -INFINITY; l[c] = 0.f;
        a[c][0] = a[c][1] = a[c][2] = a[c][3] = 0.f;
    }

    int sb[8];
    if (num > 0) {
#pragma unroll
        for (int c = 0; c < 8; ++c)
            sb[c] = srcs[beg + ((c < num) ? c : (num - 1))];
    }

    for (int i = 0; i < num; i += 8) {
        int sn[8];
        const bool more = (i + 8) < num;
        if (more) {   // prefetch next batch's src indices
#pragma unroll
            for (int c = 0; c < 8; ++c) {
                int idx = i + 8 + c;
                sn[c] = srcs[beg + ((idx < num) ? idx : (num - 1))];
            }
        }
        ushortx8 kv[8];
#pragma unroll
        for (int c = 0; c < 8; ++c)
            kv[c] = *(const ushortx8*)(KV + (size_t)sb[c] * 512 + lofs);
        float p[8];
#pragma unroll
        for (int c = 0; c < 8; ++c)
            p[c] = q0 * bf2f(kv[c][0]) + q1 * bf2f(kv[c][1]) +
                   q2 * bf2f(kv[c][2]) + q3 * bf2f(kv[c][3]);
#pragma unroll
        for (int c = 0; c < 8; ++c) p[c] += __shfl_xor(p[c], 1);
#pragma unroll
        for (int c = 0; c < 8; ++c) p[c] += __shfl_xor(p[c], 2);
#pragma unroll
        for (int c = 0; c < 8; ++c) p[c] += __shfl_xor(p[c], 4);
#pragma unroll
        for (int c = 0; c < 8; ++c) {
            if (i + c < num) {   // wave-uniform branch
                float sc = p[c] * SCALE_QK;
                float mn = fmaxf(m[c], sc);
                float eo = __expf(m[c] - mn);   // first edge: exp(-inf)=0
                float en = __expf(sc - mn);
                a[c][0] = a[c][0] * eo + en * bf2f(kv[c][4]);
                a[c][1] = a[c][1] * eo + en * bf2f(kv[c][5]);
                a[c][2] = a[c][2] * eo + en * bf2f(kv[c][6]);
                a[c][3] = a[c][3] * eo + en * bf2f(kv[c][7]);
                l[c] = l[c] * eo + en;
                m[c] = mn;
            }
        }
        if (more) {
#pragma unroll
            for (int c = 0; c < 8; ++c) sb[c] = sn[c];
        }
    }

    float ms = fmaxf(fmaxf(fmaxf(m[0], m[1]), fmaxf(m[2], m[3])),
                     fmaxf(fmaxf(m[4], m[5]), fmaxf(m[6], m[7])));
    float A0 = 0.f, A1 = 0.f, A2 = 0.f, A3 = 0.f, L = 0.f;
    if (ms > -INFINITY) {
#pragma unroll
        for (int c = 0; c < 8; ++c) {
            float w = __expf(m[c] - ms);
            A0 += a[c][0] * w; A1 += a[c][1] * w;
            A2 += a[c][2] * w; A3 += a[c][3] * w;
            L += l[c] * w;
        }
    }
    float inv = (L > 0.f) ? 1.f / L : 0.f;
    g0 = A0 * inv; g1 = A1 * inv; g2 = A2 * inv; g3 = A3 * inv;
}

__device__ __forceinline__ void wave_ln_store(
    float x0, float x1, float x2, float x3,
    const float* __restrict__ g, const float* __restrict__ b,
    float* __restrict__ out, unsigned short* __restrict__ out_bf,
    int du, int lo)
{
    float s1 = x0 + x1 + x2 + x3;
    float s2 = x0 * x0 + x1 * x1 + x2 * x2 + x3 * x3;
#pragma unroll
    for (int o = 1; o < 64; o <<= 1) {
        s1 += __shfl_xor(s1, o);
        s2 += __shfl_xor(s2, o);
    }
    float mu = s1 * (1.f / 256.f);
    float var = fmaxf(s2 * (1.f / 256.f) - mu * mu, 0.f);
    float rs = rsqrtf(var + LNEPS);
    float4 gv = *(const float4*)(g + lo);
    float4 bv = *(const float4*)(b + lo);
    float y0 = (x0 - mu) * rs * gv.x + bv.x;
    float y1 = (x1 - mu) * rs * gv.y + bv.y;
    float y2 = (x2 - mu) * rs * gv.z + bv.z;
    float y3 = (x3 - mu) * rs * gv.w + bv.w;
    *(float4*)(out + (size_t)du * 256 + lo) = make_float4(y0, y1, y2, y3);
    if (out_bf) {
        ushort4 t; t.x = f2bf(y0); t.y = f2bf(y1); t.z = f2bf(y2); t.w = f2bf(y3);
        *(ushort4*)(out_bf + (size_t)du * 256 + lo) = t;
    }
}

// Two independent aggregation problems fused into one dispatch.
// LN=0: store bf16 gm.  LN=1: feat + gelu + LayerNorm -> fp32 out.
struct AggDesc {
    const unsigned short* Q; int qs;
    const unsigned short* KV;
    const int* offs; const int* cnt; const int* srcs;
    unsigned short* gm;
    const float* feat; const float* g; const float* b; float* out;
    int N;
};
template <int LN>
__global__ __launch_bounds__(256) void agg2_kernel(AggDesc a0, AggDesc a1, int nb0)
{
    const bool first = (int)blockIdx.x < nb0;
    const AggDesc d = first ? a0 : a1;
    const int bx = first ? blockIdx.x : (blockIdx.x - nb0);
    int lane = threadIdx.x & 63, wv = threadIdx.x >> 6;
    int nd = bx * 4 + wv;
    if (nd >= d.N) return;
    int du = __builtin_amdgcn_readfirstlane(nd);
    int lo = lane * 4;
    float g0, g1, g2, g3;
    wave_attn_node(d.Q, d.qs, d.KV, d.offs, d.cnt, d.srcs, du, lane, g0, g1, g2, g3);
    if (LN == 0) {
        ushort4 t; t.x = f2bf(g0); t.y = f2bf(g1); t.z = f2bf(g2); t.w = f2bf(g3);
        *(ushort4*)(d.gm + (size_t)du * 256 + lo) = t;
    } else {
        float4 fv = *(const float4*)(d.feat + (size_t)du * 256 + lo);
        float x0 = fv.x + gelu_exact(g0);
        float x1 = fv.y + gelu_exact(g1);
        float x2 = fv.z + gelu_exact(g2);
        float x3 = fv.w + gelu_exact(g3);
        wave_ln_store(x0, x1, x2, x3, d.g, d.b, d.out, nullptr, du, lo);
    }
}

__global__ __launch_bounds__(256) void gene_fusion_kernel(
    const float* __restrict__ gene_feat, const unsigned short* __restrict__ gm_d,
    const unsigned short* __restrict__ gm_s, const float* __restrict__ e1,
    const float* __restrict__ e2, const int* __restrict__ cnt_d,
    const int* __restrict__ cnt_s, const float* __restrict__ g,
    const float* __restrict__ b, float* __restrict__ out,
    unsigned short* __restrict__ out_bf)
{
    int lane = threadIdx.x & 63, wv = threadIdx.x >> 6;
    int d = blockIdx.x * 4 + wv;
    if (d >= NG) return;
    int du = __builtin_amdgcn_readfirstlane(d);
    int lo = lane * 4;
    ushort4 v1 = *(const ushort4*)(gm_d + (size_t)du * 256 + lo);
    ushort4 v2 = *(const ushort4*)(gm_s + (size_t)du * 256 + lo);
    bool hd = cnt_d[du] > 0, hs = cnt_s[du] > 0;
    float wa, wb;
    if (hd && hs) {
        float aa = e1[du], bb = e2[du];
        float mm = fmaxf(aa, bb);   // softmax([e1+bv,e2+bv]) == softmax([e1,e2])
        float ea = __expf(aa - mm), eb = __expf(bb - mm);
        float inv = 1.f / (ea + eb);
        wa = ea * inv; wb = eb * inv;
    } else if (hd) { wa = 1.f; wb = 0.f; }
    else if (hs) { wa = 0.f; wb = 1.f; }
    else { wa = 0.f; wb = 0.f; }
    float m0 = wa * bf2f(v1.x) + wb * bf2f(v2.x);
    float m1 = wa * bf2f(v1.y) + wb * bf2f(v2.y);
    float m2 = wa * bf2f(v1.z) + wb * bf2f(v2.z);
    float m3 = wa * bf2f(v1.w) + wb * bf2f(v2.w);
    float4 fv = *(const float4*)(gene_feat + (size_t)du * 256 + lo);
    float x0 = fv.x + gelu_exact(m0);
    float x1 = fv.y + gelu_exact(m1);
    float x2 = fv.z + gelu_exact(m2);
    float x3 = fv.w + gelu_exact(m3);
    wave_ln_store(x0, x1, x2, x3, g, b, out, out_bf, du, lo);
}

// ---------------------------------------------------------------------------
extern "C" void kernel_launch(void* const* d_in, const int* in_sizes, int n_in,
                              void* d_out, int out_size, void* d_ws, size_t ws_size,
                              hipStream_t stream)
{
    float* out_f32 = (float*)d_out;

    const float* gene_feat    = (const float*)d_in[0];
    const float* drug_feat    = (const float*)d_in[1];
    const float* disease_feat = (const float*)d_in[2];
    const float* dg_Wq = (const float*)d_in[3];
    const float* dg_bq = (const float*)d_in[4];
    const float* dg_Wk = (const float*)d_in[5];
    const float* dg_bk = (const float*)d_in[6];
    const float* dg_Wv = (const float*)d_in[7];
    const float* dg_bv = (const float*)d_in[8];
    const float* disg_Wq = (const float*)d_in[9];
    const float* disg_bq = (const float*)d_in[10];
    const float* disg_Wk = (const float*)d_in[11];
    const float* disg_bk = (const float*)d_in[12];
    const float* disg_Wv = (const float*)d_in[13];
    const float* disg_bv = (const float*)d_in[14];
    const float* gd_Wq = (const float*)d_in[15];
    const float* gd_bq = (const float*)d_in[16];
    const float* gd_Wk = (const float*)d_in[17];
    const float* gd_bk = (const float*)d_in[18];
    const float* gd_Wv = (const float*)d_in[19];
    const float* gd_bv = (const float*)d_in[20];
    const float* gdis_Wq = (const float*)d_in[21];
    const float* gdis_bq = (const float*)d_in[22];
    const float* gdis_Wk = (const float*)d_in[23];
    const float* gdis_bk = (const float*)d_in[24];
    const float* gdis_Wv = (const float*)d_in[25];
    const float* gdis_bv = (const float*)d_in[26];
    const float* f_W1 = (const float*)d_in[27];
    const float* f_b1 = (const float*)d_in[28];
    const float* f_W2 = (const float*)d_in[29];
    const float* f_b2 = (const float*)d_in[30];
    const float* f_v  = (const float*)d_in[31];
    const float* ln1_g = (const float*)d_in[33];
    const float* ln1_b = (const float*)d_in[34];
    const float* ln2_g = (const float*)d_in[35];
    const float* ln2_b = (const float*)d_in[36];
    const int* dg_src   = (const int*)d_in[37];
    const int* dg_dst   = (const int*)d_in[38];
    const int* disg_src = (const int*)d_in[39];
    const int* disg_dst = (const int*)d_in[40];
    const int* gd_src   = (const int*)d_in[41];
    const int* gd_dst   = (const int*)d_in[42];
    const int* gdis_src = (const int*)d_in[43];
    const int* gdis_dst = (const int*)d_in[44];

    // ---- workspace ----
    char* ws = (char*)d_ws;
    size_t off = 0;
    auto alloc = [&](size_t bytes) -> char* {
        char* p = ws + off;
        off += (bytes + 511) & ~(size_t)511;
        return p;
    };
    // zero region start
    int* bcur = (int*)alloc(4 * MAXB * 4);
    float* e1 = (float*)alloc(NG * 4);
    float* e2 = (float*)alloc(NG * 4);
    size_t zero_len = off;   // bytes to zero each call
    int* offs_dg   = (int*)alloc(NG * 4);
    int* offs_disg = (int*)alloc(NG * 4);
    int* offs_gd   = (int*)alloc(ND * 4);
    int* offs_gdis = (int*)alloc(NS * 4);
    int* cnt_dg    = (int*)alloc(NG * 4);
    int* cnt_disg  = (int*)alloc(NG * 4);
    int* cnt_gd    = (int*)alloc(ND * 4);
    int* cnt_gdis  = (int*)alloc(NS * 4);
    int* srcs_dg   = (int*)alloc((size_t)EE * 4);
    int* srcs_disg = (int*)alloc((size_t)EE * 4);
    int* srcs_gd   = (int*)alloc((size_t)EE * 4);
    int* srcs_gdis = (int*)alloc((size_t)EE * 4);
    unsigned short* Q12  = (unsigned short*)alloc((size_t)NG * 512 * 2);  // 20.5MB
    unsigned short* KVb  = (unsigned short*)alloc((size_t)NG * 512 * 2);
    unsigned short* gm_d = (unsigned short*)alloc((size_t)NG * 256 * 2);
    unsigned short* gm_s = (unsigned short*)alloc((size_t)NG * 256 * 2);
    unsigned short* gene_bf = (unsigned short*)alloc((size_t)NG * 256 * 2);
    unsigned short* drug_bf = (unsigned short*)alloc((size_t)ND * 256 * 2);
    unsigned short* dis_bf  = (unsigned short*)alloc((size_t)NS * 256 * 2);
    unsigned short* Wbf     = (unsigned short*)alloc((size_t)14 * 65536 * 2);
    char* guard = alloc(64 * 1024);   // M-tail garbage-read guard after Wbf
    (void)guard;
    size_t need = off;

    // level-1 record buffers overlay Q12 (dead until after l2_csr_kernel)
    int* brec0 = (int*)Q12;
    int* brec1 = brec0 + RB_G;
    int* brec2 = brec1 + RB_G;
    int* brec3 = brec2 + RB_S;     // total 5.47MB <= 20.5MB

    // overlays:
    // KVb2 (stage-2 second KV, NG*512) = gm_s + gene_bf (both dead after H;
    //   each is NG*256*2 B and 512-aligned-contiguous -> exactly NG*512*2 B)
    unsigned short* KVb2 = gm_s;
    // stage-1 second KV (disg, NS rows) lives inside KVb at row offset ND
    unsigned short* KVs1b = KVb + (size_t)ND * 512;
    // stage-2 Q buffers overlay Q12 (stage-1 Q dead after AG1)
    unsigned short* Qd = Q12;                         // [ND][256]
    unsigned short* Qs = Q12 + (size_t)ND * 256;      // [NS][256]
    // gm_d is dead after gene_fusion_kernel -> reuse as bf16 gene_out
    unsigned short* gene_out_bf = gm_d;

    float* out_drug = out_f32;                       // [8000, 256]
    float* out_dis  = out_drug + (size_t)ND * 256;   // [8000, 256]
    float* out_gene = out_dis + (size_t)NS * 256;    // [20000, 256]

    if (ws_size < need) {   // sentinel: 1000.0f
        fillf_kernel<<<(out_size + 255) / 256, 256, 0, stream>>>(out_f32, out_size, 1000.0f);
        return;
    }

    // ---- fused prep: zero + weight convert + feature convert ----
    // W layout: 0 dg_Wq | 1 disg_Wq  (fused stage-1 Q, N=512)
    //           2 dg_Wk | 3 dg_Wv    4 disg_Wk | 5 disg_Wv
    //           6 gd_Wk | 7 gd_Wv    8 gdis_Wk | 9 gdis_Wv
    //           10 gd_Wq  11 gdis_Wq  12 f_W1  13 f_W2
    {
        PrepP p;
        p.zb = (int*)d_ws;
        p.zn = (int)(zero_len / 4);
        p.nzb = (p.zn + 255) / 256;
        const float* wl[14] = {dg_Wq, disg_Wq, dg_Wk, dg_Wv, disg_Wk, disg_Wv,
                               gd_Wk, gd_Wv, gdis_Wk, gdis_Wv, gd_Wq, gdis_Wq,
                               f_W1, f_W2};
        for (int i = 0; i < 14; ++i) p.wsrc[i] = wl[i];
        p.wout = Wbf;
        p.gf = gene_feat; p.df = drug_feat; p.sf = disease_feat;
        p.go = gene_bf; p.dfo = drug_bf; p.so = dis_bf;
        int nfeat = ((NG + ND + NS) * 64 + 255) / 256;
        prep_kernel<<<p.nzb + 896 + nfeat, 256, 0, stream>>>(p);
    }

    // ---- 2-level CSR build ----
    {
        L1P p;
        p.src[0] = dg_src; p.src[1] = disg_src; p.src[2] = gd_src; p.src[3] = gdis_src;
        p.dst[0] = dg_dst; p.dst[1] = disg_dst; p.dst[2] = gd_dst; p.dst[3] = gdis_dst;
        p.brec[0] = brec0; p.brec[1] = brec1; p.brec[2] = brec2; p.brec[3] = brec3;
        p.bcur = bcur;
        l1_bucket_kernel<<<4 * NCH1, 256, 0, stream>>>(p);
    }
    {
        L2P p;
        p.brec[0] = brec0; p.brec[1] = brec1; p.brec[2] = brec2; p.brec[3] = brec3;
        p.bcur = bcur;
        p.cnt[0] = cnt_dg; p.cnt[1] = cnt_disg; p.cnt[2] = cnt_gd; p.cnt[3] = cnt_gdis;
        p.offs[0] = offs_dg; p.offs[1] = offs_disg; p.offs[2] = offs_gd; p.offs[3] = offs_gdis;
        p.srcs[0] = srcs_dg; p.srcs[1] = srcs_disg; p.srcs[2] = srcs_gd; p.srcs[3] = srcs_gdis;
        l2_csr_kernel<<<144, 256, 0, stream>>>(p);
    }

    const int GXG = (NG + 127) / 128;   // 157
    const int GXS = (ND + 127) / 128;   // 63 (ND==NS)

    auto mkd = [](const unsigned short* A, const unsigned short* W,
                  const float* b1, const float* b2, const float* b3, const float* b4,
                  unsigned short* C, int ldc, const float* vv, float* ev,
                  int M, int gx, int ncol, int mode, int kvi) {
        GemmDesc d;
        d.A = A; d.W = W; d.b1 = b1; d.b2 = b2; d.b3 = b3; d.b4 = b4;
        d.C = C; d.ldc = ldc; d.vvec = vv; d.evec = ev;
        d.M = M; d.gx = gx; d.ncol = ncol; d.mode = mode; d.kvi = kvi;
        return d;
    };
    auto mka = [](const unsigned short* Q, int qs, const unsigned short* KV,
                  const int* offs, const int* cnt, const int* srcs,
                  unsigned short* gm, const float* feat, const float* g,
                  const float* b, float* out, int N) {
        AggDesc d;
        d.Q = Q; d.qs = qs; d.KV = KV; d.offs = offs; d.cnt = cnt; d.srcs = srcs;
        d.gm = gm; d.feat = feat; d.g = g; d.b = b; d.out = out; d.N = N;
        return d;
    };

    // ---- G1: stage-1 Q (fused dg|disg) + both stage-1 KV GEMMs ----
    {
        GemmBatch gb;
        gb.d[0] = mkd(gene_bf, Wbf, dg_bq, disg_bq, dg_bq, dg_bq,
                      Q12, 512, nullptr, nullptr, NG, GXG, 512, 0, 0);
        gb.d[1] = mkd(drug_bf, Wbf + (size_t)2 * 65536, dg_bk, dg_bv, dg_bk, dg_bk,
                      KVb, 512, nullptr, nullptr, ND, GXS, 512, 0, 1);
        gb.d[2] = mkd(dis_bf, Wbf + (size_t)4 * 65536, disg_bk, disg_bv, disg_bk, disg_bk,
                      KVs1b, 512, nullptr, nullptr, NS, GXS, 512, 0, 1);
        gb.d[3] = gb.d[2]; gb.d[3].gx = 0;
        gemm_batch_kernel<<<dim3(GXG, 8, 3), 256, 0, stream>>>(gb);
    }

    // ---- AG1: both stage-1 aggregations fused ----
    {
        AggDesc a0 = mka(Q12, 512, KVb, offs_dg, cnt_dg, srcs_dg,
                         gm_d, nullptr, nullptr, nullptr, nullptr, NG);
        AggDesc a1 = mka(Q12 + 256, 512, KVs1b, offs_disg, cnt_disg, srcs_disg,
                         gm_s, nullptr, nullptr, nullptr, nullptr, NG);
        int nb = (NG + 3) / 4;
        agg2_kernel<0><<<2 * nb, 256, 0, stream>>>(a0, a1, nb);
    }

    // ---- G2: Bahdanau e1/e2 GEMMs + stage-2 Q GEMMs (independent) ----
    {
        GemmBatch gb;
        gb.d[0] = mkd(gm_d, Wbf + (size_t)12 * 65536, f_b1, f_b1, f_b1, f_b1,
                      nullptr, 256, f_v, e1, NG, GXG, 256, 1, 0);
        gb.d[1] = mkd(gm_s, Wbf + (size_t)13 * 65536, f_b2, f_b2, f_b2, f_b2,
                      nullptr, 256, f_v, e2, NG, GXG, 256, 1, 0);
        gb.d[2] = mkd(drug_bf, Wbf + (size_t)10 * 65536, gd_bq, gd_bq, gd_bq, gd_bq,
                      Qd, 256, nullptr, nullptr, ND, GXS, 256, 0, 0);
        gb.d[3] = mkd(dis_bf, Wbf + (size_t)11 * 65536, gdis_bq, gdis_bq, gdis_bq, gdis_bq,
                      Qs, 256, nullptr, nullptr, NS, GXS, 256, 0, 0);
        gemm_batch_kernel<<<dim3(GXG, 4, 4), 256, 0, stream>>>(gb);
    }

    // ---- H: Bahdanau fusion + LN1 -> gene_out (fp32 + bf16 copy) ----
    gene_fusion_kernel<<<(NG + 3) / 4, 256, 0, stream>>>(
        gene_feat, gm_d, gm_s, e1, e2, cnt_dg, cnt_disg, ln1_g, ln1_b,
        out_gene, gene_out_bf);

    // ---- G3: both stage-2 KV GEMMs (gd -> KVb, gdis -> KVb2) ----
    {
        GemmBatch gb;
        gb.d[0] = mkd(gene_out_bf, Wbf + (size_t)6 * 65536, gd_bk, gd_bv, gd_bk, gd_bk,
                      KVb, 512, nullptr, nullptr, NG, GXG, 512, 0, 1);
        gb.d[1] = mkd(gene_out_bf, Wbf + (size_t)8 * 65536, gdis_bk, gdis_bv, gdis_bk, gdis_bk,
                      KVb2, 512, nullptr, nullptr, NG, GXG, 512, 0, 1);
        gb.d[2] = gb.d[1]; gb.d[2].gx = 0;
        gb.d[3] = gb.d[1]; gb.d[3].gx = 0;
        gemm_batch_kernel<<<dim3(GXG, 8, 2), 256, 0, stream>>>(gb);
    }

    // ---- AG2: both stage-2 aggregations (+gelu+LN) fused ----
    {
        AggDesc a0 = mka(Qd, 256, KVb, offs_gd, cnt_gd, srcs_gd,
                         nullptr, drug_feat, ln2_g, ln2_b, out_drug, ND);
        AggDesc a1 = mka(Qs, 256, KVb2, offs_gdis, cnt_gdis, srcs_gdis,
                         nullptr, disease_feat, ln2_g, ln2_b, out_dis, NS);
        int nb = (ND + 3) / 4;
        agg2_kernel<1><<<2 * nb, 256, 0, stream>>>(a0, a1, nb);
    }
}